// Round 1
// baseline (3087.233 us; speedup 1.0000x reference)
//
#include <hip/hip_runtime.h>
#include <math.h>

#define KDIM 5
#define KC 125

__device__ __forceinline__ int lower_bound_i(const int* __restrict__ a, int n, int v) {
    int lo = 0, hi = n;
    while (lo < hi) { int m = (lo + hi) >> 1; if (a[m] < v) lo = m + 1; else hi = m; }
    return lo;
}

__device__ __forceinline__ float elu_f(float x) { return x > 0.f ? x : (expf(x) - 1.f); }

// ---------------- Level 1: Cin=1, Cout=64 ----------------
__global__ void conv1_kernel(const float* __restrict__ pos,
                             const int* __restrict__ src, const int* __restrict__ tgt, int E,
                             const float* __restrict__ W, const float* __restrict__ R,
                             const float* __restrict__ b, float* __restrict__ xout)
{
    __shared__ float A[KC];
    __shared__ int rs_s, re_s;
    int node = blockIdx.x;
    int t = threadIdx.x;                      // blockDim = 128
    if (t < KC) A[t] = 0.f;
    if (t == 0) { rs_s = lower_bound_i(tgt, E, node); re_s = lower_bound_i(tgt, E, node + 1); }
    __syncthreads();
    int rs = rs_s, re = re_s;
    float tx = pos[node*3+0], ty = pos[node*3+1], tz = pos[node*3+2];
    for (int e = rs + t; e < re; e += blockDim.x) {
        int s = src[e];
        float p0 = fminf(fmaxf((tx - pos[s*3+0]) * 2.5f + 0.5f, 0.f), 1.f);
        float p1 = fminf(fmaxf((ty - pos[s*3+1]) * 2.5f + 0.5f, 0.f), 1.f);
        float p2 = fminf(fmaxf((tz - pos[s*3+2]) * 2.5f + 0.5f, 0.f), 1.f);
        float v0 = p0 * (KDIM - 1), v1 = p1 * (KDIM - 1), v2 = p2 * (KDIM - 1);
        int b0 = (int)floorf(v0), b1i = (int)floorf(v1), b2 = (int)floorf(v2);
        float f0 = v0 - (float)b0, f1 = v1 - (float)b1i, f2 = v2 - (float)b2;
        #pragma unroll
        for (int sb = 0; sb < 8; sb++) {
            int i0 = sb & 1, i1 = (sb >> 1) & 1, i2 = (sb >> 2) & 1;
            float w = (i0 ? f0 : 1.f - f0) * (i1 ? f1 : 1.f - f1) * (i2 ? f2 : 1.f - f2);
            int k0 = min(b0 + i0, KDIM - 1), k1 = min(b1i + i1, KDIM - 1), k2 = min(b2 + i2, KDIM - 1);
            int wi = k0 + KDIM * k1 + KDIM * KDIM * k2;
            atomicAdd(&A[wi], w);
        }
    }
    __syncthreads();
    if (t < 64) {
        float acc = 0.f;
        for (int k = 0; k < KC; k++) acc += A[k] * W[k * 64 + t];
        float deg = fmaxf((float)(re - rs), 1.f);
        float val = acc / deg + R[t] + b[t];
        xout[(size_t)node * 64 + t] = elu_f(val);
    }
}

// ---------------- Levels 2/3: Cin=64, Cout templated ----------------
template<int COUT>
__global__ void convN_kernel(const float* __restrict__ posL, const float* __restrict__ xin,
                             const int* __restrict__ src, const int* __restrict__ tgt, int E,
                             const float* __restrict__ W, const float* __restrict__ R,
                             const float* __restrict__ b, float rinv2, float* __restrict__ xout)
{
    constexpr int NG = 256 / COUT;        // 4 (COUT=64) or 2 (COUT=128) channel groups
    constexpr int CCH = 64 / NG;          // 16 or 32 input channels per group
    __shared__ float A[KC * 64];
    __shared__ float xt[64];
    __shared__ float partial[256];        // NG*COUT == 256
    __shared__ int rs_s, re_s;

    int node = blockIdx.x;
    int t = threadIdx.x;                  // blockDim = 256
    for (int i = t; i < KC * 64; i += 256) A[i] = 0.f;
    if (t == 0) { rs_s = lower_bound_i(tgt, E, node); re_s = lower_bound_i(tgt, E, node + 1); }
    if (t < 64) xt[t] = xin[(size_t)node * 64 + t];
    __syncthreads();
    int rs = rs_s, re = re_s;

    int c = t & 63, lane = t >> 6;        // wave 'lane' handles every 4th edge
    float tx = posL[node*3+0], ty = posL[node*3+1], tz = posL[node*3+2];
    for (int e = rs + lane; e < re; e += 4) {
        int s = src[e];
        float p0 = fminf(fmaxf((tx - posL[s*3+0]) * rinv2 + 0.5f, 0.f), 1.f);
        float p1 = fminf(fmaxf((ty - posL[s*3+1]) * rinv2 + 0.5f, 0.f), 1.f);
        float p2 = fminf(fmaxf((tz - posL[s*3+2]) * rinv2 + 0.5f, 0.f), 1.f);
        float v0 = p0 * (KDIM - 1), v1 = p1 * (KDIM - 1), v2 = p2 * (KDIM - 1);
        int b0 = (int)floorf(v0), b1i = (int)floorf(v1), b2 = (int)floorf(v2);
        float f0 = v0 - (float)b0, f1 = v1 - (float)b1i, f2 = v2 - (float)b2;
        float xj = xin[(size_t)s * 64 + c];
        #pragma unroll
        for (int sb = 0; sb < 8; sb++) {
            int i0 = sb & 1, i1 = (sb >> 1) & 1, i2 = (sb >> 2) & 1;
            float w = (i0 ? f0 : 1.f - f0) * (i1 ? f1 : 1.f - f1) * (i2 ? f2 : 1.f - f2);
            int k0 = min(b0 + i0, KDIM - 1), k1 = min(b1i + i1, KDIM - 1), k2 = min(b2 + i2, KDIM - 1);
            int wi = k0 + KDIM * k1 + KDIM * KDIM * k2;
            atomicAdd(&A[wi * 64 + c], w * xj);
        }
    }
    __syncthreads();

    // phase 2: msg[o] = sum_k sum_c A[k][c] * W[k][c][o]
    int o = t % COUT, g = t / COUT;
    float acc = 0.f;
    for (int k = 0; k < KC; k++) {
        const float* Wk = W + ((size_t)k * 64 + g * CCH) * COUT + o;
        const float* Ak = A + k * 64 + g * CCH;
        #pragma unroll
        for (int cc = 0; cc < CCH; cc++)
            acc += Ak[cc] * Wk[(size_t)cc * COUT];
    }
    partial[t] = acc;
    __syncthreads();
    if (g == 0) {
        #pragma unroll
        for (int gg = 1; gg < NG; gg++) acc += partial[gg * COUT + o];
        float deg = fmaxf((float)(re - rs), 1.f);
        float root = 0.f;
        for (int c2 = 0; c2 < 64; c2++) root += xt[c2] * R[c2 * COUT + o];
        float val = acc / deg + root + b[o];
        xout[(size_t)node * COUT + o] = elu_f(val);
    }
}

// ---------------- Gather x/pos by FPS indices ----------------
__global__ void gather_kernel(const float* __restrict__ x_src, const float* __restrict__ pos_src,
                              const int* __restrict__ idx, int n,
                              float* __restrict__ x_dst, float* __restrict__ pos_dst)
{
    int tid = blockIdx.x * blockDim.x + threadIdx.x;
    if (tid >= n * 64) return;
    int i = tid >> 6, c = tid & 63;
    int j = idx[i];
    x_dst[(size_t)i * 64 + c] = x_src[(size_t)j * 64 + c];
    if (c < 3) pos_dst[i * 3 + c] = pos_src[j * 3 + c];
}

__global__ void zero_kernel(float* __restrict__ p, int n)
{
    int i = blockIdx.x * blockDim.x + threadIdx.x;
    if (i < n) p[i] = 0.f;
}

// ---------------- Mean pool over clouds ----------------
__global__ void pool_kernel(const float* __restrict__ x3, const int* __restrict__ batch,
                            const int* __restrict__ idx1, const int* __restrict__ idx2, int n3,
                            float* __restrict__ gnum, float* __restrict__ cnt)
{
    int tid = blockIdx.x * blockDim.x + threadIdx.x;
    if (tid >= n3 * 128) return;
    int i = tid >> 7, c = tid & 127;
    int cloud = batch[idx1[idx2[i]]];
    atomicAdd(&gnum[cloud * 128 + c], x3[(size_t)i * 128 + c]);
    if (c == 0) atomicAdd(&cnt[cloud], 1.f);
}

// ---------------- Final MLP + log_softmax (one block per cloud) ----------------
__global__ void mlp_kernel(const float* __restrict__ gnum, const float* __restrict__ cnt,
                           const float* __restrict__ lw1, const float* __restrict__ lb1,
                           const float* __restrict__ lw2, const float* __restrict__ lb2,
                           const float* __restrict__ lw3, const float* __restrict__ lb3,
                           float* __restrict__ out)
{
    __shared__ float gv[128], h1[256], h2[256], lg[10];
    __shared__ float lse_s;
    int cl = blockIdx.x, t = threadIdx.x;   // blockDim = 256
    if (t < 128) gv[t] = gnum[cl * 128 + t] / fmaxf(cnt[cl], 1.f);
    __syncthreads();
    float a = lb1[t];
    for (int c = 0; c < 128; c++) a += gv[c] * lw1[c * 256 + t];
    h1[t] = elu_f(a);
    __syncthreads();
    a = lb2[t];
    for (int c = 0; c < 256; c++) a += h1[c] * lw2[c * 256 + t];
    h2[t] = elu_f(a);
    __syncthreads();
    if (t < 10) {
        a = lb3[t];
        for (int c = 0; c < 256; c++) a += h2[c] * lw3[c * 10 + t];
        lg[t] = a;
    }
    __syncthreads();
    if (t == 0) {
        float m = -1e30f;
        for (int i = 0; i < 10; i++) m = fmaxf(m, lg[i]);
        float s = 0.f;
        for (int i = 0; i < 10; i++) s += expf(lg[i] - m);
        lse_s = m + logf(s);
    }
    __syncthreads();
    if (t < 10) out[cl * 10 + t] = lg[t] - lse_s;
}

extern "C" void kernel_launch(void* const* d_in, const int* in_sizes, int n_in,
                              void* d_out, int out_size, void* d_ws, size_t ws_size,
                              hipStream_t stream)
{
    const float* pos   = (const float*)d_in[0];
    const int*   batch = (const int*)d_in[1];
    const int*   src1  = (const int*)d_in[2];
    const int*   tgt1  = (const int*)d_in[3];
    const int*   src2  = (const int*)d_in[4];
    const int*   tgt2  = (const int*)d_in[5];
    const int*   src3  = (const int*)d_in[6];
    const int*   tgt3  = (const int*)d_in[7];
    const int*   idx1  = (const int*)d_in[8];
    const int*   idx2  = (const int*)d_in[9];
    const float* W1 = (const float*)d_in[10];
    const float* R1 = (const float*)d_in[11];
    const float* b1 = (const float*)d_in[12];
    const float* W2 = (const float*)d_in[13];
    const float* R2 = (const float*)d_in[14];
    const float* b2 = (const float*)d_in[15];
    const float* W3 = (const float*)d_in[16];
    const float* R3 = (const float*)d_in[17];
    const float* b3 = (const float*)d_in[18];
    const float* lw1 = (const float*)d_in[19];
    const float* lb1 = (const float*)d_in[20];
    const float* lw2 = (const float*)d_in[21];
    const float* lb2 = (const float*)d_in[22];
    const float* lw3 = (const float*)d_in[23];
    const float* lb3 = (const float*)d_in[24];

    int n1 = in_sizes[0] / 3;
    int E1 = in_sizes[2];
    int E2 = in_sizes[4];
    int E3 = in_sizes[6];
    int n2 = in_sizes[8];
    int n3 = in_sizes[9];

    float* ws = (float*)d_ws;
    float* x1   = ws;                              // n1*64
    float* pos2 = x1   + (size_t)n1 * 64;          // n2*3
    float* x2in = pos2 + (size_t)n2 * 3;           // n2*64
    float* x2o  = x2in + (size_t)n2 * 64;          // n2*64
    float* pos3 = x2o  + (size_t)n2 * 64;          // n3*3
    float* x3in = pos3 + (size_t)n3 * 3;           // n3*64
    float* x3o  = x3in + (size_t)n3 * 64;          // n3*128
    float* gnum = x3o  + (size_t)n3 * 128;         // 16*128
    float* cnt  = gnum + 16 * 128;                 // 16

    float* out = (float*)d_out;

    // Level 1
    conv1_kernel<<<n1, 128, 0, stream>>>(pos, src1, tgt1, E1, W1, R1, b1, x1);
    // Subsample 1
    gather_kernel<<<(n2 * 64 + 255) / 256, 256, 0, stream>>>(x1, pos, idx1, n2, x2in, pos2);
    // Level 2
    convN_kernel<64><<<n2, 256, 0, stream>>>(pos2, x2in, src2, tgt2, E2, W2, R2, b2, 1.25f, x2o);
    // Subsample 2
    gather_kernel<<<(n3 * 64 + 255) / 256, 256, 0, stream>>>(x2o, pos2, idx2, n3, x3in, pos3);
    // Level 3
    convN_kernel<128><<<n3, 256, 0, stream>>>(pos3, x3in, src3, tgt3, E3, W3, R3, b3, 0.5f, x3o);
    // Pool (zero accumulators first: ws is poisoned)
    zero_kernel<<<(16 * 128 + 16 + 255) / 256, 256, 0, stream>>>(gnum, 16 * 128 + 16);
    pool_kernel<<<(n3 * 128 + 255) / 256, 256, 0, stream>>>(x3o, batch, idx1, idx2, n3, gnum, cnt);
    // MLP head
    mlp_kernel<<<16, 256, 0, stream>>>(gnum, cnt, lw1, lb1, lw2, lb2, lw3, lb3, out);
}

// Round 2
// 2759.562 us; speedup vs baseline: 1.1187x; 1.1187x over previous
//
#include <hip/hip_runtime.h>
#include <math.h>

#define KDIM 5
#define KC 125
#define KTOT 8064   // 125*64 spline rows + 64 root rows

__device__ __forceinline__ int lower_bound_i(const int* __restrict__ a, int n, int v) {
    int lo = 0, hi = n;
    while (lo < hi) { int m = (lo + hi) >> 1; if (a[m] < v) lo = m + 1; else hi = m; }
    return lo;
}

__device__ __forceinline__ float elu_f(float x) { return x > 0.f ? x : (expf(x) - 1.f); }

// ---------------- Level 1: Cin=1, Cout=64 (fused, cheap W) ----------------
__global__ void conv1_kernel(const float* __restrict__ pos,
                             const int* __restrict__ src, const int* __restrict__ tgt, int E,
                             const float* __restrict__ W, const float* __restrict__ R,
                             const float* __restrict__ b, float* __restrict__ xout)
{
    __shared__ float A[KC];
    __shared__ int rs_s, re_s;
    int node = blockIdx.x;
    int t = threadIdx.x;                      // blockDim = 128
    if (t < KC) A[t] = 0.f;
    if (t == 0) { rs_s = lower_bound_i(tgt, E, node); re_s = lower_bound_i(tgt, E, node + 1); }
    __syncthreads();
    int rs = rs_s, re = re_s;
    float tx = pos[node*3+0], ty = pos[node*3+1], tz = pos[node*3+2];
    for (int e = rs + t; e < re; e += blockDim.x) {
        int s = src[e];
        float p0 = fminf(fmaxf((tx - pos[s*3+0]) * 2.5f + 0.5f, 0.f), 1.f);
        float p1 = fminf(fmaxf((ty - pos[s*3+1]) * 2.5f + 0.5f, 0.f), 1.f);
        float p2 = fminf(fmaxf((tz - pos[s*3+2]) * 2.5f + 0.5f, 0.f), 1.f);
        float v0 = p0 * (KDIM - 1), v1 = p1 * (KDIM - 1), v2 = p2 * (KDIM - 1);
        int b0 = (int)floorf(v0), b1i = (int)floorf(v1), b2 = (int)floorf(v2);
        float f0 = v0 - (float)b0, f1 = v1 - (float)b1i, f2 = v2 - (float)b2;
        #pragma unroll
        for (int sb = 0; sb < 8; sb++) {
            int i0 = sb & 1, i1 = (sb >> 1) & 1, i2 = (sb >> 2) & 1;
            float w = (i0 ? f0 : 1.f - f0) * (i1 ? f1 : 1.f - f1) * (i2 ? f2 : 1.f - f2);
            int k0 = min(b0 + i0, KDIM - 1), k1 = min(b1i + i1, KDIM - 1), k2 = min(b2 + i2, KDIM - 1);
            int wi = k0 + KDIM * k1 + KDIM * KDIM * k2;
            atomicAdd(&A[wi], w);
        }
    }
    __syncthreads();
    if (t < 64) {
        float acc = 0.f;
        for (int k = 0; k < KC; k++) acc += A[k] * W[k * 64 + t];
        float deg = fmaxf((float)(re - rs), 1.f);
        float val = acc / deg + R[t] + b[t];
        xout[(size_t)node * 64 + t] = elu_f(val);
    }
}

// ---------------- buildA: accumulate spline basis * x_j into A rows ----------------
// Aout row layout per node (K=8064): [k*64+c] = A[k][c]/deg for k<125; [8000+c] = x[node][c]
__global__ void buildA_kernel(const float* __restrict__ posL, const float* __restrict__ xin,
                              const int* __restrict__ src, const int* __restrict__ tgt, int E,
                              float rinv2, int nodeBase, float* __restrict__ Aout)
{
    __shared__ float A[KC * 64];
    __shared__ int rs_s, re_s;
    int node = nodeBase + blockIdx.x;
    int t = threadIdx.x;                  // blockDim = 256
    for (int i = t; i < KC * 64; i += 256) A[i] = 0.f;
    if (t == 0) { rs_s = lower_bound_i(tgt, E, node); re_s = lower_bound_i(tgt, E, node + 1); }
    __syncthreads();
    int rs = rs_s, re = re_s;

    int c = t & 63, lane = t >> 6;        // 4 edge-lanes of 64 channels
    float tx = posL[node*3+0], ty = posL[node*3+1], tz = posL[node*3+2];
    for (int e = rs + lane; e < re; e += 4) {
        int s = src[e];
        float p0 = fminf(fmaxf((tx - posL[s*3+0]) * rinv2 + 0.5f, 0.f), 1.f);
        float p1 = fminf(fmaxf((ty - posL[s*3+1]) * rinv2 + 0.5f, 0.f), 1.f);
        float p2 = fminf(fmaxf((tz - posL[s*3+2]) * rinv2 + 0.5f, 0.f), 1.f);
        float v0 = p0 * (KDIM - 1), v1 = p1 * (KDIM - 1), v2 = p2 * (KDIM - 1);
        int b0 = (int)floorf(v0), b1i = (int)floorf(v1), b2 = (int)floorf(v2);
        float f0 = v0 - (float)b0, f1 = v1 - (float)b1i, f2 = v2 - (float)b2;
        float xj = xin[(size_t)s * 64 + c];
        #pragma unroll
        for (int sb = 0; sb < 8; sb++) {
            int i0 = sb & 1, i1 = (sb >> 1) & 1, i2 = (sb >> 2) & 1;
            float w = (i0 ? f0 : 1.f - f0) * (i1 ? f1 : 1.f - f1) * (i2 ? f2 : 1.f - f2);
            int k0 = min(b0 + i0, KDIM - 1), k1 = min(b1i + i1, KDIM - 1), k2 = min(b2 + i2, KDIM - 1);
            int wi = k0 + KDIM * k1 + KDIM * KDIM * k2;
            atomicAdd(&A[wi * 64 + c], w * xj);
        }
    }
    __syncthreads();
    float invdeg = 1.f / fmaxf((float)(re - rs), 1.f);
    float* out = Aout + (size_t)blockIdx.x * KTOT;
    for (int i = t; i < KC * 64; i += 256) out[i] = A[i] * invdeg;
    if (t < 64) out[KC * 64 + t] = xin[(size_t)node * 64 + t];
}

// ---------------- concat W (8000 x COUT) with R (64 x COUT) ----------------
__global__ void concatW_kernel(const float* __restrict__ W, const float* __restrict__ R,
                               int COUT, float* __restrict__ Wf)
{
    int i = blockIdx.x * blockDim.x + threadIdx.x;
    int total = KTOT * COUT;
    if (i >= total) return;
    int r = i / COUT, o = i - r * COUT;
    Wf[i] = (r < KC * 64) ? W[i] : R[(r - KC * 64) * COUT + o];
}

// ---------------- Tiled fp32 GEMM: P[z] = A[:, zslice] x Wf[zslice, ntile] ----------------
// TM=64, TN=64, 256 threads, 4x4 per thread, register-prefetch double buffering.
__global__ __launch_bounds__(256) void gemm_kernel(const float* __restrict__ A,
                                                   const float* __restrict__ Wf,
                                                   int Mrows, int COUT, int Ksz,
                                                   float* __restrict__ P)
{
    __shared__ float As[64][36];   // pad 36 keeps float4 alignment, breaks pow2 stride
    __shared__ float Ws[32][64];
    int tid = threadIdx.x;
    int mblk = blockIdx.x * 64;
    int nblk = blockIdx.y * 64;
    int kBase = blockIdx.z * Ksz;
    int tx = tid & 15, ty = tid >> 4;
    int am = tid >> 2, ak = (tid & 3) * 8;     // A loader: row am, 8 k's
    int wk = tid >> 3, wn = (tid & 7) * 8;     // W loader: k-row wk, 8 n's

    const float* Ap = A + (size_t)(mblk + am) * KTOT + kBase + ak;
    const float* Wp = Wf + (size_t)(kBase + wk) * COUT + nblk + wn;

    float4 a0 = *(const float4*)Ap;
    float4 a1 = *(const float4*)(Ap + 4);
    float4 w0 = *(const float4*)Wp;
    float4 w1 = *(const float4*)(Wp + 4);

    float acc[4][4] = {};
    int ktiles = Ksz >> 5;
    for (int kt = 0; kt < ktiles; kt++) {
        *(float4*)&As[am][ak]     = a0;
        *(float4*)&As[am][ak + 4] = a1;
        *(float4*)&Ws[wk][wn]     = w0;
        *(float4*)&Ws[wk][wn + 4] = w1;
        __syncthreads();
        if (kt + 1 < ktiles) {
            Ap += 32;
            Wp += (size_t)32 * COUT;
            a0 = *(const float4*)Ap;
            a1 = *(const float4*)(Ap + 4);
            w0 = *(const float4*)Wp;
            w1 = *(const float4*)(Wp + 4);
        }
        #pragma unroll
        for (int kk = 0; kk < 32; kk += 4) {
            float a4[4][4];
            #pragma unroll
            for (int i = 0; i < 4; i++)
                *(float4*)a4[i] = *(const float4*)&As[ty * 4 + i][kk];
            #pragma unroll
            for (int q = 0; q < 4; q++) {
                float4 wv = *(const float4*)&Ws[kk + q][tx * 4];
                #pragma unroll
                for (int i = 0; i < 4; i++) {
                    float av = a4[i][q];
                    acc[i][0] += av * wv.x;
                    acc[i][1] += av * wv.y;
                    acc[i][2] += av * wv.z;
                    acc[i][3] += av * wv.w;
                }
            }
        }
        __syncthreads();
    }
    float* Pz = P + (size_t)blockIdx.z * Mrows * COUT;
    #pragma unroll
    for (int i = 0; i < 4; i++) {
        int m = mblk + ty * 4 + i;
        float* row = Pz + (size_t)m * COUT + nblk + tx * 4;
        *(float4*)row = *(float4*)acc[i];
    }
}

// ---------------- combine K-split partials + bias + ELU ----------------
__global__ void combine_kernel(const float* __restrict__ P, const float* __restrict__ b,
                               int Mrows, int COUT, int NS, float* __restrict__ xout)
{
    int i = blockIdx.x * blockDim.x + threadIdx.x;
    int total = Mrows * COUT;
    if (i >= total) return;
    float s = 0.f;
    for (int z = 0; z < NS; z++) s += P[(size_t)z * total + i];
    int o = i % COUT;
    xout[i] = elu_f(s + b[o]);
}

// ---------------- Gather x/pos by FPS indices ----------------
__global__ void gather_kernel(const float* __restrict__ x_src, const float* __restrict__ pos_src,
                              const int* __restrict__ idx, int n,
                              float* __restrict__ x_dst, float* __restrict__ pos_dst)
{
    int tid = blockIdx.x * blockDim.x + threadIdx.x;
    if (tid >= n * 64) return;
    int i = tid >> 6, c = tid & 63;
    int j = idx[i];
    x_dst[(size_t)i * 64 + c] = x_src[(size_t)j * 64 + c];
    if (c < 3) pos_dst[i * 3 + c] = pos_src[j * 3 + c];
}

__global__ void zero_kernel(float* __restrict__ p, int n)
{
    int i = blockIdx.x * blockDim.x + threadIdx.x;
    if (i < n) p[i] = 0.f;
}

// ---------------- Mean pool over clouds ----------------
__global__ void pool_kernel(const float* __restrict__ x3, const int* __restrict__ batch,
                            const int* __restrict__ idx1, const int* __restrict__ idx2, int n3,
                            float* __restrict__ gnum, float* __restrict__ cnt)
{
    int tid = blockIdx.x * blockDim.x + threadIdx.x;
    if (tid >= n3 * 128) return;
    int i = tid >> 7, c = tid & 127;
    int cloud = batch[idx1[idx2[i]]];
    atomicAdd(&gnum[cloud * 128 + c], x3[(size_t)i * 128 + c]);
    if (c == 0) atomicAdd(&cnt[cloud], 1.f);
}

// ---------------- Final MLP + log_softmax ----------------
__global__ void mlp_kernel(const float* __restrict__ gnum, const float* __restrict__ cnt,
                           const float* __restrict__ lw1, const float* __restrict__ lb1,
                           const float* __restrict__ lw2, const float* __restrict__ lb2,
                           const float* __restrict__ lw3, const float* __restrict__ lb3,
                           float* __restrict__ out)
{
    __shared__ float gv[128], h1[256], h2[256], lg[10];
    __shared__ float lse_s;
    int cl = blockIdx.x, t = threadIdx.x;   // blockDim = 256
    if (t < 128) gv[t] = gnum[cl * 128 + t] / fmaxf(cnt[cl], 1.f);
    __syncthreads();
    float a = lb1[t];
    for (int c = 0; c < 128; c++) a += gv[c] * lw1[c * 256 + t];
    h1[t] = elu_f(a);
    __syncthreads();
    a = lb2[t];
    for (int c = 0; c < 256; c++) a += h1[c] * lw2[c * 256 + t];
    h2[t] = elu_f(a);
    __syncthreads();
    if (t < 10) {
        a = lb3[t];
        for (int c = 0; c < 256; c++) a += h2[c] * lw3[c * 10 + t];
        lg[t] = a;
    }
    __syncthreads();
    if (t == 0) {
        float m = -1e30f;
        for (int i = 0; i < 10; i++) m = fmaxf(m, lg[i]);
        float s = 0.f;
        for (int i = 0; i < 10; i++) s += expf(lg[i] - m);
        lse_s = m + logf(s);
    }
    __syncthreads();
    if (t < 10) out[cl * 10 + t] = lg[t] - lse_s;
}

static void run_level(const float* posL, const float* xin,
                      const int* src, const int* tgt, int E, float rinv2,
                      const float* Wf, const float* bvec, int n, int COUT, int NS,
                      float* Abuf, int AbufRows, float* P, float* xout, hipStream_t stream)
{
    int Ksz = KTOT / NS;
    for (int cs = 0; cs < n; cs += AbufRows) {
        int cr = min(AbufRows, n - cs);
        buildA_kernel<<<cr, 256, 0, stream>>>(posL, xin, src, tgt, E, rinv2, cs, Abuf);
        dim3 grid(cr / 64, COUT / 64, NS);
        gemm_kernel<<<grid, 256, 0, stream>>>(Abuf, Wf, cr, COUT, Ksz, P);
        combine_kernel<<<(cr * COUT + 255) / 256, 256, 0, stream>>>(P, bvec, cr, COUT, NS,
                                                                    xout + (size_t)cs * COUT);
    }
}

extern "C" void kernel_launch(void* const* d_in, const int* in_sizes, int n_in,
                              void* d_out, int out_size, void* d_ws, size_t ws_size,
                              hipStream_t stream)
{
    const float* pos   = (const float*)d_in[0];
    const int*   batch = (const int*)d_in[1];
    const int*   src1  = (const int*)d_in[2];
    const int*   tgt1  = (const int*)d_in[3];
    const int*   src2  = (const int*)d_in[4];
    const int*   tgt2  = (const int*)d_in[5];
    const int*   src3  = (const int*)d_in[6];
    const int*   tgt3  = (const int*)d_in[7];
    const int*   idx1  = (const int*)d_in[8];
    const int*   idx2  = (const int*)d_in[9];
    const float* W1 = (const float*)d_in[10];
    const float* R1 = (const float*)d_in[11];
    const float* b1 = (const float*)d_in[12];
    const float* W2 = (const float*)d_in[13];
    const float* R2 = (const float*)d_in[14];
    const float* b2 = (const float*)d_in[15];
    const float* W3 = (const float*)d_in[16];
    const float* R3 = (const float*)d_in[17];
    const float* b3 = (const float*)d_in[18];
    const float* lw1 = (const float*)d_in[19];
    const float* lb1 = (const float*)d_in[20];
    const float* lw2 = (const float*)d_in[21];
    const float* lb2 = (const float*)d_in[22];
    const float* lw3 = (const float*)d_in[23];
    const float* lb3 = (const float*)d_in[24];

    int n1 = in_sizes[0] / 3;
    int E1 = in_sizes[2];
    int E2 = in_sizes[4];
    int E3 = in_sizes[6];
    int n2 = in_sizes[8];
    int n3 = in_sizes[9];

    float* ws = (float*)d_ws;
    float* x1   = ws;                              // n1*64
    float* pos2 = x1   + (size_t)n1 * 64;          // n2*3
    float* x2in = pos2 + (size_t)n2 * 3;           // n2*64
    float* x2o  = x2in + (size_t)n2 * 64;          // n2*64
    float* pos3 = x2o  + (size_t)n2 * 64;          // n3*3
    float* x3in = pos3 + (size_t)n3 * 3;           // n3*64
    float* x3o  = x3in + (size_t)n3 * 64;          // n3*128
    float* gnum = x3o  + (size_t)n3 * 128;         // 16*128
    float* cnt  = gnum + 16 * 128;                 // 16
    float* Wf2  = cnt  + 16;                       // KTOT*64
    float* Wf3  = Wf2  + (size_t)KTOT * 64;        // KTOT*128
    float* P    = Wf3  + (size_t)KTOT * 128;       // NS*chunk*COUT partials (max 2M floats)
    float* Abuf = P    + (size_t)2 * 1024 * 1024;  // chunked A rows

    size_t usedFloats = (size_t)(Abuf - ws);
    size_t availFloats = ws_size / 4 > usedFloats ? ws_size / 4 - usedFloats : 0;
    int maxRows = (int)(availFloats / KTOT);
    maxRows &= ~63;                                // multiple of 64
    if (maxRows < 64) maxRows = 64;                // last-resort (ws too small anyway)
    int rows2 = maxRows < n2 ? maxRows : n2;
    int rows3 = maxRows < n3 ? maxRows : n3;

    float* out = (float*)d_out;

    // Level 1 (fused, W1 small)
    conv1_kernel<<<n1, 128, 0, stream>>>(pos, src1, tgt1, E1, W1, R1, b1, x1);
    gather_kernel<<<(n2 * 64 + 255) / 256, 256, 0, stream>>>(x1, pos, idx1, n2, x2in, pos2);

    // Precompute concatenated weights
    concatW_kernel<<<(KTOT * 64 + 255) / 256, 256, 0, stream>>>(W2, R2, 64, Wf2);
    concatW_kernel<<<(KTOT * 128 + 255) / 256, 256, 0, stream>>>(W3, R3, 128, Wf3);

    // Level 2: buildA + GEMM + combine (K-split 2 -> 512 blocks)
    run_level(pos2, x2in, src2, tgt2, E2, 1.25f, Wf2, b2, n2, 64, 2, Abuf, rows2, P, x2o, stream);

    gather_kernel<<<(n3 * 64 + 255) / 256, 256, 0, stream>>>(x2o, pos2, idx2, n3, x3in, pos3);

    // Level 3: (K-split 4 -> 512 blocks)
    run_level(pos3, x3in, src3, tgt3, E3, 0.5f, Wf3, b3, n3, 128, 4, Abuf, rows3, P, x3o, stream);

    // Pool + MLP head
    zero_kernel<<<(16 * 128 + 16 + 255) / 256, 256, 0, stream>>>(gnum, 16 * 128 + 16);
    pool_kernel<<<(n3 * 128 + 255) / 256, 256, 0, stream>>>(x3o, batch, idx1, idx2, n3, gnum, cnt);
    mlp_kernel<<<16, 256, 0, stream>>>(gnum, cnt, lw1, lb1, lw2, lb2, lw3, lb3, out);
}

// Round 3
// 2662.230 us; speedup vs baseline: 1.1596x; 1.0366x over previous
//
#include <hip/hip_runtime.h>
#include <math.h>

#define KDIM 5
#define KC 125
#define KTOT 8064   // 125*64 spline rows + 64 root rows

__device__ __forceinline__ int lower_bound_i(const int* __restrict__ a, int n, int v) {
    int lo = 0, hi = n;
    while (lo < hi) { int m = (lo + hi) >> 1; if (a[m] < v) lo = m + 1; else hi = m; }
    return lo;
}

__device__ __forceinline__ float elu_f(float x) { return x > 0.f ? x : (expf(x) - 1.f); }

// Native fp32 atomic add (ds_add_f32 / global_atomic_add_f32), no CAS loop.
__device__ __forceinline__ void fadd_atomic(float* p, float v) {
    unsafeAtomicAdd(p, v);
}

// ---------------- Level 1: Cin=1, Cout=64 (fused, cheap W) ----------------
__global__ void conv1_kernel(const float* __restrict__ pos,
                             const int* __restrict__ src, const int* __restrict__ tgt, int E,
                             const float* __restrict__ W, const float* __restrict__ R,
                             const float* __restrict__ b, float* __restrict__ xout)
{
    __shared__ float A[KC];
    __shared__ int rs_s, re_s;
    int node = blockIdx.x;
    int t = threadIdx.x;                      // blockDim = 128
    if (t < KC) A[t] = 0.f;
    if (t == 0) { rs_s = lower_bound_i(tgt, E, node); re_s = lower_bound_i(tgt, E, node + 1); }
    __syncthreads();
    int rs = rs_s, re = re_s;
    float tx = pos[node*3+0], ty = pos[node*3+1], tz = pos[node*3+2];
    for (int e = rs + t; e < re; e += blockDim.x) {
        int s = src[e];
        float p0 = fminf(fmaxf((tx - pos[s*3+0]) * 2.5f + 0.5f, 0.f), 1.f);
        float p1 = fminf(fmaxf((ty - pos[s*3+1]) * 2.5f + 0.5f, 0.f), 1.f);
        float p2 = fminf(fmaxf((tz - pos[s*3+2]) * 2.5f + 0.5f, 0.f), 1.f);
        float v0 = p0 * (KDIM - 1), v1 = p1 * (KDIM - 1), v2 = p2 * (KDIM - 1);
        int b0 = (int)floorf(v0), b1i = (int)floorf(v1), b2 = (int)floorf(v2);
        float f0 = v0 - (float)b0, f1 = v1 - (float)b1i, f2 = v2 - (float)b2;
        #pragma unroll
        for (int sb = 0; sb < 8; sb++) {
            int i0 = sb & 1, i1 = (sb >> 1) & 1, i2 = (sb >> 2) & 1;
            float w = (i0 ? f0 : 1.f - f0) * (i1 ? f1 : 1.f - f1) * (i2 ? f2 : 1.f - f2);
            int k0 = min(b0 + i0, KDIM - 1), k1 = min(b1i + i1, KDIM - 1), k2 = min(b2 + i2, KDIM - 1);
            int wi = k0 + KDIM * k1 + KDIM * KDIM * k2;
            fadd_atomic(&A[wi], w);
        }
    }
    __syncthreads();
    if (t < 64) {
        float acc = 0.f;
        for (int k = 0; k < KC; k++) acc += A[k] * W[k * 64 + t];
        float deg = fmaxf((float)(re - rs), 1.f);
        float val = acc / deg + R[t] + b[t];
        xout[(size_t)node * 64 + t] = elu_f(val);
    }
}

// ---------------- buildA: accumulate spline basis * x_j into A rows ----------------
// Aout row layout per node (K=8064): [k*64+c] = A[k][c]/deg for k<125; [8000+c] = x[node][c]
__global__ void buildA_kernel(const float* __restrict__ posL, const float* __restrict__ xin,
                              const int* __restrict__ src, const int* __restrict__ tgt, int E,
                              float rinv2, int nodeBase, float* __restrict__ Aout)
{
    __shared__ float A[KC * 64];              // 8000 floats = 2000 float4
    __shared__ int rs_s, re_s;
    int node = nodeBase + blockIdx.x;
    int t = threadIdx.x;                  // blockDim = 256
    for (int i = t; i < KC * 16; i += 256) ((float4*)A)[i] = make_float4(0.f, 0.f, 0.f, 0.f);
    if (t == 0) { rs_s = lower_bound_i(tgt, E, node); re_s = lower_bound_i(tgt, E, node + 1); }
    __syncthreads();
    int rs = rs_s, re = re_s;

    int c = t & 63, lane = t >> 6;        // 4 edge-lanes of 64 channels
    float tx = posL[node*3+0], ty = posL[node*3+1], tz = posL[node*3+2];
    for (int e = rs + lane; e < re; e += 4) {
        int s = src[e];
        float p0 = fminf(fmaxf((tx - posL[s*3+0]) * rinv2 + 0.5f, 0.f), 1.f);
        float p1 = fminf(fmaxf((ty - posL[s*3+1]) * rinv2 + 0.5f, 0.f), 1.f);
        float p2 = fminf(fmaxf((tz - posL[s*3+2]) * rinv2 + 0.5f, 0.f), 1.f);
        float v0 = p0 * (KDIM - 1), v1 = p1 * (KDIM - 1), v2 = p2 * (KDIM - 1);
        int b0 = (int)floorf(v0), b1i = (int)floorf(v1), b2 = (int)floorf(v2);
        float f0 = v0 - (float)b0, f1 = v1 - (float)b1i, f2 = v2 - (float)b2;
        float xj = xin[(size_t)s * 64 + c];
        #pragma unroll
        for (int sb = 0; sb < 8; sb++) {
            int i0 = sb & 1, i1 = (sb >> 1) & 1, i2 = (sb >> 2) & 1;
            float w = (i0 ? f0 : 1.f - f0) * (i1 ? f1 : 1.f - f1) * (i2 ? f2 : 1.f - f2);
            int k0 = min(b0 + i0, KDIM - 1), k1 = min(b1i + i1, KDIM - 1), k2 = min(b2 + i2, KDIM - 1);
            int wi = k0 + KDIM * k1 + KDIM * KDIM * k2;
            fadd_atomic(&A[wi * 64 + c], w * xj);
        }
    }
    __syncthreads();
    float invdeg = 1.f / fmaxf((float)(re - rs), 1.f);
    float* out = Aout + (size_t)blockIdx.x * KTOT;
    for (int i = t; i < KC * 16; i += 256) {
        float4 v = ((const float4*)A)[i];
        v.x *= invdeg; v.y *= invdeg; v.z *= invdeg; v.w *= invdeg;
        ((float4*)out)[i] = v;
    }
    if (t < 64) out[KC * 64 + t] = xin[(size_t)node * 64 + t];
}

// ---------------- concat W (8000 x COUT) with R (64 x COUT) ----------------
__global__ void concatW_kernel(const float* __restrict__ W, const float* __restrict__ R,
                               int COUT, float* __restrict__ Wf)
{
    int i = blockIdx.x * blockDim.x + threadIdx.x;
    int total = KTOT * COUT;
    if (i >= total) return;
    int r = i / COUT, o = i - r * COUT;
    Wf[i] = (r < KC * 64) ? W[i] : R[(r - KC * 64) * COUT + o];
}

// ---------------- Tiled fp32 GEMM: P[z] = A[:, zslice] x Wf[zslice, ntile] ----------------
__global__ __launch_bounds__(256) void gemm_kernel(const float* __restrict__ A,
                                                   const float* __restrict__ Wf,
                                                   int Mrows, int COUT, int Ksz,
                                                   float* __restrict__ P)
{
    __shared__ float As[64][36];
    __shared__ float Ws[32][64];
    int tid = threadIdx.x;
    int mblk = blockIdx.x * 64;
    int nblk = blockIdx.y * 64;
    int kBase = blockIdx.z * Ksz;
    int tx = tid & 15, ty = tid >> 4;
    int am = tid >> 2, ak = (tid & 3) * 8;
    int wk = tid >> 3, wn = (tid & 7) * 8;

    const float* Ap = A + (size_t)(mblk + am) * KTOT + kBase + ak;
    const float* Wp = Wf + (size_t)(kBase + wk) * COUT + nblk + wn;

    float4 a0 = *(const float4*)Ap;
    float4 a1 = *(const float4*)(Ap + 4);
    float4 w0 = *(const float4*)Wp;
    float4 w1 = *(const float4*)(Wp + 4);

    float acc[4][4] = {};
    int ktiles = Ksz >> 5;
    for (int kt = 0; kt < ktiles; kt++) {
        *(float4*)&As[am][ak]     = a0;
        *(float4*)&As[am][ak + 4] = a1;
        *(float4*)&Ws[wk][wn]     = w0;
        *(float4*)&Ws[wk][wn + 4] = w1;
        __syncthreads();
        if (kt + 1 < ktiles) {
            Ap += 32;
            Wp += (size_t)32 * COUT;
            a0 = *(const float4*)Ap;
            a1 = *(const float4*)(Ap + 4);
            w0 = *(const float4*)Wp;
            w1 = *(const float4*)(Wp + 4);
        }
        #pragma unroll
        for (int kk = 0; kk < 32; kk += 4) {
            float a4[4][4];
            #pragma unroll
            for (int i = 0; i < 4; i++)
                *(float4*)a4[i] = *(const float4*)&As[ty * 4 + i][kk];
            #pragma unroll
            for (int q = 0; q < 4; q++) {
                float4 wv = *(const float4*)&Ws[kk + q][tx * 4];
                #pragma unroll
                for (int i = 0; i < 4; i++) {
                    float av = a4[i][q];
                    acc[i][0] += av * wv.x;
                    acc[i][1] += av * wv.y;
                    acc[i][2] += av * wv.z;
                    acc[i][3] += av * wv.w;
                }
            }
        }
        __syncthreads();
    }
    float* Pz = P + (size_t)blockIdx.z * Mrows * COUT;
    #pragma unroll
    for (int i = 0; i < 4; i++) {
        int m = mblk + ty * 4 + i;
        float* row = Pz + (size_t)m * COUT + nblk + tx * 4;
        *(float4*)row = *(float4*)acc[i];
    }
}

// ---------------- combine K-split partials + bias + ELU ----------------
__global__ void combine_kernel(const float* __restrict__ P, const float* __restrict__ b,
                               int Mrows, int COUT, int NS, float* __restrict__ xout)
{
    int i = blockIdx.x * blockDim.x + threadIdx.x;
    int total = Mrows * COUT;
    if (i >= total) return;
    float s = 0.f;
    for (int z = 0; z < NS; z++) s += P[(size_t)z * total + i];
    int o = i % COUT;
    xout[i] = elu_f(s + b[o]);
}

// ---------------- Gather x/pos by FPS indices ----------------
__global__ void gather_kernel(const float* __restrict__ x_src, const float* __restrict__ pos_src,
                              const int* __restrict__ idx, int n,
                              float* __restrict__ x_dst, float* __restrict__ pos_dst)
{
    int tid = blockIdx.x * blockDim.x + threadIdx.x;
    if (tid >= n * 64) return;
    int i = tid >> 6, c = tid & 63;
    int j = idx[i];
    x_dst[(size_t)i * 64 + c] = x_src[(size_t)j * 64 + c];
    if (c < 3) pos_dst[i * 3 + c] = pos_src[j * 3 + c];
}

__global__ void zero_kernel(float* __restrict__ p, int n)
{
    int i = blockIdx.x * blockDim.x + threadIdx.x;
    if (i < n) p[i] = 0.f;
}

// ---------------- Mean pool over clouds ----------------
__global__ void pool_kernel(const float* __restrict__ x3, const int* __restrict__ batch,
                            const int* __restrict__ idx1, const int* __restrict__ idx2, int n3,
                            float* __restrict__ gnum, float* __restrict__ cnt)
{
    int tid = blockIdx.x * blockDim.x + threadIdx.x;
    if (tid >= n3 * 128) return;
    int i = tid >> 7, c = tid & 127;
    int cloud = batch[idx1[idx2[i]]];
    fadd_atomic(&gnum[cloud * 128 + c], x3[(size_t)i * 128 + c]);
    if (c == 0) fadd_atomic(&cnt[cloud], 1.f);
}

// ---------------- Final MLP + log_softmax ----------------
__global__ void mlp_kernel(const float* __restrict__ gnum, const float* __restrict__ cnt,
                           const float* __restrict__ lw1, const float* __restrict__ lb1,
                           const float* __restrict__ lw2, const float* __restrict__ lb2,
                           const float* __restrict__ lw3, const float* __restrict__ lb3,
                           float* __restrict__ out)
{
    __shared__ float gv[128], h1[256], h2[256], lg[10];
    __shared__ float lse_s;
    int cl = blockIdx.x, t = threadIdx.x;   // blockDim = 256
    if (t < 128) gv[t] = gnum[cl * 128 + t] / fmaxf(cnt[cl], 1.f);
    __syncthreads();
    float a = lb1[t];
    for (int c = 0; c < 128; c++) a += gv[c] * lw1[c * 256 + t];
    h1[t] = elu_f(a);
    __syncthreads();
    a = lb2[t];
    for (int c = 0; c < 256; c++) a += h1[c] * lw2[c * 256 + t];
    h2[t] = elu_f(a);
    __syncthreads();
    if (t < 10) {
        a = lb3[t];
        for (int c = 0; c < 256; c++) a += h2[c] * lw3[c * 10 + t];
        lg[t] = a;
    }
    __syncthreads();
    if (t == 0) {
        float m = -1e30f;
        for (int i = 0; i < 10; i++) m = fmaxf(m, lg[i]);
        float s = 0.f;
        for (int i = 0; i < 10; i++) s += expf(lg[i] - m);
        lse_s = m + logf(s);
    }
    __syncthreads();
    if (t < 10) out[cl * 10 + t] = lg[t] - lse_s;
}

static void run_level(const float* posL, const float* xin,
                      const int* src, const int* tgt, int E, float rinv2,
                      const float* Wf, const float* bvec, int n, int COUT, int NS,
                      float* Abuf, int AbufRows, float* P, float* xout, hipStream_t stream)
{
    int Ksz = KTOT / NS;
    for (int cs = 0; cs < n; cs += AbufRows) {
        int cr = min(AbufRows, n - cs);
        buildA_kernel<<<cr, 256, 0, stream>>>(posL, xin, src, tgt, E, rinv2, cs, Abuf);
        dim3 grid(cr / 64, COUT / 64, NS);
        gemm_kernel<<<grid, 256, 0, stream>>>(Abuf, Wf, cr, COUT, Ksz, P);
        combine_kernel<<<(cr * COUT + 255) / 256, 256, 0, stream>>>(P, bvec, cr, COUT, NS,
                                                                    xout + (size_t)cs * COUT);
    }
}

extern "C" void kernel_launch(void* const* d_in, const int* in_sizes, int n_in,
                              void* d_out, int out_size, void* d_ws, size_t ws_size,
                              hipStream_t stream)
{
    const float* pos   = (const float*)d_in[0];
    const int*   batch = (const int*)d_in[1];
    const int*   src1  = (const int*)d_in[2];
    const int*   tgt1  = (const int*)d_in[3];
    const int*   src2  = (const int*)d_in[4];
    const int*   tgt2  = (const int*)d_in[5];
    const int*   src3  = (const int*)d_in[6];
    const int*   tgt3  = (const int*)d_in[7];
    const int*   idx1  = (const int*)d_in[8];
    const int*   idx2  = (const int*)d_in[9];
    const float* W1 = (const float*)d_in[10];
    const float* R1 = (const float*)d_in[11];
    const float* b1 = (const float*)d_in[12];
    const float* W2 = (const float*)d_in[13];
    const float* R2 = (const float*)d_in[14];
    const float* b2 = (const float*)d_in[15];
    const float* W3 = (const float*)d_in[16];
    const float* R3 = (const float*)d_in[17];
    const float* b3 = (const float*)d_in[18];
    const float* lw1 = (const float*)d_in[19];
    const float* lb1 = (const float*)d_in[20];
    const float* lw2 = (const float*)d_in[21];
    const float* lb2 = (const float*)d_in[22];
    const float* lw3 = (const float*)d_in[23];
    const float* lb3 = (const float*)d_in[24];

    int n1 = in_sizes[0] / 3;
    int E1 = in_sizes[2];
    int E2 = in_sizes[4];
    int E3 = in_sizes[6];
    int n2 = in_sizes[8];
    int n3 = in_sizes[9];

    float* ws = (float*)d_ws;
    float* x1   = ws;                              // n1*64
    float* pos2 = x1   + (size_t)n1 * 64;          // n2*3
    float* x2in = pos2 + (size_t)n2 * 3;           // n2*64
    float* x2o  = x2in + (size_t)n2 * 64;          // n2*64
    float* pos3 = x2o  + (size_t)n2 * 64;          // n3*3
    float* x3in = pos3 + (size_t)n3 * 3;           // n3*64
    float* x3o  = x3in + (size_t)n3 * 64;          // n3*128
    float* gnum = x3o  + (size_t)n3 * 128;         // 16*128
    float* cnt  = gnum + 16 * 128;                 // 16
    float* Wf2  = cnt  + 16;                       // KTOT*64
    float* Wf3  = Wf2  + (size_t)KTOT * 64;        // KTOT*128
    float* P    = Wf3  + (size_t)KTOT * 128;       // NS*chunk*COUT partials
    float* Abuf = P    + (size_t)2 * 1024 * 1024;  // chunked A rows

    size_t usedFloats = (size_t)(Abuf - ws);
    size_t availFloats = ws_size / 4 > usedFloats ? ws_size / 4 - usedFloats : 0;
    int maxRows = (int)(availFloats / KTOT);
    maxRows &= ~63;
    if (maxRows < 64) maxRows = 64;
    int rows2 = maxRows < n2 ? maxRows : n2;
    int rows3 = maxRows < n3 ? maxRows : n3;

    float* out = (float*)d_out;

    conv1_kernel<<<n1, 128, 0, stream>>>(pos, src1, tgt1, E1, W1, R1, b1, x1);
    gather_kernel<<<(n2 * 64 + 255) / 256, 256, 0, stream>>>(x1, pos, idx1, n2, x2in, pos2);

    concatW_kernel<<<(KTOT * 64 + 255) / 256, 256, 0, stream>>>(W2, R2, 64, Wf2);
    concatW_kernel<<<(KTOT * 128 + 255) / 256, 256, 0, stream>>>(W3, R3, 128, Wf3);

    run_level(pos2, x2in, src2, tgt2, E2, 1.25f, Wf2, b2, n2, 64, 2, Abuf, rows2, P, x2o, stream);

    gather_kernel<<<(n3 * 64 + 255) / 256, 256, 0, stream>>>(x2o, pos2, idx2, n3, x3in, pos3);

    run_level(pos3, x3in, src3, tgt3, E3, 0.5f, Wf3, b3, n3, 128, 4, Abuf, rows3, P, x3o, stream);

    zero_kernel<<<(16 * 128 + 16 + 255) / 256, 256, 0, stream>>>(gnum, 16 * 128 + 16);
    pool_kernel<<<(n3 * 128 + 255) / 256, 256, 0, stream>>>(x3o, batch, idx1, idx2, n3, gnum, cnt);
    mlp_kernel<<<16, 256, 0, stream>>>(gnum, cnt, lw1, lb1, lw2, lb2, lw3, lb3, out);
}

// Round 4
// 2562.260 us; speedup vs baseline: 1.2049x; 1.0390x over previous
//
#include <hip/hip_runtime.h>
#include <math.h>

#define KDIM 5
#define KC 125
#define KTOT 8064   // 125*64 spline rows + 64 root rows

__device__ __forceinline__ float elu_f(float x) { return x > 0.f ? x : (expf(x) - 1.f); }

__device__ __forceinline__ void fadd_atomic(float* p, float v) {
    unsafeAtomicAdd(p, v);
}

// ---------------- rowptr: tgt is sorted; rowptr[v] = first edge with tgt >= v ----------------
__global__ void rowptr_kernel(const int* __restrict__ tgt, int E, int n, int* __restrict__ rowptr)
{
    int e = blockIdx.x * blockDim.x + threadIdx.x;
    if (e > E) return;
    if (e < E) {
        int t = tgt[e];
        int p = (e == 0) ? -1 : tgt[e - 1];
        for (int v = p + 1; v <= t; v++) rowptr[v] = e;
    } else {
        int p = tgt[E - 1];
        for (int v = p + 1; v <= n; v++) rowptr[v] = E;
    }
}

// ---------------- edge records: fracs + packed (b0,b1,b2,src) ----------------
// bits = b0 | b1<<3 | b2<<6 | src<<9   (b in 0..4; src < 2^22)
__global__ void edgerec_kernel(const float* __restrict__ posL, const int* __restrict__ src,
                               const int* __restrict__ tgt, int E, float rinv2,
                               float4* __restrict__ rec)
{
    int e = blockIdx.x * blockDim.x + threadIdx.x;
    if (e >= E) return;
    int s = src[e], t = tgt[e];
    float p0 = fminf(fmaxf((posL[t*3+0] - posL[s*3+0]) * rinv2 + 0.5f, 0.f), 1.f);
    float p1 = fminf(fmaxf((posL[t*3+1] - posL[s*3+1]) * rinv2 + 0.5f, 0.f), 1.f);
    float p2 = fminf(fmaxf((posL[t*3+2] - posL[s*3+2]) * rinv2 + 0.5f, 0.f), 1.f);
    float v0 = p0 * (KDIM - 1), v1 = p1 * (KDIM - 1), v2 = p2 * (KDIM - 1);
    int b0 = (int)floorf(v0), b1 = (int)floorf(v1), b2 = (int)floorf(v2);
    unsigned int bits = (unsigned int)b0 | ((unsigned int)b1 << 3) | ((unsigned int)b2 << 6)
                      | ((unsigned int)s << 9);
    rec[e] = make_float4(v0 - (float)b0, v1 - (float)b1, v2 - (float)b2, __uint_as_float(bits));
}

// ---------------- Level 1: Cin=1, Cout=64 ----------------
__global__ void conv1_kernel(const float4* __restrict__ rec, const int* __restrict__ rowptr,
                             const float* __restrict__ W, const float* __restrict__ R,
                             const float* __restrict__ b, float* __restrict__ xout)
{
    __shared__ float A[KC];
    int node = blockIdx.x;
    int t = threadIdx.x;                      // blockDim = 128
    if (t < KC) A[t] = 0.f;
    int rs = rowptr[node], re = rowptr[node + 1];
    __syncthreads();
    for (int e = rs + t; e < re; e += 128) {
        float4 rc = rec[e];
        unsigned int bits = __float_as_uint(rc.w);
        int b0 = bits & 7, b1i = (bits >> 3) & 7, b2 = (bits >> 6) & 7;
        float f0 = rc.x, f1 = rc.y, f2 = rc.z;
        #pragma unroll
        for (int sb = 0; sb < 8; sb++) {
            int i0 = sb & 1, i1 = (sb >> 1) & 1, i2 = (sb >> 2) & 1;
            float w = (i0 ? f0 : 1.f - f0) * (i1 ? f1 : 1.f - f1) * (i2 ? f2 : 1.f - f2);
            int k0 = min(b0 + i0, KDIM - 1), k1 = min(b1i + i1, KDIM - 1), k2 = min(b2 + i2, KDIM - 1);
            int wi = k0 + KDIM * k1 + KDIM * KDIM * k2;
            fadd_atomic(&A[wi], w);
        }
    }
    __syncthreads();
    if (t < 64) {
        float acc = 0.f;
        for (int k = 0; k < KC; k++) acc += A[k] * W[k * 64 + t];
        float deg = fmaxf((float)(re - rs), 1.f);
        float val = acc / deg + R[t] + b[t];
        xout[(size_t)node * 64 + t] = elu_f(val);
    }
}

// ---------------- buildA: accumulate spline basis * x_j into A rows ----------------
__global__ void buildA_kernel(const float4* __restrict__ rec, const int* __restrict__ rowptr,
                              const float* __restrict__ xin, int nodeBase,
                              float* __restrict__ Aout)
{
    __shared__ float A[KC * 64];              // 8000 floats
    int node = nodeBase + blockIdx.x;
    int t = threadIdx.x;                      // blockDim = 256
    for (int i = t; i < KC * 16; i += 256) ((float4*)A)[i] = make_float4(0.f, 0.f, 0.f, 0.f);
    int rs = rowptr[node], re = rowptr[node + 1];
    __syncthreads();

    int c = t & 63, lane = t >> 6;            // 4 edge-lanes of 64 channels
    int e = rs + lane;
    float4 rc; float xj;
    if (e < re) {
        rc = rec[e];
        xj = xin[(size_t)(__float_as_uint(rc.w) >> 9) * 64 + c];
    }
    while (e < re) {
        int en = e + 4;
        float4 rcn; float xjn;
        if (en < re) rcn = rec[en];           // prefetch next record
        unsigned int bits = __float_as_uint(rc.w);
        int b0 = bits & 7, b1i = (bits >> 3) & 7, b2 = (bits >> 6) & 7;
        float f0 = rc.x, f1 = rc.y, f2 = rc.z;
        if (en < re) xjn = xin[(size_t)(__float_as_uint(rcn.w) >> 9) * 64 + c]; // prefetch gather
        #pragma unroll
        for (int sb = 0; sb < 8; sb++) {
            int i0 = sb & 1, i1 = (sb >> 1) & 1, i2 = (sb >> 2) & 1;
            float w = (i0 ? f0 : 1.f - f0) * (i1 ? f1 : 1.f - f1) * (i2 ? f2 : 1.f - f2);
            int k0 = min(b0 + i0, KDIM - 1), k1 = min(b1i + i1, KDIM - 1), k2 = min(b2 + i2, KDIM - 1);
            int wi = k0 + KDIM * k1 + KDIM * KDIM * k2;
            fadd_atomic(&A[wi * 64 + c], w * xj);
        }
        e = en; rc = rcn; xj = xjn;
    }
    __syncthreads();
    float invdeg = 1.f / fmaxf((float)(re - rs), 1.f);
    float* out = Aout + (size_t)blockIdx.x * KTOT;
    for (int i = t; i < KC * 16; i += 256) {
        float4 v = ((const float4*)A)[i];
        v.x *= invdeg; v.y *= invdeg; v.z *= invdeg; v.w *= invdeg;
        ((float4*)out)[i] = v;
    }
    if (t < 64) out[KC * 64 + t] = xin[(size_t)node * 64 + t];
}

// ---------------- concat W (8000 x COUT) with R (64 x COUT) ----------------
__global__ void concatW_kernel(const float* __restrict__ W, const float* __restrict__ R,
                               int COUT, float* __restrict__ Wf)
{
    int i = blockIdx.x * blockDim.x + threadIdx.x;
    int total = KTOT * COUT;
    if (i >= total) return;
    int r = i / COUT, o = i - r * COUT;
    Wf[i] = (r < KC * 64) ? W[i] : R[(r - KC * 64) * COUT + o];
}

// ---------------- Tiled fp32 GEMM ----------------
__global__ __launch_bounds__(256) void gemm_kernel(const float* __restrict__ A,
                                                   const float* __restrict__ Wf,
                                                   int Mrows, int COUT, int Ksz,
                                                   float* __restrict__ P)
{
    __shared__ float As[64][36];
    __shared__ float Ws[32][64];
    int tid = threadIdx.x;
    int mblk = blockIdx.x * 64;
    int nblk = blockIdx.y * 64;
    int kBase = blockIdx.z * Ksz;
    int tx = tid & 15, ty = tid >> 4;
    int am = tid >> 2, ak = (tid & 3) * 8;
    int wk = tid >> 3, wn = (tid & 7) * 8;

    const float* Ap = A + (size_t)(mblk + am) * KTOT + kBase + ak;
    const float* Wp = Wf + (size_t)(kBase + wk) * COUT + nblk + wn;

    float4 a0 = *(const float4*)Ap;
    float4 a1 = *(const float4*)(Ap + 4);
    float4 w0 = *(const float4*)Wp;
    float4 w1 = *(const float4*)(Wp + 4);

    float acc[4][4] = {};
    int ktiles = Ksz >> 5;
    for (int kt = 0; kt < ktiles; kt++) {
        *(float4*)&As[am][ak]     = a0;
        *(float4*)&As[am][ak + 4] = a1;
        *(float4*)&Ws[wk][wn]     = w0;
        *(float4*)&Ws[wk][wn + 4] = w1;
        __syncthreads();
        if (kt + 1 < ktiles) {
            Ap += 32;
            Wp += (size_t)32 * COUT;
            a0 = *(const float4*)Ap;
            a1 = *(const float4*)(Ap + 4);
            w0 = *(const float4*)Wp;
            w1 = *(const float4*)(Wp + 4);
        }
        #pragma unroll
        for (int kk = 0; kk < 32; kk += 4) {
            float a4[4][4];
            #pragma unroll
            for (int i = 0; i < 4; i++)
                *(float4*)a4[i] = *(const float4*)&As[ty * 4 + i][kk];
            #pragma unroll
            for (int q = 0; q < 4; q++) {
                float4 wv = *(const float4*)&Ws[kk + q][tx * 4];
                #pragma unroll
                for (int i = 0; i < 4; i++) {
                    float av = a4[i][q];
                    acc[i][0] += av * wv.x;
                    acc[i][1] += av * wv.y;
                    acc[i][2] += av * wv.z;
                    acc[i][3] += av * wv.w;
                }
            }
        }
        __syncthreads();
    }
    float* Pz = P + (size_t)blockIdx.z * Mrows * COUT;
    #pragma unroll
    for (int i = 0; i < 4; i++) {
        int m = mblk + ty * 4 + i;
        float* row = Pz + (size_t)m * COUT + nblk + tx * 4;
        *(float4*)row = *(float4*)acc[i];
    }
}

// ---------------- combine K-split partials + bias + ELU ----------------
__global__ void combine_kernel(const float* __restrict__ P, const float* __restrict__ b,
                               int Mrows, int COUT, int NS, float* __restrict__ xout)
{
    int i = blockIdx.x * blockDim.x + threadIdx.x;
    int total = Mrows * COUT;
    if (i >= total) return;
    float s = 0.f;
    for (int z = 0; z < NS; z++) s += P[(size_t)z * total + i];
    int o = i % COUT;
    xout[i] = elu_f(s + b[o]);
}

// ---------------- gathers ----------------
__global__ void xgather_kernel(const float* __restrict__ x_src, const int* __restrict__ idx,
                               int n, float* __restrict__ x_dst)
{
    int tid = blockIdx.x * blockDim.x + threadIdx.x;
    if (tid >= n * 64) return;
    int i = tid >> 6, c = tid & 63;
    x_dst[(size_t)i * 64 + c] = x_src[(size_t)idx[i] * 64 + c];
}

__global__ void posgather_kernel(const float* __restrict__ pos_src, const int* __restrict__ idx,
                                 int n, float* __restrict__ pos_dst)
{
    int tid = blockIdx.x * blockDim.x + threadIdx.x;
    if (tid >= n * 3) return;
    int i = tid / 3, d = tid - i * 3;
    pos_dst[tid] = pos_src[idx[i] * 3 + d];
}

__global__ void zero_kernel(float* __restrict__ p, int n)
{
    int i = blockIdx.x * blockDim.x + threadIdx.x;
    if (i < n) p[i] = 0.f;
}

// ---------------- Mean pool over clouds ----------------
__global__ void pool_kernel(const float* __restrict__ x3, const int* __restrict__ batch,
                            const int* __restrict__ idx1, const int* __restrict__ idx2, int n3,
                            float* __restrict__ gnum, float* __restrict__ cnt)
{
    int tid = blockIdx.x * blockDim.x + threadIdx.x;
    if (tid >= n3 * 128) return;
    int i = tid >> 7, c = tid & 127;
    int cloud = batch[idx1[idx2[i]]];
    fadd_atomic(&gnum[cloud * 128 + c], x3[(size_t)i * 128 + c]);
    if (c == 0) fadd_atomic(&cnt[cloud], 1.f);
}

// ---------------- Final MLP + log_softmax ----------------
__global__ void mlp_kernel(const float* __restrict__ gnum, const float* __restrict__ cnt,
                           const float* __restrict__ lw1, const float* __restrict__ lb1,
                           const float* __restrict__ lw2, const float* __restrict__ lb2,
                           const float* __restrict__ lw3, const float* __restrict__ lb3,
                           float* __restrict__ out)
{
    __shared__ float gv[128], h1[256], h2[256], lg[10];
    __shared__ float lse_s;
    int cl = blockIdx.x, t = threadIdx.x;   // blockDim = 256
    if (t < 128) gv[t] = gnum[cl * 128 + t] / fmaxf(cnt[cl], 1.f);
    __syncthreads();
    float a = lb1[t];
    for (int c = 0; c < 128; c++) a += gv[c] * lw1[c * 256 + t];
    h1[t] = elu_f(a);
    __syncthreads();
    a = lb2[t];
    for (int c = 0; c < 256; c++) a += h1[c] * lw2[c * 256 + t];
    h2[t] = elu_f(a);
    __syncthreads();
    if (t < 10) {
        a = lb3[t];
        for (int c = 0; c < 256; c++) a += h2[c] * lw3[c * 10 + t];
        lg[t] = a;
    }
    __syncthreads();
    if (t == 0) {
        float m = -1e30f;
        for (int i = 0; i < 10; i++) m = fmaxf(m, lg[i]);
        float s = 0.f;
        for (int i = 0; i < 10; i++) s += expf(lg[i] - m);
        lse_s = m + logf(s);
    }
    __syncthreads();
    if (t < 10) out[cl * 10 + t] = lg[t] - lse_s;
}

static void run_level(const float4* rec, const int* rowptr, const float* xin,
                      const float* Wf, const float* bvec, int n, int COUT, int NS,
                      float* Abuf, int AbufRows, float* P, float* xout, hipStream_t stream)
{
    int Ksz = KTOT / NS;
    for (int cs = 0; cs < n; cs += AbufRows) {
        int cr = min(AbufRows, n - cs);
        buildA_kernel<<<cr, 256, 0, stream>>>(rec, rowptr, xin, cs, Abuf);
        dim3 grid(cr / 64, COUT / 64, NS);
        gemm_kernel<<<grid, 256, 0, stream>>>(Abuf, Wf, cr, COUT, Ksz, P);
        combine_kernel<<<(cr * COUT + 255) / 256, 256, 0, stream>>>(P, bvec, cr, COUT, NS,
                                                                    xout + (size_t)cs * COUT);
    }
}

extern "C" void kernel_launch(void* const* d_in, const int* in_sizes, int n_in,
                              void* d_out, int out_size, void* d_ws, size_t ws_size,
                              hipStream_t stream)
{
    const float* pos   = (const float*)d_in[0];
    const int*   batch = (const int*)d_in[1];
    const int*   src1  = (const int*)d_in[2];
    const int*   tgt1  = (const int*)d_in[3];
    const int*   src2  = (const int*)d_in[4];
    const int*   tgt2  = (const int*)d_in[5];
    const int*   src3  = (const int*)d_in[6];
    const int*   tgt3  = (const int*)d_in[7];
    const int*   idx1  = (const int*)d_in[8];
    const int*   idx2  = (const int*)d_in[9];
    const float* W1 = (const float*)d_in[10];
    const float* R1 = (const float*)d_in[11];
    const float* b1 = (const float*)d_in[12];
    const float* W2 = (const float*)d_in[13];
    const float* R2 = (const float*)d_in[14];
    const float* b2 = (const float*)d_in[15];
    const float* W3 = (const float*)d_in[16];
    const float* R3 = (const float*)d_in[17];
    const float* b3 = (const float*)d_in[18];
    const float* lw1 = (const float*)d_in[19];
    const float* lb1 = (const float*)d_in[20];
    const float* lw2 = (const float*)d_in[21];
    const float* lb2 = (const float*)d_in[22];
    const float* lw3 = (const float*)d_in[23];
    const float* lb3 = (const float*)d_in[24];

    int n1 = in_sizes[0] / 3;
    int E1 = in_sizes[2];
    int E2 = in_sizes[4];
    int E3 = in_sizes[6];
    int n2 = in_sizes[8];
    int n3 = in_sizes[9];

    float* ws = (float*)d_ws;
    float* x1   = ws;                               // n1*64
    float* x2in = x1   + (size_t)n1 * 64;           // n2*64
    float* x2o  = x2in + (size_t)n2 * 64;           // n2*64
    float* x3in = x2o  + (size_t)n2 * 64;           // n3*64
    float* x3o  = x3in + (size_t)n3 * 64;           // n3*128
    float* pos2 = x3o  + (size_t)n3 * 128;          // n2*3
    float* pos3 = pos2 + (size_t)n2 * 3;            // n3*3
    float* gnum = pos3 + (size_t)n3 * 3;            // 16*128
    float* cnt  = gnum + 16 * 128;                  // 16
    float* Wf2  = cnt  + 16;                        // KTOT*64
    float* Wf3  = Wf2  + (size_t)KTOT * 64;         // KTOT*128
    int*   rp1  = (int*)(Wf3 + (size_t)KTOT * 128); // n1+1 (padded to mult-of-4)
    int*   rp2  = rp1 + ((n1 + 4) & ~3);
    int*   rp3  = rp2 + ((n2 + 4) & ~3);
    float4* rec1 = (float4*)(rp3 + ((n3 + 4) & ~3));
    float4* rec2 = rec1 + E1;
    float4* rec3 = rec2 + E2;
    float*  P    = (float*)(rec3 + E3);             // 2M floats
    float*  Abuf = P + (size_t)2 * 1024 * 1024;

    size_t usedFloats = (size_t)(Abuf - ws);
    size_t availFloats = ws_size / 4 > usedFloats ? ws_size / 4 - usedFloats : 0;
    int maxRows = (int)(availFloats / KTOT);
    maxRows &= ~63;
    if (maxRows < 64) maxRows = 64;
    int rows2 = maxRows < n2 ? maxRows : n2;
    int rows3 = maxRows < n3 ? maxRows : n3;

    float* out = (float*)d_out;

    // --- graph preprocessing (all independent of features) ---
    rowptr_kernel<<<(E1 + 256) / 256, 256, 0, stream>>>(tgt1, E1, n1, rp1);
    rowptr_kernel<<<(E2 + 256) / 256, 256, 0, stream>>>(tgt2, E2, n2, rp2);
    rowptr_kernel<<<(E3 + 256) / 256, 256, 0, stream>>>(tgt3, E3, n3, rp3);
    posgather_kernel<<<(n2 * 3 + 255) / 256, 256, 0, stream>>>(pos, idx1, n2, pos2);
    posgather_kernel<<<(n3 * 3 + 255) / 256, 256, 0, stream>>>(pos2, idx2, n3, pos3);
    edgerec_kernel<<<(E1 + 255) / 256, 256, 0, stream>>>(pos,  src1, tgt1, E1, 2.5f,  rec1);
    edgerec_kernel<<<(E2 + 255) / 256, 256, 0, stream>>>(pos2, src2, tgt2, E2, 1.25f, rec2);
    edgerec_kernel<<<(E3 + 255) / 256, 256, 0, stream>>>(pos3, src3, tgt3, E3, 0.5f,  rec3);
    concatW_kernel<<<(KTOT * 64 + 255) / 256, 256, 0, stream>>>(W2, R2, 64, Wf2);
    concatW_kernel<<<(KTOT * 128 + 255) / 256, 256, 0, stream>>>(W3, R3, 128, Wf3);

    // --- level 1 ---
    conv1_kernel<<<n1, 128, 0, stream>>>(rec1, rp1, W1, R1, b1, x1);
    xgather_kernel<<<(n2 * 64 + 255) / 256, 256, 0, stream>>>(x1, idx1, n2, x2in);

    // --- level 2 ---
    run_level(rec2, rp2, x2in, Wf2, b2, n2, 64, 2, Abuf, rows2, P, x2o, stream);
    xgather_kernel<<<(n3 * 64 + 255) / 256, 256, 0, stream>>>(x2o, idx2, n3, x3in);

    // --- level 3 ---
    run_level(rec3, rp3, x3in, Wf3, b3, n3, 128, 4, Abuf, rows3, P, x3o, stream);

    // --- pool + head ---
    zero_kernel<<<(16 * 128 + 16 + 255) / 256, 256, 0, stream>>>(gnum, 16 * 128 + 16);
    pool_kernel<<<(n3 * 128 + 255) / 256, 256, 0, stream>>>(x3o, batch, idx1, idx2, n3, gnum, cnt);
    mlp_kernel<<<16, 256, 0, stream>>>(gnum, cnt, lw1, lb1, lw2, lb2, lw3, lb3, out);
}

// Round 6
// 1079.395 us; speedup vs baseline: 2.8602x; 2.3738x over previous
//
#include <hip/hip_runtime.h>
#include <math.h>

#define KDIM 5
#define KC 125
#define KTOT 8064   // 125*64 spline rows + 64 root rows
#define EPB 32      // edges staged per tile (max_nb = 32)

__device__ __forceinline__ float elu_f(float x) { return x > 0.f ? x : (expf(x) - 1.f); }

__device__ __forceinline__ void fadd_atomic(float* p, float v) {
    unsafeAtomicAdd(p, v);
}

// ---------------- rowptr: tgt is sorted; rowptr[v] = first edge with tgt >= v ----------------
__global__ void rowptr_kernel(const int* __restrict__ tgt, int E, int n, int* __restrict__ rowptr)
{
    int e = blockIdx.x * blockDim.x + threadIdx.x;
    if (e > E) return;
    if (e < E) {
        int t = tgt[e];
        int p = (e == 0) ? -1 : tgt[e - 1];
        for (int v = p + 1; v <= t; v++) rowptr[v] = e;
    } else {
        int p = tgt[E - 1];
        for (int v = p + 1; v <= n; v++) rowptr[v] = E;
    }
}

// ---------------- edge records: fracs + packed (b0,b1,b2,src) ----------------
// bits = b0 | b1<<3 | b2<<6 | src<<9   (b in 0..4; src < 2^22)
__global__ void edgerec_kernel(const float* __restrict__ posL, const int* __restrict__ src,
                               const int* __restrict__ tgt, int E, float rinv2,
                               float4* __restrict__ rec)
{
    int e = blockIdx.x * blockDim.x + threadIdx.x;
    if (e >= E) return;
    int s = src[e], t = tgt[e];
    float p0 = fminf(fmaxf((posL[t*3+0] - posL[s*3+0]) * rinv2 + 0.5f, 0.f), 1.f);
    float p1 = fminf(fmaxf((posL[t*3+1] - posL[s*3+1]) * rinv2 + 0.5f, 0.f), 1.f);
    float p2 = fminf(fmaxf((posL[t*3+2] - posL[s*3+2]) * rinv2 + 0.5f, 0.f), 1.f);
    float v0 = p0 * (KDIM - 1), v1 = p1 * (KDIM - 1), v2 = p2 * (KDIM - 1);
    int b0 = (int)floorf(v0), b1 = (int)floorf(v1), b2 = (int)floorf(v2);
    unsigned int bits = (unsigned int)b0 | ((unsigned int)b1 << 3) | ((unsigned int)b2 << 6)
                      | ((unsigned int)s << 9);
    rec[e] = make_float4(v0 - (float)b0, v1 - (float)b1, v2 - (float)b2, __uint_as_float(bits));
}

// ---------------- Level 1: Cin=1, Cout=64 (per-wave private histograms) ----------------
__global__ void conv1_kernel(const float4* __restrict__ rec, const int* __restrict__ rowptr,
                             const float* __restrict__ W, const float* __restrict__ R,
                             const float* __restrict__ b, float* __restrict__ xout)
{
    __shared__ float A2[2][KC];               // one histogram per wave
    int node = blockIdx.x;
    int t = threadIdx.x;                      // blockDim = 128
    for (int i = t; i < 2 * KC; i += 128) A2[0][i] = 0.f;   // FIX: full zero-init
    int rs = rowptr[node], re = rowptr[node + 1];
    int wv = t >> 6;
    __syncthreads();
    for (int e = rs + t; e < re; e += 128) {
        float4 rc = rec[e];
        unsigned int bits = __float_as_uint(rc.w);
        int b0 = bits & 7, b1i = (bits >> 3) & 7, b2 = (bits >> 6) & 7;
        float f0 = rc.x, f1 = rc.y, f2 = rc.z;
        #pragma unroll
        for (int sb = 0; sb < 8; sb++) {
            int i0 = sb & 1, i1 = (sb >> 1) & 1, i2 = (sb >> 2) & 1;
            float w = (i0 ? f0 : 1.f - f0) * (i1 ? f1 : 1.f - f1) * (i2 ? f2 : 1.f - f2);
            int k0 = min(b0 + i0, KDIM - 1), k1 = min(b1i + i1, KDIM - 1), k2 = min(b2 + i2, KDIM - 1);
            int wi = k0 + KDIM * k1 + KDIM * KDIM * k2;
            unsafeAtomicAdd(&A2[wv][wi], w);
        }
    }
    __syncthreads();
    if (t < 64) {
        float acc = 0.f;
        for (int k = 0; k < KC; k++) acc += (A2[0][k] + A2[1][k]) * W[k * 64 + t];
        float deg = fmaxf((float)(re - rs), 1.f);
        float val = acc / deg + R[t] + b[t];
        xout[(size_t)node * 64 + t] = elu_f(val);
    }
}

// ---------------- buildA: atomic-free LDS accumulation ----------------
// Wave w owns channels [16w, 16w+16). Lanes = 4 slot-groups x 16 channels.
// Clamp-alias slots have weight exactly 0 and are redirected to dummy row 125.
__global__ __launch_bounds__(256) void buildA_kernel(
    const float4* __restrict__ rec, const int* __restrict__ rowptr,
    const float* __restrict__ xin, int nodeBase, float* __restrict__ Aout)
{
    __shared__ float A[(KC + 1) * 64];        // 126 rows; row 125 = dummy sink
    __shared__ float Xs[EPB * 64];            // staged x_j rows
    __shared__ float4 recs[EPB];              // staged edge records
    int node = nodeBase + blockIdx.x;
    int t = threadIdx.x;                      // blockDim = 256
    for (int i = t; i < (KC + 1) * 16; i += 256)
        ((float4*)A)[i] = make_float4(0.f, 0.f, 0.f, 0.f);
    int rs = rowptr[node], re = rowptr[node + 1];

    int wave = t >> 6, lane = t & 63;
    int sgrp = lane >> 4;                     // slot group 0..3
    int c = wave * 16 + (lane & 15);          // owned channel
    int i0 = sgrp & 1, i1 = sgrp >> 1;

    for (int ts = rs; ts < re; ts += EPB) {
        int ne = min(EPB, re - ts);
        __syncthreads();                      // protect recs/Xs reuse across tiles
        if (t < ne) recs[t] = rec[ts + t];
        __syncthreads();
        for (int i = t; i < ne * 64; i += 256) {
            int el = i >> 6, cc = i & 63;
            unsigned int sj = __float_as_uint(recs[el].w) >> 9;
            Xs[i] = xin[(size_t)sj * 64 + cc];
        }
        __syncthreads();
        for (int et = 0; et < ne; et++) {
            float4 rc = recs[et];             // LDS broadcast
            unsigned int bits = __float_as_uint(rc.w);
            int b0 = bits & 7, b1i = (bits >> 3) & 7, b2 = (bits >> 6) & 7;
            float f0 = rc.x, f1 = rc.y, f2 = rc.z;
            float xj = Xs[et * 64 + c];
            float wa = (i0 ? f0 : 1.f - f0) * (i1 ? f1 : 1.f - f1);
            int k0 = min(b0 + i0, KDIM - 1), k1 = min(b1i + i1, KDIM - 1);
            int kbase = k0 + KDIM * k1;
            #pragma unroll
            for (int i2 = 0; i2 < 2; i2++) {
                float w = wa * (i2 ? f2 : 1.f - f2);
                int k2 = min(b2 + i2, KDIM - 1);
                int wi = kbase + KDIM * KDIM * k2;
                wi = (w == 0.f) ? KC : wi;    // redirect exact-zero (alias-risk) slots
                int addr = wi * 64 + c;
                A[addr] += w * xj;            // non-atomic: cell has a unique writer
            }
        }
    }
    __syncthreads();
    float invdeg = 1.f / fmaxf((float)(re - rs), 1.f);
    float* out = Aout + (size_t)blockIdx.x * KTOT;
    for (int i = t; i < KC * 16; i += 256) {  // skip dummy row
        float4 v = ((const float4*)A)[i];
        v.x *= invdeg; v.y *= invdeg; v.z *= invdeg; v.w *= invdeg;
        ((float4*)out)[i] = v;
    }
    if (t < 64) out[KC * 64 + t] = xin[(size_t)node * 64 + t];
}

// ---------------- concat W (8000 x COUT) with R (64 x COUT) ----------------
__global__ void concatW_kernel(const float* __restrict__ W, const float* __restrict__ R,
                               int COUT, float* __restrict__ Wf)
{
    int i = blockIdx.x * blockDim.x + threadIdx.x;
    int total = KTOT * COUT;
    if (i >= total) return;
    int r = i / COUT, o = i - r * COUT;
    Wf[i] = (r < KC * 64) ? W[i] : R[(r - KC * 64) * COUT + o];
}

// ---------------- Tiled fp32 GEMM ----------------
__global__ __launch_bounds__(256) void gemm_kernel(const float* __restrict__ A,
                                                   const float* __restrict__ Wf,
                                                   int Mrows, int COUT, int Ksz,
                                                   float* __restrict__ P)
{
    __shared__ float As[64][36];
    __shared__ float Ws[32][64];
    int tid = threadIdx.x;
    int mblk = blockIdx.x * 64;
    int nblk = blockIdx.y * 64;
    int kBase = blockIdx.z * Ksz;
    int tx = tid & 15, ty = tid >> 4;
    int am = tid >> 2, ak = (tid & 3) * 8;
    int wk = tid >> 3, wn = (tid & 7) * 8;

    const float* Ap = A + (size_t)(mblk + am) * KTOT + kBase + ak;
    const float* Wp = Wf + (size_t)(kBase + wk) * COUT + nblk + wn;

    float4 a0 = *(const float4*)Ap;
    float4 a1 = *(const float4*)(Ap + 4);
    float4 w0 = *(const float4*)Wp;
    float4 w1 = *(const float4*)(Wp + 4);

    float acc[4][4] = {};
    int ktiles = Ksz >> 5;
    for (int kt = 0; kt < ktiles; kt++) {
        *(float4*)&As[am][ak]     = a0;
        *(float4*)&As[am][ak + 4] = a1;
        *(float4*)&Ws[wk][wn]     = w0;
        *(float4*)&Ws[wk][wn + 4] = w1;
        __syncthreads();
        if (kt + 1 < ktiles) {
            Ap += 32;
            Wp += (size_t)32 * COUT;
            a0 = *(const float4*)Ap;
            a1 = *(const float4*)(Ap + 4);
            w0 = *(const float4*)Wp;
            w1 = *(const float4*)(Wp + 4);
        }
        #pragma unroll
        for (int kk = 0; kk < 32; kk += 4) {
            float a4[4][4];
            #pragma unroll
            for (int i = 0; i < 4; i++)
                *(float4*)a4[i] = *(const float4*)&As[ty * 4 + i][kk];
            #pragma unroll
            for (int q = 0; q < 4; q++) {
                float4 wv = *(const float4*)&Ws[kk + q][tx * 4];
                #pragma unroll
                for (int i = 0; i < 4; i++) {
                    float av = a4[i][q];
                    acc[i][0] += av * wv.x;
                    acc[i][1] += av * wv.y;
                    acc[i][2] += av * wv.z;
                    acc[i][3] += av * wv.w;
                }
            }
        }
        __syncthreads();
    }
    float* Pz = P + (size_t)blockIdx.z * Mrows * COUT;
    #pragma unroll
    for (int i = 0; i < 4; i++) {
        int m = mblk + ty * 4 + i;
        float* row = Pz + (size_t)m * COUT + nblk + tx * 4;
        *(float4*)row = *(float4*)acc[i];
    }
}

// ---------------- combine K-split partials + bias + ELU ----------------
__global__ void combine_kernel(const float* __restrict__ P, const float* __restrict__ b,
                               int Mrows, int COUT, int NS, float* __restrict__ xout)
{
    int i = blockIdx.x * blockDim.x + threadIdx.x;
    int total = Mrows * COUT;
    if (i >= total) return;
    float s = 0.f;
    for (int z = 0; z < NS; z++) s += P[(size_t)z * total + i];
    int o = i % COUT;
    xout[i] = elu_f(s + b[o]);
}

// ---------------- gathers ----------------
__global__ void xgather_kernel(const float* __restrict__ x_src, const int* __restrict__ idx,
                               int n, float* __restrict__ x_dst)
{
    int tid = blockIdx.x * blockDim.x + threadIdx.x;
    if (tid >= n * 64) return;
    int i = tid >> 6, c = tid & 63;
    x_dst[(size_t)i * 64 + c] = x_src[(size_t)idx[i] * 64 + c];
}

__global__ void posgather_kernel(const float* __restrict__ pos_src, const int* __restrict__ idx,
                                 int n, float* __restrict__ pos_dst)
{
    int tid = blockIdx.x * blockDim.x + threadIdx.x;
    if (tid >= n * 3) return;
    int i = tid / 3, d = tid - i * 3;
    pos_dst[tid] = pos_src[idx[i] * 3 + d];
}

__global__ void zero_kernel(float* __restrict__ p, int n)
{
    int i = blockIdx.x * blockDim.x + threadIdx.x;
    if (i < n) p[i] = 0.f;
}

// ---------------- Mean pool over clouds ----------------
__global__ void pool_kernel(const float* __restrict__ x3, const int* __restrict__ batch,
                            const int* __restrict__ idx1, const int* __restrict__ idx2, int n3,
                            float* __restrict__ gnum, float* __restrict__ cnt)
{
    int tid = blockIdx.x * blockDim.x + threadIdx.x;
    if (tid >= n3 * 128) return;
    int i = tid >> 7, c = tid & 127;
    int cloud = batch[idx1[idx2[i]]];
    fadd_atomic(&gnum[cloud * 128 + c], x3[(size_t)i * 128 + c]);
    if (c == 0) fadd_atomic(&cnt[cloud], 1.f);
}

// ---------------- Final MLP + log_softmax ----------------
__global__ void mlp_kernel(const float* __restrict__ gnum, const float* __restrict__ cnt,
                           const float* __restrict__ lw1, const float* __restrict__ lb1,
                           const float* __restrict__ lw2, const float* __restrict__ lb2,
                           const float* __restrict__ lw3, const float* __restrict__ lb3,
                           float* __restrict__ out)
{
    __shared__ float gv[128], h1[256], h2[256], lg[10];
    __shared__ float lse_s;
    int cl = blockIdx.x, t = threadIdx.x;   // blockDim = 256
    if (t < 128) gv[t] = gnum[cl * 128 + t] / fmaxf(cnt[cl], 1.f);
    __syncthreads();
    float a = lb1[t];
    for (int c = 0; c < 128; c++) a += gv[c] * lw1[c * 256 + t];
    h1[t] = elu_f(a);
    __syncthreads();
    a = lb2[t];
    for (int c = 0; c < 256; c++) a += h1[c] * lw2[c * 256 + t];
    h2[t] = elu_f(a);
    __syncthreads();
    if (t < 10) {
        a = lb3[t];
        for (int c = 0; c < 256; c++) a += h2[c] * lw3[c * 10 + t];
        lg[t] = a;
    }
    __syncthreads();
    if (t == 0) {
        float m = -1e30f;
        for (int i = 0; i < 10; i++) m = fmaxf(m, lg[i]);
        float s = 0.f;
        for (int i = 0; i < 10; i++) s += expf(lg[i] - m);
        lse_s = m + logf(s);
    }
    __syncthreads();
    if (t < 10) out[cl * 10 + t] = lg[t] - lse_s;
}

static void run_level(const float4* rec, const int* rowptr, const float* xin,
                      const float* Wf, const float* bvec, int n, int COUT, int NS,
                      float* Abuf, int AbufRows, float* P, float* xout, hipStream_t stream)
{
    int Ksz = KTOT / NS;
    for (int cs = 0; cs < n; cs += AbufRows) {
        int cr = min(AbufRows, n - cs);
        buildA_kernel<<<cr, 256, 0, stream>>>(rec, rowptr, xin, cs, Abuf);
        dim3 grid(cr / 64, COUT / 64, NS);
        gemm_kernel<<<grid, 256, 0, stream>>>(Abuf, Wf, cr, COUT, Ksz, P);
        combine_kernel<<<(cr * COUT + 255) / 256, 256, 0, stream>>>(P, bvec, cr, COUT, NS,
                                                                    xout + (size_t)cs * COUT);
    }
}

extern "C" void kernel_launch(void* const* d_in, const int* in_sizes, int n_in,
                              void* d_out, int out_size, void* d_ws, size_t ws_size,
                              hipStream_t stream)
{
    const float* pos   = (const float*)d_in[0];
    const int*   batch = (const int*)d_in[1];
    const int*   src1  = (const int*)d_in[2];
    const int*   tgt1  = (const int*)d_in[3];
    const int*   src2  = (const int*)d_in[4];
    const int*   tgt2  = (const int*)d_in[5];
    const int*   src3  = (const int*)d_in[6];
    const int*   tgt3  = (const int*)d_in[7];
    const int*   idx1  = (const int*)d_in[8];
    const int*   idx2  = (const int*)d_in[9];
    const float* W1 = (const float*)d_in[10];
    const float* R1 = (const float*)d_in[11];
    const float* b1 = (const float*)d_in[12];
    const float* W2 = (const float*)d_in[13];
    const float* R2 = (const float*)d_in[14];
    const float* b2 = (const float*)d_in[15];
    const float* W3 = (const float*)d_in[16];
    const float* R3 = (const float*)d_in[17];
    const float* b3 = (const float*)d_in[18];
    const float* lw1 = (const float*)d_in[19];
    const float* lb1 = (const float*)d_in[20];
    const float* lw2 = (const float*)d_in[21];
    const float* lb2 = (const float*)d_in[22];
    const float* lw3 = (const float*)d_in[23];
    const float* lb3 = (const float*)d_in[24];

    int n1 = in_sizes[0] / 3;
    int E1 = in_sizes[2];
    int E2 = in_sizes[4];
    int E3 = in_sizes[6];
    int n2 = in_sizes[8];
    int n3 = in_sizes[9];

    float* ws = (float*)d_ws;
    float* x1   = ws;                               // n1*64
    float* x2in = x1   + (size_t)n1 * 64;           // n2*64
    float* x2o  = x2in + (size_t)n2 * 64;           // n2*64
    float* x3in = x2o  + (size_t)n2 * 64;           // n3*64
    float* x3o  = x3in + (size_t)n3 * 64;           // n3*128
    float* pos2 = x3o  + (size_t)n3 * 128;          // n2*3
    float* pos3 = pos2 + (size_t)n2 * 3;            // n3*3
    float* gnum = pos3 + (size_t)n3 * 3;            // 16*128
    float* cnt  = gnum + 16 * 128;                  // 16
    float* Wf2  = cnt  + 16;                        // KTOT*64
    float* Wf3  = Wf2  + (size_t)KTOT * 64;         // KTOT*128
    int*   rp1  = (int*)(Wf3 + (size_t)KTOT * 128); // n1+1 (padded)
    int*   rp2  = rp1 + ((n1 + 4) & ~3);
    int*   rp3  = rp2 + ((n2 + 4) & ~3);
    float4* rec1 = (float4*)(rp3 + ((n3 + 4) & ~3));
    float4* rec2 = rec1 + E1;
    float4* rec3 = rec2 + E2;
    float*  P    = (float*)(rec3 + E3);             // 2M floats
    float*  Abuf = P + (size_t)2 * 1024 * 1024;

    size_t usedFloats = (size_t)(Abuf - ws);
    size_t availFloats = ws_size / 4 > usedFloats ? ws_size / 4 - usedFloats : 0;
    int maxRows = (int)(availFloats / KTOT);
    maxRows &= ~63;
    if (maxRows < 64) maxRows = 64;
    int rows2 = maxRows < n2 ? maxRows : n2;
    int rows3 = maxRows < n3 ? maxRows : n3;

    float* out = (float*)d_out;

    // --- graph preprocessing ---
    rowptr_kernel<<<(E1 + 256) / 256, 256, 0, stream>>>(tgt1, E1, n1, rp1);
    rowptr_kernel<<<(E2 + 256) / 256, 256, 0, stream>>>(tgt2, E2, n2, rp2);
    rowptr_kernel<<<(E3 + 256) / 256, 256, 0, stream>>>(tgt3, E3, n3, rp3);
    posgather_kernel<<<(n2 * 3 + 255) / 256, 256, 0, stream>>>(pos, idx1, n2, pos2);
    posgather_kernel<<<(n3 * 3 + 255) / 256, 256, 0, stream>>>(pos2, idx2, n3, pos3);
    edgerec_kernel<<<(E1 + 255) / 256, 256, 0, stream>>>(pos,  src1, tgt1, E1, 2.5f,  rec1);
    edgerec_kernel<<<(E2 + 255) / 256, 256, 0, stream>>>(pos2, src2, tgt2, E2, 1.25f, rec2);
    edgerec_kernel<<<(E3 + 255) / 256, 256, 0, stream>>>(pos3, src3, tgt3, E3, 0.5f,  rec3);
    concatW_kernel<<<(KTOT * 64 + 255) / 256, 256, 0, stream>>>(W2, R2, 64, Wf2);
    concatW_kernel<<<(KTOT * 128 + 255) / 256, 256, 0, stream>>>(W3, R3, 128, Wf3);

    // --- level 1 ---
    conv1_kernel<<<n1, 128, 0, stream>>>(rec1, rp1, W1, R1, b1, x1);
    xgather_kernel<<<(n2 * 64 + 255) / 256, 256, 0, stream>>>(x1, idx1, n2, x2in);

    // --- level 2 ---
    run_level(rec2, rp2, x2in, Wf2, b2, n2, 64, 2, Abuf, rows2, P, x2o, stream);
    xgather_kernel<<<(n3 * 64 + 255) / 256, 256, 0, stream>>>(x2o, idx2, n3, x3in);

    // --- level 3 ---
    run_level(rec3, rp3, x3in, Wf3, b3, n3, 128, 4, Abuf, rows3, P, x3o, stream);

    // --- pool + head ---
    zero_kernel<<<(16 * 128 + 16 + 255) / 256, 256, 0, stream>>>(gnum, 16 * 128 + 16);
    pool_kernel<<<(n3 * 128 + 255) / 256, 256, 0, stream>>>(x3o, batch, idx1, idx2, n3, gnum, cnt);
    mlp_kernel<<<16, 256, 0, stream>>>(gnum, cnt, lw1, lb1, lw2, lb2, lw3, lb3, out);
}

// Round 7
// 614.246 us; speedup vs baseline: 5.0261x; 1.7573x over previous
//
#include <hip/hip_runtime.h>
#include <math.h>

#define KDIM 5
#define KC 125
#define KPAD 8192   // 125*64 spline rows + 64 root rows + 128 zero pad
#define EPB 32      // edges staged per tile (max_nb = 32)
#define NSPLIT 8    // GEMM K-split
#define LDA 72      // LDS tile row stride in bf16 (64 + 8 pad)

typedef short bf16x8 __attribute__((ext_vector_type(8)));
typedef float f32x4 __attribute__((ext_vector_type(4)));

__device__ __forceinline__ float elu_f(float x) { return x > 0.f ? x : (expf(x) - 1.f); }

__device__ __forceinline__ void fadd_atomic(float* p, float v) {
    unsafeAtomicAdd(p, v);
}

__device__ __forceinline__ unsigned short f2bf(float x) {
    union { float f; unsigned u; } v; v.f = x;
    unsigned r = (v.u + 0x7FFFu + ((v.u >> 16) & 1u)) >> 16;
    return (unsigned short)r;
}
__device__ __forceinline__ unsigned pack2(float lo, float hi) {
    return (unsigned)f2bf(lo) | ((unsigned)f2bf(hi) << 16);
}

// ---------------- rowptr: tgt is sorted; rowptr[v] = first edge with tgt >= v ----------------
__global__ void rowptr_kernel(const int* __restrict__ tgt, int E, int n, int* __restrict__ rowptr)
{
    int e = blockIdx.x * blockDim.x + threadIdx.x;
    if (e > E) return;
    if (e < E) {
        int t = tgt[e];
        int p = (e == 0) ? -1 : tgt[e - 1];
        for (int v = p + 1; v <= t; v++) rowptr[v] = e;
    } else {
        int p = tgt[E - 1];
        for (int v = p + 1; v <= n; v++) rowptr[v] = E;
    }
}

// ---------------- edge records: fracs + packed (b0,b1,b2,src) ----------------
__global__ void edgerec_kernel(const float* __restrict__ posL, const int* __restrict__ src,
                               const int* __restrict__ tgt, int E, float rinv2,
                               float4* __restrict__ rec)
{
    int e = blockIdx.x * blockDim.x + threadIdx.x;
    if (e >= E) return;
    int s = src[e], t = tgt[e];
    float p0 = fminf(fmaxf((posL[t*3+0] - posL[s*3+0]) * rinv2 + 0.5f, 0.f), 1.f);
    float p1 = fminf(fmaxf((posL[t*3+1] - posL[s*3+1]) * rinv2 + 0.5f, 0.f), 1.f);
    float p2 = fminf(fmaxf((posL[t*3+2] - posL[s*3+2]) * rinv2 + 0.5f, 0.f), 1.f);
    float v0 = p0 * (KDIM - 1), v1 = p1 * (KDIM - 1), v2 = p2 * (KDIM - 1);
    int b0 = (int)floorf(v0), b1 = (int)floorf(v1), b2 = (int)floorf(v2);
    unsigned int bits = (unsigned int)b0 | ((unsigned int)b1 << 3) | ((unsigned int)b2 << 6)
                      | ((unsigned int)s << 9);
    rec[e] = make_float4(v0 - (float)b0, v1 - (float)b1, v2 - (float)b2, __uint_as_float(bits));
}

// ---------------- Level 1: Cin=1, Cout=64 (per-wave private histograms) ----------------
__global__ void conv1_kernel(const float4* __restrict__ rec, const int* __restrict__ rowptr,
                             const float* __restrict__ W, const float* __restrict__ R,
                             const float* __restrict__ b, float* __restrict__ xout)
{
    __shared__ float A2[2][KC];
    int node = blockIdx.x;
    int t = threadIdx.x;                      // blockDim = 128
    for (int i = t; i < 2 * KC; i += 128) A2[0][i] = 0.f;
    int rs = rowptr[node], re = rowptr[node + 1];
    int wv = t >> 6;
    __syncthreads();
    for (int e = rs + t; e < re; e += 128) {
        float4 rc = rec[e];
        unsigned int bits = __float_as_uint(rc.w);
        int b0 = bits & 7, b1i = (bits >> 3) & 7, b2 = (bits >> 6) & 7;
        float f0 = rc.x, f1 = rc.y, f2 = rc.z;
        #pragma unroll
        for (int sb = 0; sb < 8; sb++) {
            int i0 = sb & 1, i1 = (sb >> 1) & 1, i2 = (sb >> 2) & 1;
            float w = (i0 ? f0 : 1.f - f0) * (i1 ? f1 : 1.f - f1) * (i2 ? f2 : 1.f - f2);
            int k0 = min(b0 + i0, KDIM - 1), k1 = min(b1i + i1, KDIM - 1), k2 = min(b2 + i2, KDIM - 1);
            int wi = k0 + KDIM * k1 + KDIM * KDIM * k2;
            unsafeAtomicAdd(&A2[wv][wi], w);
        }
    }
    __syncthreads();
    if (t < 64) {
        float acc = 0.f;
        for (int k = 0; k < KC; k++) acc += (A2[0][k] + A2[1][k]) * W[k * 64 + t];
        float deg = fmaxf((float)(re - rs), 1.f);
        float val = acc / deg + R[t] + b[t];
        xout[(size_t)node * 64 + t] = elu_f(val);
    }
}

// ---------------- buildA: atomic-free LDS accumulation, bf16 output ----------------
// Wave w owns channels [16w, 16w+16). Lanes = 4 slot-groups x 16 channels.
__global__ __launch_bounds__(256) void buildA_kernel(
    const float4* __restrict__ rec, const int* __restrict__ rowptr,
    const float* __restrict__ xin, int nodeBase, unsigned short* __restrict__ Aout)
{
    __shared__ float A[(KC + 1) * 64];        // 126 rows; row 125 = dummy sink
    __shared__ float Xs[EPB * 64];
    __shared__ float4 recs[EPB];
    int node = nodeBase + blockIdx.x;
    int t = threadIdx.x;                      // blockDim = 256
    for (int i = t; i < (KC + 1) * 16; i += 256)
        ((float4*)A)[i] = make_float4(0.f, 0.f, 0.f, 0.f);
    int rs = rowptr[node], re = rowptr[node + 1];

    int wave = t >> 6, lane = t & 63;
    int sgrp = lane >> 4;
    int c = wave * 16 + (lane & 15);
    int i0 = sgrp & 1, i1 = sgrp >> 1;

    for (int ts = rs; ts < re; ts += EPB) {
        int ne = min(EPB, re - ts);
        __syncthreads();
        if (t < ne) recs[t] = rec[ts + t];
        __syncthreads();
        for (int i = t; i < ne * 64; i += 256) {
            int el = i >> 6, cc = i & 63;
            unsigned int sj = __float_as_uint(recs[el].w) >> 9;
            Xs[i] = xin[(size_t)sj * 64 + cc];
        }
        __syncthreads();
        for (int et = 0; et < ne; et++) {
            float4 rc = recs[et];
            unsigned int bits = __float_as_uint(rc.w);
            int b0 = bits & 7, b1i = (bits >> 3) & 7, b2 = (bits >> 6) & 7;
            float f0 = rc.x, f1 = rc.y, f2 = rc.z;
            float xj = Xs[et * 64 + c];
            float wa = (i0 ? f0 : 1.f - f0) * (i1 ? f1 : 1.f - f1);
            int k0 = min(b0 + i0, KDIM - 1), k1 = min(b1i + i1, KDIM - 1);
            int kbase = k0 + KDIM * k1;
            #pragma unroll
            for (int i2 = 0; i2 < 2; i2++) {
                float w = wa * (i2 ? f2 : 1.f - f2);
                int k2 = min(b2 + i2, KDIM - 1);
                int wi = kbase + KDIM * KDIM * k2;
                wi = (w == 0.f) ? KC : wi;
                A[wi * 64 + c] += w * xj;
            }
        }
    }
    __syncthreads();
    float invdeg = 1.f / fmaxf((float)(re - rs), 1.f);
    unsigned short* out = Aout + (size_t)blockIdx.x * KPAD;
    for (int i = t; i < 1000; i += 256) {     // 8000 floats -> bf16 in groups of 8
        float4 v0 = ((const float4*)A)[i * 2];
        float4 v1 = ((const float4*)A)[i * 2 + 1];
        uint4 pk;
        pk.x = pack2(v0.x * invdeg, v0.y * invdeg);
        pk.y = pack2(v0.z * invdeg, v0.w * invdeg);
        pk.z = pack2(v1.x * invdeg, v1.y * invdeg);
        pk.w = pack2(v1.z * invdeg, v1.w * invdeg);
        *(uint4*)&out[i * 8] = pk;
    }
    if (t < 8) {                              // root rows = x[node]
        const float* xr = xin + (size_t)node * 64 + t * 8;
        uint4 pk;
        pk.x = pack2(xr[0], xr[1]);
        pk.y = pack2(xr[2], xr[3]);
        pk.z = pack2(xr[4], xr[5]);
        pk.w = pack2(xr[6], xr[7]);
        *(uint4*)&out[8000 + t * 8] = pk;
    } else if (t < 24) {                      // zero padding rows 8064..8191
        *(uint4*)&out[8064 + (t - 8) * 8] = make_uint4(0, 0, 0, 0);
    }
}

// ---------------- concat + transpose weights to bf16: WfT[n][k] ----------------
__global__ void concatWT_kernel(const float* __restrict__ W, const float* __restrict__ R,
                                int COUT, unsigned short* __restrict__ WfT)
{
    int i = blockIdx.x * blockDim.x + threadIdx.x;
    if (i >= COUT * KPAD) return;
    int n = i >> 13, k = i & (KPAD - 1);
    float v = (k < KC * 64) ? W[(size_t)k * COUT + n]
            : (k < KC * 64 + 64 ? R[(size_t)(k - KC * 64) * COUT + n] : 0.f);
    WfT[i] = f2bf(v);
}

// ---------------- bf16 MFMA GEMM: P[z] = A[:, zslice] x WfT[:, zslice]^T ----------------
// 64x64 tile, 4 waves x (2x2) mfma_f32_16x16x32_bf16, register-prefetch dbuf.
__global__ __launch_bounds__(256) void gemm_kernel(const unsigned short* __restrict__ A,
                                                   const unsigned short* __restrict__ BT,
                                                   int Mrows, int COUT, int Ksz,
                                                   float* __restrict__ P)
{
    __shared__ unsigned short As[64 * LDA];
    __shared__ unsigned short Bs[64 * LDA];
    int t = threadIdx.x;
    int mblk = blockIdx.x * 64, nblk = blockIdx.y * 64;
    int kBase = blockIdx.z * Ksz;

    int lr = t >> 2;                 // staging row 0..63
    int lc = (t & 3) * 16;           // staging col (bf16 units): 32 B per thread

    const unsigned short* Ap = A + (size_t)(mblk + lr) * KPAD + kBase + lc;
    const unsigned short* Bp = BT + (size_t)(nblk + lr) * KPAD + kBase + lc;

    uint4 a0 = *(const uint4*)Ap;  uint4 a1 = *(const uint4*)(Ap + 8);
    uint4 b0 = *(const uint4*)Bp;  uint4 b1 = *(const uint4*)(Bp + 8);

    int wave = t >> 6, lane = t & 63;
    int mw = (wave & 1) * 32, nw = (wave >> 1) * 32;
    int fr = lane & 15;              // fragment row (m or n)
    int fq = (lane >> 4) * 8;        // fragment k offset

    f32x4 acc[2][2];
    #pragma unroll
    for (int i = 0; i < 2; i++)
        #pragma unroll
        for (int j = 0; j < 2; j++) acc[i][j] = (f32x4){0.f, 0.f, 0.f, 0.f};

    int ktiles = Ksz / 64;
    for (int kt = 0; kt < ktiles; kt++) {
        *(uint4*)&As[lr * LDA + lc]     = a0;
        *(uint4*)&As[lr * LDA + lc + 8] = a1;
        *(uint4*)&Bs[lr * LDA + lc]     = b0;
        *(uint4*)&Bs[lr * LDA + lc + 8] = b1;
        __syncthreads();
        if (kt + 1 < ktiles) {
            Ap += 64; Bp += 64;
            a0 = *(const uint4*)Ap; a1 = *(const uint4*)(Ap + 8);
            b0 = *(const uint4*)Bp; b1 = *(const uint4*)(Bp + 8);
        }
        #pragma unroll
        for (int ks = 0; ks < 2; ks++) {
            bf16x8 af0 = *(const bf16x8*)&As[(mw + fr) * LDA + ks * 32 + fq];
            bf16x8 af1 = *(const bf16x8*)&As[(mw + 16 + fr) * LDA + ks * 32 + fq];
            bf16x8 bg0 = *(const bf16x8*)&Bs[(nw + fr) * LDA + ks * 32 + fq];
            bf16x8 bg1 = *(const bf16x8*)&Bs[(nw + 16 + fr) * LDA + ks * 32 + fq];
            acc[0][0] = __builtin_amdgcn_mfma_f32_16x16x32_bf16(af0, bg0, acc[0][0], 0, 0, 0);
            acc[0][1] = __builtin_amdgcn_mfma_f32_16x16x32_bf16(af0, bg1, acc[0][1], 0, 0, 0);
            acc[1][0] = __builtin_amdgcn_mfma_f32_16x16x32_bf16(af1, bg0, acc[1][0], 0, 0, 0);
            acc[1][1] = __builtin_amdgcn_mfma_f32_16x16x32_bf16(af1, bg1, acc[1][1], 0, 0, 0);
        }
        __syncthreads();
    }
    float* Pz = P + (size_t)blockIdx.z * Mrows * COUT;
    int crow = (lane >> 4) * 4, ccol = lane & 15;
    #pragma unroll
    for (int i = 0; i < 2; i++)
        #pragma unroll
        for (int j = 0; j < 2; j++) {
            int m0 = mblk + mw + i * 16 + crow;
            int n0 = nblk + nw + j * 16 + ccol;
            #pragma unroll
            for (int r = 0; r < 4; r++)
                Pz[(size_t)(m0 + r) * COUT + n0] = acc[i][j][r];
        }
}

// ---------------- combine K-split partials + bias + ELU ----------------
__global__ void combine_kernel(const float* __restrict__ P, const float* __restrict__ b,
                               int Mrows, int COUT, int NS, float* __restrict__ xout)
{
    int i = blockIdx.x * blockDim.x + threadIdx.x;
    int total = Mrows * COUT;
    if (i >= total) return;
    float s = 0.f;
    for (int z = 0; z < NS; z++) s += P[(size_t)z * total + i];
    int o = i % COUT;
    xout[i] = elu_f(s + b[o]);
}

// ---------------- gathers ----------------
__global__ void xgather_kernel(const float* __restrict__ x_src, const int* __restrict__ idx,
                               int n, float* __restrict__ x_dst)
{
    int tid = blockIdx.x * blockDim.x + threadIdx.x;
    if (tid >= n * 64) return;
    int i = tid >> 6, c = tid & 63;
    x_dst[(size_t)i * 64 + c] = x_src[(size_t)idx[i] * 64 + c];
}

__global__ void posgather_kernel(const float* __restrict__ pos_src, const int* __restrict__ idx,
                                 int n, float* __restrict__ pos_dst)
{
    int tid = blockIdx.x * blockDim.x + threadIdx.x;
    if (tid >= n * 3) return;
    int i = tid / 3, d = tid - i * 3;
    pos_dst[tid] = pos_src[idx[i] * 3 + d];
}

__global__ void zero_kernel(float* __restrict__ p, int n)
{
    int i = blockIdx.x * blockDim.x + threadIdx.x;
    if (i < n) p[i] = 0.f;
}

// ---------------- Mean pool over clouds ----------------
__global__ void pool_kernel(const float* __restrict__ x3, const int* __restrict__ batch,
                            const int* __restrict__ idx1, const int* __restrict__ idx2, int n3,
                            float* __restrict__ gnum, float* __restrict__ cnt)
{
    int tid = blockIdx.x * blockDim.x + threadIdx.x;
    if (tid >= n3 * 128) return;
    int i = tid >> 7, c = tid & 127;
    int cloud = batch[idx1[idx2[i]]];
    fadd_atomic(&gnum[cloud * 128 + c], x3[(size_t)i * 128 + c]);
    if (c == 0) fadd_atomic(&cnt[cloud], 1.f);
}

// ---------------- Final MLP + log_softmax ----------------
__global__ void mlp_kernel(const float* __restrict__ gnum, const float* __restrict__ cnt,
                           const float* __restrict__ lw1, const float* __restrict__ lb1,
                           const float* __restrict__ lw2, const float* __restrict__ lb2,
                           const float* __restrict__ lw3, const float* __restrict__ lb3,
                           float* __restrict__ out)
{
    __shared__ float gv[128], h1[256], h2[256], lg[10];
    __shared__ float lse_s;
    int cl = blockIdx.x, t = threadIdx.x;   // blockDim = 256
    if (t < 128) gv[t] = gnum[cl * 128 + t] / fmaxf(cnt[cl], 1.f);
    __syncthreads();
    float a = lb1[t];
    for (int c = 0; c < 128; c++) a += gv[c] * lw1[c * 256 + t];
    h1[t] = elu_f(a);
    __syncthreads();
    a = lb2[t];
    for (int c = 0; c < 256; c++) a += h1[c] * lw2[c * 256 + t];
    h2[t] = elu_f(a);
    __syncthreads();
    if (t < 10) {
        a = lb3[t];
        for (int c = 0; c < 256; c++) a += h2[c] * lw3[c * 10 + t];
        lg[t] = a;
    }
    __syncthreads();
    if (t == 0) {
        float m = -1e30f;
        for (int i = 0; i < 10; i++) m = fmaxf(m, lg[i]);
        float s = 0.f;
        for (int i = 0; i < 10; i++) s += expf(lg[i] - m);
        lse_s = m + logf(s);
    }
    __syncthreads();
    if (t < 10) out[cl * 10 + t] = lg[t] - lse_s;
}

static void run_level(const float4* rec, const int* rowptr, const float* xin,
                      const unsigned short* WfT, const float* bvec, int n, int COUT,
                      unsigned short* Abuf, int AbufRows, float* P, float* xout,
                      hipStream_t stream)
{
    int Ksz = KPAD / NSPLIT;
    for (int cs = 0; cs < n; cs += AbufRows) {
        int cr = min(AbufRows, n - cs);
        buildA_kernel<<<cr, 256, 0, stream>>>(rec, rowptr, xin, cs, Abuf);
        dim3 grid(cr / 64, COUT / 64, NSPLIT);
        gemm_kernel<<<grid, 256, 0, stream>>>(Abuf, WfT, cr, COUT, Ksz, P);
        combine_kernel<<<(cr * COUT + 255) / 256, 256, 0, stream>>>(P, bvec, cr, COUT, NSPLIT,
                                                                    xout + (size_t)cs * COUT);
    }
}

extern "C" void kernel_launch(void* const* d_in, const int* in_sizes, int n_in,
                              void* d_out, int out_size, void* d_ws, size_t ws_size,
                              hipStream_t stream)
{
    const float* pos   = (const float*)d_in[0];
    const int*   batch = (const int*)d_in[1];
    const int*   src1  = (const int*)d_in[2];
    const int*   tgt1  = (const int*)d_in[3];
    const int*   src2  = (const int*)d_in[4];
    const int*   tgt2  = (const int*)d_in[5];
    const int*   src3  = (const int*)d_in[6];
    const int*   tgt3  = (const int*)d_in[7];
    const int*   idx1  = (const int*)d_in[8];
    const int*   idx2  = (const int*)d_in[9];
    const float* W1 = (const float*)d_in[10];
    const float* R1 = (const float*)d_in[11];
    const float* b1 = (const float*)d_in[12];
    const float* W2 = (const float*)d_in[13];
    const float* R2 = (const float*)d_in[14];
    const float* b2 = (const float*)d_in[15];
    const float* W3 = (const float*)d_in[16];
    const float* R3 = (const float*)d_in[17];
    const float* b3 = (const float*)d_in[18];
    const float* lw1 = (const float*)d_in[19];
    const float* lb1 = (const float*)d_in[20];
    const float* lw2 = (const float*)d_in[21];
    const float* lb2 = (const float*)d_in[22];
    const float* lw3 = (const float*)d_in[23];
    const float* lb3 = (const float*)d_in[24];

    int n1 = in_sizes[0] / 3;
    int E1 = in_sizes[2];
    int E2 = in_sizes[4];
    int E3 = in_sizes[6];
    int n2 = in_sizes[8];
    int n3 = in_sizes[9];

    float* ws = (float*)d_ws;
    float* x1   = ws;                               // n1*64
    float* x2in = x1   + (size_t)n1 * 64;           // n2*64
    float* x2o  = x2in + (size_t)n2 * 64;           // n2*64
    float* x3in = x2o  + (size_t)n2 * 64;           // n3*64
    float* x3o  = x3in + (size_t)n3 * 64;           // n3*128
    float* pos2 = x3o  + (size_t)n3 * 128;          // n2*3
    float* pos3 = pos2 + (size_t)n2 * 3;            // n3*3
    float* gnum = pos3 + (size_t)n3 * 3;            // 16*128
    float* cnt  = gnum + 16 * 128;                  // 16
    unsigned short* WfT2 = (unsigned short*)(cnt + 16);    // 64*KPAD bf16
    unsigned short* WfT3 = WfT2 + (size_t)64 * KPAD;       // 128*KPAD bf16
    int*   rp1  = (int*)(WfT3 + (size_t)128 * KPAD);
    int*   rp2  = rp1 + ((n1 + 4) & ~3);
    int*   rp3  = rp2 + ((n2 + 4) & ~3);
    float4* rec1 = (float4*)(rp3 + ((n3 + 4) & ~3));
    float4* rec2 = rec1 + E1;
    float4* rec3 = rec2 + E2;
    float*  P    = (float*)(rec3 + E3);             // 8M floats
    unsigned short* Abuf = (unsigned short*)(P + (size_t)8 * 1024 * 1024);

    size_t usedBytes = (size_t)((char*)Abuf - (char*)ws);
    size_t availBytes = ws_size > usedBytes ? ws_size - usedBytes : 0;
    int maxRows = (int)(availBytes / ((size_t)KPAD * 2));
    maxRows &= ~63;
    if (maxRows < 64) maxRows = 64;
    int rowsP2 = ((8 * 1024 * 1024) / (NSPLIT * 64)) & ~63;
    int rowsP3 = ((8 * 1024 * 1024) / (NSPLIT * 128)) & ~63;
    int rows2 = min(min(maxRows, rowsP2), n2);
    int rows3 = min(min(maxRows, rowsP3), n3);

    float* out = (float*)d_out;

    // --- graph preprocessing ---
    rowptr_kernel<<<(E1 + 256) / 256, 256, 0, stream>>>(tgt1, E1, n1, rp1);
    rowptr_kernel<<<(E2 + 256) / 256, 256, 0, stream>>>(tgt2, E2, n2, rp2);
    rowptr_kernel<<<(E3 + 256) / 256, 256, 0, stream>>>(tgt3, E3, n3, rp3);
    posgather_kernel<<<(n2 * 3 + 255) / 256, 256, 0, stream>>>(pos, idx1, n2, pos2);
    posgather_kernel<<<(n3 * 3 + 255) / 256, 256, 0, stream>>>(pos2, idx2, n3, pos3);
    edgerec_kernel<<<(E1 + 255) / 256, 256, 0, stream>>>(pos,  src1, tgt1, E1, 2.5f,  rec1);
    edgerec_kernel<<<(E2 + 255) / 256, 256, 0, stream>>>(pos2, src2, tgt2, E2, 1.25f, rec2);
    edgerec_kernel<<<(E3 + 255) / 256, 256, 0, stream>>>(pos3, src3, tgt3, E3, 0.5f,  rec3);
    concatWT_kernel<<<(64 * KPAD + 255) / 256, 256, 0, stream>>>(W2, R2, 64, WfT2);
    concatWT_kernel<<<(128 * KPAD + 255) / 256, 256, 0, stream>>>(W3, R3, 128, WfT3);

    // --- level 1 ---
    conv1_kernel<<<n1, 128, 0, stream>>>(rec1, rp1, W1, R1, b1, x1);
    xgather_kernel<<<(n2 * 64 + 255) / 256, 256, 0, stream>>>(x1, idx1, n2, x2in);

    // --- level 2 ---
    run_level(rec2, rp2, x2in, WfT2, b2, n2, 64, Abuf, rows2, P, x2o, stream);
    xgather_kernel<<<(n3 * 64 + 255) / 256, 256, 0, stream>>>(x2o, idx2, n3, x3in);

    // --- level 3 ---
    run_level(rec3, rp3, x3in, WfT3, b3, n3, 128, Abuf, rows3, P, x3o, stream);

    // --- pool + head ---
    zero_kernel<<<(16 * 128 + 16 + 255) / 256, 256, 0, stream>>>(gnum, 16 * 128 + 16);
    pool_kernel<<<(n3 * 128 + 255) / 256, 256, 0, stream>>>(x3o, batch, idx1, idx2, n3, gnum, cnt);
    mlp_kernel<<<16, 256, 0, stream>>>(gnum, cnt, lw1, lb1, lw2, lb2, lw3, lb3, out);
}

// Round 8
// 594.608 us; speedup vs baseline: 5.1920x; 1.0330x over previous
//
#include <hip/hip_runtime.h>
#include <math.h>

#define KDIM 5
#define KC 125
#define KPAD 8192   // 125*64 spline rows + 64 root rows + 128 zero pad (levels 2/3)
#define EPB 32      // edges staged per tile (max_nb = 32)
#define NSPLIT 8    // GEMM K-split for levels 2/3
#define LDA 72      // GEMM LDS tile row stride in bf16 (64 + 8 pad)
#define ASTRIDE 65  // buildA LDS row stride in floats (odd -> banks spread)

typedef short bf16x8 __attribute__((ext_vector_type(8)));
typedef float f32x4 __attribute__((ext_vector_type(4)));

__device__ __forceinline__ float elu_f(float x) { return x > 0.f ? x : (expf(x) - 1.f); }

__device__ __forceinline__ void fadd_atomic(float* p, float v) {
    unsafeAtomicAdd(p, v);
}

__device__ __forceinline__ unsigned short f2bf(float x) {
    union { float f; unsigned u; } v; v.f = x;
    unsigned r = (v.u + 0x7FFFu + ((v.u >> 16) & 1u)) >> 16;
    return (unsigned short)r;
}
__device__ __forceinline__ unsigned pack2(float lo, float hi) {
    return (unsigned)f2bf(lo) | ((unsigned)f2bf(hi) << 16);
}

// ---------------- rowptr: tgt is sorted; rowptr[v] = first edge with tgt >= v ----------------
__global__ void rowptr_kernel(const int* __restrict__ tgt, int E, int n, int* __restrict__ rowptr)
{
    int e = blockIdx.x * blockDim.x + threadIdx.x;
    if (e > E) return;
    if (e < E) {
        int t = tgt[e];
        int p = (e == 0) ? -1 : tgt[e - 1];
        for (int v = p + 1; v <= t; v++) rowptr[v] = e;
    } else {
        int p = tgt[E - 1];
        for (int v = p + 1; v <= n; v++) rowptr[v] = E;
    }
}

// ---------------- slot table: per edge 8 words = (w with wi packed in low 7 mantissa bits) ----
// zero-weight slots are redirected to sinkrow at build time.
__global__ void slots_kernel(const float* __restrict__ posL, const int* __restrict__ src,
                             const int* __restrict__ tgt, int E, float rinv2, int sinkrow,
                             unsigned* __restrict__ slots)
{
    int e = blockIdx.x * blockDim.x + threadIdx.x;
    if (e >= E) return;
    int s = src[e], t = tgt[e];
    float p0 = fminf(fmaxf((posL[t*3+0] - posL[s*3+0]) * rinv2 + 0.5f, 0.f), 1.f);
    float p1 = fminf(fmaxf((posL[t*3+1] - posL[s*3+1]) * rinv2 + 0.5f, 0.f), 1.f);
    float p2 = fminf(fmaxf((posL[t*3+2] - posL[s*3+2]) * rinv2 + 0.5f, 0.f), 1.f);
    float v0 = p0 * (KDIM - 1), v1 = p1 * (KDIM - 1), v2 = p2 * (KDIM - 1);
    int b0 = (int)floorf(v0), b1 = (int)floorf(v1), b2 = (int)floorf(v2);
    float f0 = v0 - (float)b0, f1 = v1 - (float)b1, f2 = v2 - (float)b2;
    unsigned out[8];
    #pragma unroll
    for (int sb = 0; sb < 8; sb++) {
        int i0 = sb & 1, i1 = (sb >> 1) & 1, i2 = (sb >> 2) & 1;
        float w = (i0 ? f0 : 1.f - f0) * (i1 ? f1 : 1.f - f1) * (i2 ? f2 : 1.f - f2);
        int k0 = min(b0 + i0, KDIM - 1), k1 = min(b1 + i1, KDIM - 1), k2 = min(b2 + i2, KDIM - 1);
        int wi = k0 + KDIM * k1 + KDIM * KDIM * k2;
        if (w == 0.f) wi = sinkrow;
        out[sb] = (__float_as_uint(w) & ~127u) | (unsigned)wi;
    }
    uint4* dst = (uint4*)&slots[(size_t)e * 8];
    dst[0] = make_uint4(out[0], out[1], out[2], out[3]);
    dst[1] = make_uint4(out[4], out[5], out[6], out[7]);
}

// ---------------- Level 1 histogram: one wave per node, A1 bf16 [node][128] ----------------
// Row 125 = max(deg,1) (so /deg -> 1.0 root row), rows 126 (sink) / 127 forced 0 via W rows.
__global__ __launch_bounds__(256) void histo1_kernel(const unsigned* __restrict__ slots,
                                                     const int* __restrict__ rowptr,
                                                     unsigned short* __restrict__ Aout)
{
    __shared__ float A1s[4][128];
    int wave = threadIdx.x >> 6, lane = threadIdx.x & 63;
    int node = blockIdx.x * 4 + wave;
    A1s[wave][lane] = 0.f;
    A1s[wave][64 + lane] = 0.f;
    int rs = rowptr[node], re = rowptr[node + 1];
    for (int e = rs + lane; e < re; e += 64) {
        uint4 s0 = *(const uint4*)&slots[(size_t)e * 8];
        uint4 s1 = *(const uint4*)&slots[(size_t)e * 8 + 4];
        unsafeAtomicAdd(&A1s[wave][s0.x & 127u], __uint_as_float(s0.x));
        unsafeAtomicAdd(&A1s[wave][s0.y & 127u], __uint_as_float(s0.y));
        unsafeAtomicAdd(&A1s[wave][s0.z & 127u], __uint_as_float(s0.z));
        unsafeAtomicAdd(&A1s[wave][s0.w & 127u], __uint_as_float(s0.w));
        unsafeAtomicAdd(&A1s[wave][s1.x & 127u], __uint_as_float(s1.x));
        unsafeAtomicAdd(&A1s[wave][s1.y & 127u], __uint_as_float(s1.y));
        unsafeAtomicAdd(&A1s[wave][s1.z & 127u], __uint_as_float(s1.z));
        unsafeAtomicAdd(&A1s[wave][s1.w & 127u], __uint_as_float(s1.w));
    }
    __syncthreads();
    float deg = (float)(re - rs);
    float invdeg = 1.f / fmaxf(deg, 1.f);
    if (lane == 0) {
        A1s[wave][125] = fmaxf(deg, 1.f);
        A1s[wave][126] = 0.f;
        A1s[wave][127] = 0.f;
    }
    __syncthreads();
    unsigned* out = (unsigned*)(Aout + (size_t)node * 128);
    out[lane] = pack2(A1s[wave][2 * lane] * invdeg, A1s[wave][2 * lane + 1] * invdeg);
}

// ---------------- buildA (levels 2/3): atomic-free, slot-table driven, stride-65 A ----------
// Wave w owns channels [16w,16w+16). Lanes = 4 slot-groups x 16 channels.
__global__ __launch_bounds__(256) void buildA_kernel(
    const unsigned* __restrict__ slots, const int* __restrict__ src,
    const int* __restrict__ rowptr, const float* __restrict__ xin,
    int nodeBase, unsigned short* __restrict__ Aout)
{
    __shared__ float A[8192];                 // 126 rows x stride 65 (max 8188) + pad
    __shared__ float Xs[EPB * 64];
    __shared__ unsigned Ss[EPB * 8];
    __shared__ int Es[EPB];
    int node = nodeBase + blockIdx.x;
    int t = threadIdx.x;                      // blockDim = 256
    for (int i = t; i < 2048; i += 256) ((float4*)A)[i] = make_float4(0.f, 0.f, 0.f, 0.f);
    int rs = rowptr[node], re = rowptr[node + 1];

    int wave = t >> 6, lane = t & 63;
    int sgrp = lane >> 4;                     // slot group 0..3 -> slots {2s, 2s+1}
    int c = wave * 16 + (lane & 15);          // owned channel

    for (int ts = rs; ts < re; ts += EPB) {
        int ne = min(EPB, re - ts);
        __syncthreads();
        if (t < ne) Es[t] = src[ts + t];
        if (t < ne * 8) Ss[t] = slots[(size_t)ts * 8 + t];
        __syncthreads();
        for (int i = t; i < ne * 64; i += 256) {
            int el = i >> 6, cc = i & 63;
            Xs[i] = xin[(size_t)Es[el] * 64 + cc];
        }
        __syncthreads();
        for (int et = 0; et < ne; et++) {
            float xj = Xs[et * 64 + c];
            #pragma unroll
            for (int i2 = 0; i2 < 2; i2++) {
                unsigned word = Ss[et * 8 + sgrp * 2 + i2];   // broadcast across 16 lanes
                int wi = word & 127u;
                A[wi * ASTRIDE + c] += __uint_as_float(word) * xj;
            }
        }
    }
    __syncthreads();
    float invdeg = 1.f / fmaxf((float)(re - rs), 1.f);
    unsigned short* out = Aout + (size_t)blockIdx.x * KPAD;
    for (int u = t; u < 1000; u += 256) {     // unit = (wi, 8-channel group)
        int wi = u >> 3, cg = (u & 7) * 8;
        const float* Ap = &A[wi * ASTRIDE + cg];
        uint4 pk;
        pk.x = pack2(Ap[0] * invdeg, Ap[1] * invdeg);
        pk.y = pack2(Ap[2] * invdeg, Ap[3] * invdeg);
        pk.z = pack2(Ap[4] * invdeg, Ap[5] * invdeg);
        pk.w = pack2(Ap[6] * invdeg, Ap[7] * invdeg);
        *(uint4*)&out[wi * 64 + cg] = pk;
    }
    if (t < 8) {                              // root rows = x[node]
        const float* xr = xin + (size_t)node * 64 + t * 8;
        uint4 pk;
        pk.x = pack2(xr[0], xr[1]);
        pk.y = pack2(xr[2], xr[3]);
        pk.z = pack2(xr[4], xr[5]);
        pk.w = pack2(xr[6], xr[7]);
        *(uint4*)&out[8000 + t * 8] = pk;
    } else if (t < 24) {                      // zero padding rows 8064..8191
        *(uint4*)&out[8064 + (t - 8) * 8] = make_uint4(0, 0, 0, 0);
    }
}

// ---------------- concat + transpose weights to bf16: WfT[n][k], K padded ----------------
__global__ void concatWT_kernel(const float* __restrict__ W, const float* __restrict__ R,
                                int COUT, int kpad, int krows, int cin,
                                unsigned short* __restrict__ WfT)
{
    int i = blockIdx.x * blockDim.x + threadIdx.x;
    if (i >= COUT * kpad) return;
    int n = i / kpad, k = i - n * kpad;
    float v = 0.f;
    if (k < krows) v = W[(size_t)k * COUT + n];
    else if (k < krows + cin) v = R[(size_t)(k - krows) * COUT + n];
    WfT[i] = f2bf(v);
}

// ---------------- bf16 MFMA GEMM: P[z] = A[:, zslice] x BT[:, zslice]^T ----------------
__global__ __launch_bounds__(256) void gemm_kernel(const unsigned short* __restrict__ A,
                                                   const unsigned short* __restrict__ BT,
                                                   int Mrows, int COUT, int Ksz, int lda,
                                                   float* __restrict__ P)
{
    __shared__ unsigned short As[64 * LDA];
    __shared__ unsigned short Bs[64 * LDA];
    int t = threadIdx.x;
    int mblk = blockIdx.x * 64, nblk = blockIdx.y * 64;
    int kBase = blockIdx.z * Ksz;

    int lr = t >> 2;                 // staging row 0..63
    int lc = (t & 3) * 16;           // staging col (bf16 units)

    const unsigned short* Ap = A + (size_t)(mblk + lr) * lda + kBase + lc;
    const unsigned short* Bp = BT + (size_t)(nblk + lr) * lda + kBase + lc;

    uint4 a0 = *(const uint4*)Ap;  uint4 a1 = *(const uint4*)(Ap + 8);
    uint4 b0 = *(const uint4*)Bp;  uint4 b1 = *(const uint4*)(Bp + 8);

    int wave = t >> 6, lane = t & 63;
    int mw = (wave & 1) * 32, nw = (wave >> 1) * 32;
    int fr = lane & 15;
    int fq = (lane >> 4) * 8;

    f32x4 acc[2][2];
    #pragma unroll
    for (int i = 0; i < 2; i++)
        #pragma unroll
        for (int j = 0; j < 2; j++) acc[i][j] = (f32x4){0.f, 0.f, 0.f, 0.f};

    int ktiles = Ksz / 64;
    for (int kt = 0; kt < ktiles; kt++) {
        *(uint4*)&As[lr * LDA + lc]     = a0;
        *(uint4*)&As[lr * LDA + lc + 8] = a1;
        *(uint4*)&Bs[lr * LDA + lc]     = b0;
        *(uint4*)&Bs[lr * LDA + lc + 8] = b1;
        __syncthreads();
        if (kt + 1 < ktiles) {
            Ap += 64; Bp += 64;
            a0 = *(const uint4*)Ap; a1 = *(const uint4*)(Ap + 8);
            b0 = *(const uint4*)Bp; b1 = *(const uint4*)(Bp + 8);
        }
        #pragma unroll
        for (int ks = 0; ks < 2; ks++) {
            bf16x8 af0 = *(const bf16x8*)&As[(mw + fr) * LDA + ks * 32 + fq];
            bf16x8 af1 = *(const bf16x8*)&As[(mw + 16 + fr) * LDA + ks * 32 + fq];
            bf16x8 bg0 = *(const bf16x8*)&Bs[(nw + fr) * LDA + ks * 32 + fq];
            bf16x8 bg1 = *(const bf16x8*)&Bs[(nw + 16 + fr) * LDA + ks * 32 + fq];
            acc[0][0] = __builtin_amdgcn_mfma_f32_16x16x32_bf16(af0, bg0, acc[0][0], 0, 0, 0);
            acc[0][1] = __builtin_amdgcn_mfma_f32_16x16x32_bf16(af0, bg1, acc[0][1], 0, 0, 0);
            acc[1][0] = __builtin_amdgcn_mfma_f32_16x16x32_bf16(af1, bg0, acc[1][0], 0, 0, 0);
            acc[1][1] = __builtin_amdgcn_mfma_f32_16x16x32_bf16(af1, bg1, acc[1][1], 0, 0, 0);
        }
        __syncthreads();
    }
    float* Pz = P + (size_t)blockIdx.z * Mrows * COUT;
    int crow = (lane >> 4) * 4, ccol = lane & 15;
    #pragma unroll
    for (int i = 0; i < 2; i++)
        #pragma unroll
        for (int j = 0; j < 2; j++) {
            int m0 = mblk + mw + i * 16 + crow;
            int n0 = nblk + nw + j * 16 + ccol;
            #pragma unroll
            for (int r = 0; r < 4; r++)
                Pz[(size_t)(m0 + r) * COUT + n0] = acc[i][j][r];
        }
}

// ---------------- combine K-split partials + bias + ELU ----------------
__global__ void combine_kernel(const float* __restrict__ P, const float* __restrict__ b,
                               int Mrows, int COUT, int NS, float* __restrict__ xout)
{
    int i = blockIdx.x * blockDim.x + threadIdx.x;
    int total = Mrows * COUT;
    if (i >= total) return;
    float s = 0.f;
    for (int z = 0; z < NS; z++) s += P[(size_t)z * total + i];
    int o = i % COUT;
    xout[i] = elu_f(s + b[o]);
}

// ---------------- gathers ----------------
__global__ void xgather_kernel(const float* __restrict__ x_src, const int* __restrict__ idx,
                               int n, float* __restrict__ x_dst)
{
    int tid = blockIdx.x * blockDim.x + threadIdx.x;
    if (tid >= n * 64) return;
    int i = tid >> 6, c = tid & 63;
    x_dst[(size_t)i * 64 + c] = x_src[(size_t)idx[i] * 64 + c];
}

__global__ void posgather_kernel(const float* __restrict__ pos_src, const int* __restrict__ idx,
                                 int n, float* __restrict__ pos_dst)
{
    int tid = blockIdx.x * blockDim.x + threadIdx.x;
    if (tid >= n * 3) return;
    int i = tid / 3, d = tid - i * 3;
    pos_dst[tid] = pos_src[idx[i] * 3 + d];
}

__global__ void zero_kernel(float* __restrict__ p, int n)
{
    int i = blockIdx.x * blockDim.x + threadIdx.x;
    if (i < n) p[i] = 0.f;
}

// ---------------- Mean pool over clouds ----------------
__global__ void pool_kernel(const float* __restrict__ x3, const int* __restrict__ batch,
                            const int* __restrict__ idx1, const int* __restrict__ idx2, int n3,
                            float* __restrict__ gnum, float* __restrict__ cnt)
{
    int tid = blockIdx.x * blockDim.x + threadIdx.x;
    if (tid >= n3 * 128) return;
    int i = tid >> 7, c = tid & 127;
    int cloud = batch[idx1[idx2[i]]];
    fadd_atomic(&gnum[cloud * 128 + c], x3[(size_t)i * 128 + c]);
    if (c == 0) fadd_atomic(&cnt[cloud], 1.f);
}

// ---------------- Final MLP + log_softmax ----------------
__global__ void mlp_kernel(const float* __restrict__ gnum, const float* __restrict__ cnt,
                           const float* __restrict__ lw1, const float* __restrict__ lb1,
                           const float* __restrict__ lw2, const float* __restrict__ lb2,
                           const float* __restrict__ lw3, const float* __restrict__ lb3,
                           float* __restrict__ out)
{
    __shared__ float gv[128], h1[256], h2[256], lg[10];
    __shared__ float lse_s;
    int cl = blockIdx.x, t = threadIdx.x;   // blockDim = 256
    if (t < 128) gv[t] = gnum[cl * 128 + t] / fmaxf(cnt[cl], 1.f);
    __syncthreads();
    float a = lb1[t];
    for (int c = 0; c < 128; c++) a += gv[c] * lw1[c * 256 + t];
    h1[t] = elu_f(a);
    __syncthreads();
    a = lb2[t];
    for (int c = 0; c < 256; c++) a += h1[c] * lw2[c * 256 + t];
    h2[t] = elu_f(a);
    __syncthreads();
    if (t < 10) {
        a = lb3[t];
        for (int c = 0; c < 256; c++) a += h2[c] * lw3[c * 10 + t];
        lg[t] = a;
    }
    __syncthreads();
    if (t == 0) {
        float m = -1e30f;
        for (int i = 0; i < 10; i++) m = fmaxf(m, lg[i]);
        float s = 0.f;
        for (int i = 0; i < 10; i++) s += expf(lg[i] - m);
        lse_s = m + logf(s);
    }
    __syncthreads();
    if (t < 10) out[cl * 10 + t] = lg[t] - lse_s;
}

static void run_level(const unsigned* slots, const int* src, const int* rowptr,
                      const float* xin, const unsigned short* WfT, const float* bvec,
                      int n, int COUT, unsigned short* Abuf, int AbufRows, float* P,
                      float* xout, hipStream_t stream)
{
    int Ksz = KPAD / NSPLIT;
    for (int cs = 0; cs < n; cs += AbufRows) {
        int cr = min(AbufRows, n - cs);
        buildA_kernel<<<cr, 256, 0, stream>>>(slots, src, rowptr, xin, cs, Abuf);
        dim3 grid(cr / 64, COUT / 64, NSPLIT);
        gemm_kernel<<<grid, 256, 0, stream>>>(Abuf, WfT, cr, COUT, Ksz, KPAD, P);
        combine_kernel<<<(cr * COUT + 255) / 256, 256, 0, stream>>>(P, bvec, cr, COUT, NSPLIT,
                                                                    xout + (size_t)cs * COUT);
    }
}

extern "C" void kernel_launch(void* const* d_in, const int* in_sizes, int n_in,
                              void* d_out, int out_size, void* d_ws, size_t ws_size,
                              hipStream_t stream)
{
    const float* pos   = (const float*)d_in[0];
    const int*   batch = (const int*)d_in[1];
    const int*   src1  = (const int*)d_in[2];
    const int*   tgt1  = (const int*)d_in[3];
    const int*   src2  = (const int*)d_in[4];
    const int*   tgt2  = (const int*)d_in[5];
    const int*   src3  = (const int*)d_in[6];
    const int*   tgt3  = (const int*)d_in[7];
    const int*   idx1  = (const int*)d_in[8];
    const int*   idx2  = (const int*)d_in[9];
    const float* W1 = (const float*)d_in[10];
    const float* R1 = (const float*)d_in[11];
    const float* b1 = (const float*)d_in[12];
    const float* W2 = (const float*)d_in[13];
    const float* R2 = (const float*)d_in[14];
    const float* b2 = (const float*)d_in[15];
    const float* W3 = (const float*)d_in[16];
    const float* R3 = (const float*)d_in[17];
    const float* b3 = (const float*)d_in[18];
    const float* lw1 = (const float*)d_in[19];
    const float* lb1 = (const float*)d_in[20];
    const float* lw2 = (const float*)d_in[21];
    const float* lb2 = (const float*)d_in[22];
    const float* lw3 = (const float*)d_in[23];
    const float* lb3 = (const float*)d_in[24];

    int n1 = in_sizes[0] / 3;
    int E1 = in_sizes[2];
    int E2 = in_sizes[4];
    int E3 = in_sizes[6];
    int n2 = in_sizes[8];
    int n3 = in_sizes[9];

    float* ws = (float*)d_ws;
    float* x1   = ws;                               // n1*64
    float* x2in = x1   + (size_t)n1 * 64;           // n2*64
    float* x2o  = x2in + (size_t)n2 * 64;           // n2*64
    float* x3in = x2o  + (size_t)n2 * 64;           // n3*64
    float* x3o  = x3in + (size_t)n3 * 64;           // n3*128
    float* pos2 = x3o  + (size_t)n3 * 128;          // n2*3
    float* pos3 = pos2 + (size_t)n2 * 3;            // n3*3
    float* gnum = pos3 + (size_t)n3 * 3;            // 16*128
    float* cnt  = gnum + 16 * 128;                  // 16
    unsigned short* WfT1 = (unsigned short*)(cnt + 16);    // 64*128 bf16
    unsigned short* WfT2 = WfT1 + (size_t)64 * 128;        // 64*KPAD
    unsigned short* WfT3 = WfT2 + (size_t)64 * KPAD;       // 128*KPAD
    int*   rp1  = (int*)(WfT3 + (size_t)128 * KPAD);
    int*   rp2  = rp1 + ((n1 + 4) & ~3);
    int*   rp3  = rp2 + ((n2 + 4) & ~3);
    unsigned* slots1 = (unsigned*)(rp3 + ((n3 + 4) & ~3));
    unsigned* slots2 = slots1 + (size_t)E1 * 8;
    unsigned* slots3 = slots2 + (size_t)E2 * 8;
    unsigned short* A1buf = (unsigned short*)(slots3 + (size_t)E3 * 8);  // n1*128 bf16
    float*  P    = (float*)(A1buf + (size_t)n1 * 128);  // 8M floats
    unsigned short* Abuf = (unsigned short*)(P + (size_t)8 * 1024 * 1024);

    size_t usedBytes = (size_t)((char*)Abuf - (char*)ws);
    size_t availBytes = ws_size > usedBytes ? ws_size - usedBytes : 0;
    int maxRows = (int)(availBytes / ((size_t)KPAD * 2));
    maxRows &= ~63;
    if (maxRows < 64) maxRows = 64;
    int rowsP2 = ((8 * 1024 * 1024) / (NSPLIT * 64)) & ~63;
    int rowsP3 = ((8 * 1024 * 1024) / (NSPLIT * 128)) & ~63;
    int rows2 = min(min(maxRows, rowsP2), n2);
    int rows3 = min(min(maxRows, rowsP3), n3);

    float* out = (float*)d_out;

    // --- graph preprocessing ---
    rowptr_kernel<<<(E1 + 256) / 256, 256, 0, stream>>>(tgt1, E1, n1, rp1);
    rowptr_kernel<<<(E2 + 256) / 256, 256, 0, stream>>>(tgt2, E2, n2, rp2);
    rowptr_kernel<<<(E3 + 256) / 256, 256, 0, stream>>>(tgt3, E3, n3, rp3);
    posgather_kernel<<<(n2 * 3 + 255) / 256, 256, 0, stream>>>(pos, idx1, n2, pos2);
    posgather_kernel<<<(n3 * 3 + 255) / 256, 256, 0, stream>>>(pos2, idx2, n3, pos3);
    slots_kernel<<<(E1 + 255) / 256, 256, 0, stream>>>(pos,  src1, tgt1, E1, 2.5f,  126, slots1);
    slots_kernel<<<(E2 + 255) / 256, 256, 0, stream>>>(pos2, src2, tgt2, E2, 1.25f, 125, slots2);
    slots_kernel<<<(E3 + 255) / 256, 256, 0, stream>>>(pos3, src3, tgt3, E3, 0.5f,  125, slots3);
    concatWT_kernel<<<(64 * 128 + 255) / 256, 256, 0, stream>>>(W1, R1, 64, 128, KC, 1, WfT1);
    concatWT_kernel<<<(64 * KPAD + 255) / 256, 256, 0, stream>>>(W2, R2, 64, KPAD, KC * 64, 64, WfT2);
    concatWT_kernel<<<(128 * KPAD + 255) / 256, 256, 0, stream>>>(W3, R3, 128, KPAD, KC * 64, 64, WfT3);

    // --- level 1: histogram + GEMM(K=128) ---
    histo1_kernel<<<n1 / 4, 256, 0, stream>>>(slots1, rp1, A1buf);
    {
        dim3 g1(n1 / 64, 1, 1);
        gemm_kernel<<<g1, 256, 0, stream>>>(A1buf, WfT1, n1, 64, 128, 128, P);
        combine_kernel<<<(n1 * 64 + 255) / 256, 256, 0, stream>>>(P, b1, n1, 64, 1, x1);
    }
    xgather_kernel<<<(n2 * 64 + 255) / 256, 256, 0, stream>>>(x1, idx1, n2, x2in);

    // --- level 2 ---
    run_level(slots2, src2, rp2, x2in, WfT2, b2, n2, 64, Abuf, rows2, P, x2o, stream);
    xgather_kernel<<<(n3 * 64 + 255) / 256, 256, 0, stream>>>(x2o, idx2, n3, x3in);

    // --- level 3 ---
    run_level(slots3, src3, rp3, x3in, WfT3, b3, n3, 128, Abuf, rows3, P, x3o, stream);

    // --- pool + head ---
    zero_kernel<<<(16 * 128 + 16 + 255) / 256, 256, 0, stream>>>(gnum, 16 * 128 + 16);
    pool_kernel<<<(n3 * 128 + 255) / 256, 256, 0, stream>>>(x3o, batch, idx1, idx2, n3, gnum, cnt);
    mlp_kernel<<<16, 256, 0, stream>>>(gnum, cnt, lw1, lb1, lw2, lb2, lw3, lb3, out);
}

// Round 9
// 551.840 us; speedup vs baseline: 5.5944x; 1.0775x over previous
//
#include <hip/hip_runtime.h>
#include <hip/hip_bf16.h>
#include <math.h>

#define KDIM 5
#define KC 125
#define KPAD 8192   // 125*64 spline rows + 64 root rows + 128 zero pad (levels 2/3)
#define EPB 32      // edges staged per tile (max_nb = 32)
#define NSPLIT 8    // GEMM K-split for levels 2/3
#define LDA 72      // GEMM LDS tile row stride in bf16 (64 + 8 pad)
#define ASTR 66     // buildA LDS row stride in floats (even -> float2 aligned)

typedef short bf16x8 __attribute__((ext_vector_type(8)));
typedef float f32x4 __attribute__((ext_vector_type(4)));

__device__ __forceinline__ float elu_f(float x) { return x > 0.f ? x : (expf(x) - 1.f); }

__device__ __forceinline__ void fadd_atomic(float* p, float v) {
    unsafeAtomicAdd(p, v);
}

__device__ __forceinline__ unsigned short f2bf(float x) {
    union { float f; unsigned u; } v; v.f = x;
    unsigned r = (v.u + 0x7FFFu + ((v.u >> 16) & 1u)) >> 16;
    return (unsigned short)r;
}
// HW packed cvt: v_cvt_pk_bf16_f32 (RNE, matches f2bf)
__device__ __forceinline__ unsigned pack2(float lo, float hi) {
    __hip_bfloat162 h = __float22bfloat162_rn(make_float2(lo, hi));
    unsigned r; __builtin_memcpy(&r, &h, 4); return r;
}

// ---------------- rowptr: tgt is sorted; rowptr[v] = first edge with tgt >= v ----------------
__global__ void rowptr_kernel(const int* __restrict__ tgt, int E, int n, int* __restrict__ rowptr)
{
    int e = blockIdx.x * blockDim.x + threadIdx.x;
    if (e > E) return;
    if (e < E) {
        int t = tgt[e];
        int p = (e == 0) ? -1 : tgt[e - 1];
        for (int v = p + 1; v <= t; v++) rowptr[v] = e;
    } else {
        int p = tgt[E - 1];
        for (int v = p + 1; v <= n; v++) rowptr[v] = E;
    }
}

// ---------------- slot table: per edge 8 words = (w with wi packed in low 7 mantissa bits) ----
__global__ void slots_kernel(const float* __restrict__ posL, const int* __restrict__ src,
                             const int* __restrict__ tgt, int E, float rinv2, int sinkrow,
                             unsigned* __restrict__ slots)
{
    int e = blockIdx.x * blockDim.x + threadIdx.x;
    if (e >= E) return;
    int s = src[e], t = tgt[e];
    float p0 = fminf(fmaxf((posL[t*3+0] - posL[s*3+0]) * rinv2 + 0.5f, 0.f), 1.f);
    float p1 = fminf(fmaxf((posL[t*3+1] - posL[s*3+1]) * rinv2 + 0.5f, 0.f), 1.f);
    float p2 = fminf(fmaxf((posL[t*3+2] - posL[s*3+2]) * rinv2 + 0.5f, 0.f), 1.f);
    float v0 = p0 * (KDIM - 1), v1 = p1 * (KDIM - 1), v2 = p2 * (KDIM - 1);
    int b0 = (int)floorf(v0), b1 = (int)floorf(v1), b2 = (int)floorf(v2);
    float f0 = v0 - (float)b0, f1 = v1 - (float)b1, f2 = v2 - (float)b2;
    unsigned out[8];
    #pragma unroll
    for (int sb = 0; sb < 8; sb++) {
        int i0 = sb & 1, i1 = (sb >> 1) & 1, i2 = (sb >> 2) & 1;
        float w = (i0 ? f0 : 1.f - f0) * (i1 ? f1 : 1.f - f1) * (i2 ? f2 : 1.f - f2);
        int k0 = min(b0 + i0, KDIM - 1), k1 = min(b1 + i1, KDIM - 1), k2 = min(b2 + i2, KDIM - 1);
        int wi = k0 + KDIM * k1 + KDIM * KDIM * k2;
        if (w == 0.f) wi = sinkrow;
        out[sb] = (__float_as_uint(w) & ~127u) | (unsigned)wi;
    }
    uint4* dst = (uint4*)&slots[(size_t)e * 8];
    dst[0] = make_uint4(out[0], out[1], out[2], out[3]);
    dst[1] = make_uint4(out[4], out[5], out[6], out[7]);
}

// ---------------- Level 1 histogram: one wave per node, A1 bf16 [node][128] ----------------
__global__ __launch_bounds__(256) void histo1_kernel(const unsigned* __restrict__ slots,
                                                     const int* __restrict__ rowptr,
                                                     unsigned short* __restrict__ Aout)
{
    __shared__ float A1s[4][128];
    int wave = threadIdx.x >> 6, lane = threadIdx.x & 63;
    int node = blockIdx.x * 4 + wave;
    A1s[wave][lane] = 0.f;
    A1s[wave][64 + lane] = 0.f;
    int rs = rowptr[node], re = rowptr[node + 1];
    for (int e = rs + lane; e < re; e += 64) {
        uint4 s0 = *(const uint4*)&slots[(size_t)e * 8];
        uint4 s1 = *(const uint4*)&slots[(size_t)e * 8 + 4];
        unsafeAtomicAdd(&A1s[wave][s0.x & 127u], __uint_as_float(s0.x));
        unsafeAtomicAdd(&A1s[wave][s0.y & 127u], __uint_as_float(s0.y));
        unsafeAtomicAdd(&A1s[wave][s0.z & 127u], __uint_as_float(s0.z));
        unsafeAtomicAdd(&A1s[wave][s0.w & 127u], __uint_as_float(s0.w));
        unsafeAtomicAdd(&A1s[wave][s1.x & 127u], __uint_as_float(s1.x));
        unsafeAtomicAdd(&A1s[wave][s1.y & 127u], __uint_as_float(s1.y));
        unsafeAtomicAdd(&A1s[wave][s1.z & 127u], __uint_as_float(s1.z));
        unsafeAtomicAdd(&A1s[wave][s1.w & 127u], __uint_as_float(s1.w));
    }
    __syncthreads();
    float deg = (float)(re - rs);
    float invdeg = 1.f / fmaxf(deg, 1.f);
    if (lane == 0) {
        A1s[wave][125] = fmaxf(deg, 1.f);
        A1s[wave][126] = 0.f;
        A1s[wave][127] = 0.f;
    }
    __syncthreads();
    unsigned* out = (unsigned*)(Aout + (size_t)node * 128);
    out[lane] = pack2(A1s[wave][2 * lane] * invdeg, A1s[wave][2 * lane + 1] * invdeg);
}

// ---------------- buildA (levels 2/3): atomic-free float2 RMW, 8 slots/wave-instr ----------
// Wave w owns channels [16w,16w+16) as 8 pairs. Lanes = 8 slot-groups x 8 channel-pairs.
__global__ __launch_bounds__(256) void buildA_kernel(
    const unsigned* __restrict__ slots, const int* __restrict__ src,
    const int* __restrict__ rowptr, const float* __restrict__ xin,
    int nodeBase, unsigned short* __restrict__ Aout)
{
    __shared__ float A[8320];                 // 126 rows x stride 66 (sink row = 125)
    __shared__ unsigned Xs[EPB * 32];         // x_j as packed bf16 pairs
    __shared__ unsigned Ss[EPB * 8];
    __shared__ int Es[EPB];
    int node = nodeBase + blockIdx.x;
    int t = threadIdx.x;                      // blockDim = 256
    for (int i = t; i < 2080; i += 256) ((float4*)A)[i] = make_float4(0.f, 0.f, 0.f, 0.f);
    int rs = rowptr[node], re = rowptr[node + 1];

    int wave = t >> 6, lane = t & 63;
    int sgrp = lane >> 3;                     // slot 0..7
    int jp = lane & 7;                        // channel pair 0..7
    int c0 = wave * 16 + jp * 2;              // owned channel pair base
    int cpi = wave * 8 + jp;                  // pair index 0..31

    for (int ts = rs; ts < re; ts += EPB) {
        int ne = min(EPB, re - ts);
        __syncthreads();                      // protect staging reuse across tiles
        if (t < ne) Es[t] = src[ts + t];
        if (t < ne * 8) Ss[t] = slots[(size_t)ts * 8 + t];
        __syncthreads();
        for (int i = t; i < ne * 32; i += 256) {
            int el = i >> 5, cp = i & 31;
            const float* xp = &xin[(size_t)Es[el] * 64 + cp * 2];
            Xs[i] = pack2(xp[0], xp[1]);
        }
        __syncthreads();
        for (int et = 0; et < ne; et++) {
            unsigned word = Ss[et * 8 + sgrp];            // broadcast across 8 lanes
            unsigned xw = Xs[et * 32 + cpi];              // broadcast across 8 sgrps
            int wi = word & 127u;
            float w = __uint_as_float(word);
            float x0 = __uint_as_float(xw << 16);
            float x1 = __uint_as_float(xw & 0xFFFF0000u);
            float* ap = &A[wi * ASTR + c0];
            float2 av = *(float2*)ap;                     // unique writer per address
            av.x += w * x0;
            av.y += w * x1;
            *(float2*)ap = av;
        }
    }
    __syncthreads();
    float invdeg = 1.f / fmaxf((float)(re - rs), 1.f);
    unsigned short* out = Aout + (size_t)blockIdx.x * KPAD;
    for (int u = t; u < 1000; u += 256) {     // unit = (wi, 8-channel group)
        int wi = u >> 3, cg = (u & 7) * 8;
        const float* Ap = &A[wi * ASTR + cg];
        float2 q0 = *(const float2*)&Ap[0];
        float2 q1 = *(const float2*)&Ap[2];
        float2 q2 = *(const float2*)&Ap[4];
        float2 q3 = *(const float2*)&Ap[6];
        uint4 pk;
        pk.x = pack2(q0.x * invdeg, q0.y * invdeg);
        pk.y = pack2(q1.x * invdeg, q1.y * invdeg);
        pk.z = pack2(q2.x * invdeg, q2.y * invdeg);
        pk.w = pack2(q3.x * invdeg, q3.y * invdeg);
        *(uint4*)&out[wi * 64 + cg] = pk;
    }
    if (t < 8) {                              // root rows = x[node]
        const float* xr = xin + (size_t)node * 64 + t * 8;
        uint4 pk;
        pk.x = pack2(xr[0], xr[1]);
        pk.y = pack2(xr[2], xr[3]);
        pk.z = pack2(xr[4], xr[5]);
        pk.w = pack2(xr[6], xr[7]);
        *(uint4*)&out[8000 + t * 8] = pk;
    } else if (t < 24) {                      // zero padding rows 8064..8191
        *(uint4*)&out[8064 + (t - 8) * 8] = make_uint4(0, 0, 0, 0);
    }
}

// ---------------- concat + transpose weights to bf16: WfT[n][k], K padded ----------------
__global__ void concatWT_kernel(const float* __restrict__ W, const float* __restrict__ R,
                                int COUT, int kpad, int krows, int cin,
                                unsigned short* __restrict__ WfT)
{
    int i = blockIdx.x * blockDim.x + threadIdx.x;
    if (i >= COUT * kpad) return;
    int n = i / kpad, k = i - n * kpad;
    float v = 0.f;
    if (k < krows) v = W[(size_t)k * COUT + n];
    else if (k < krows + cin) v = R[(size_t)(k - krows) * COUT + n];
    WfT[i] = f2bf(v);
}

// ---------------- bf16 MFMA GEMM: P[z] = A[:, zslice] x BT[:, zslice]^T ----------------
__global__ __launch_bounds__(256) void gemm_kernel(const unsigned short* __restrict__ A,
                                                   const unsigned short* __restrict__ BT,
                                                   int Mrows, int COUT, int Ksz, int lda,
                                                   float* __restrict__ P)
{
    __shared__ unsigned short As[64 * LDA];
    __shared__ unsigned short Bs[64 * LDA];
    int t = threadIdx.x;
    int mblk = blockIdx.x * 64, nblk = blockIdx.y * 64;
    int kBase = blockIdx.z * Ksz;

    int lr = t >> 2;                 // staging row 0..63
    int lc = (t & 3) * 16;           // staging col (bf16 units)

    const unsigned short* Ap = A + (size_t)(mblk + lr) * lda + kBase + lc;
    const unsigned short* Bp = BT + (size_t)(nblk + lr) * lda + kBase + lc;

    uint4 a0 = *(const uint4*)Ap;  uint4 a1 = *(const uint4*)(Ap + 8);
    uint4 b0 = *(const uint4*)Bp;  uint4 b1 = *(const uint4*)(Bp + 8);

    int wave = t >> 6, lane = t & 63;
    int mw = (wave & 1) * 32, nw = (wave >> 1) * 32;
    int fr = lane & 15;
    int fq = (lane >> 4) * 8;

    f32x4 acc[2][2];
    #pragma unroll
    for (int i = 0; i < 2; i++)
        #pragma unroll
        for (int j = 0; j < 2; j++) acc[i][j] = (f32x4){0.f, 0.f, 0.f, 0.f};

    int ktiles = Ksz / 64;
    for (int kt = 0; kt < ktiles; kt++) {
        *(uint4*)&As[lr * LDA + lc]     = a0;
        *(uint4*)&As[lr * LDA + lc + 8] = a1;
        *(uint4*)&Bs[lr * LDA + lc]     = b0;
        *(uint4*)&Bs[lr * LDA + lc + 8] = b1;
        __syncthreads();
        if (kt + 1 < ktiles) {
            Ap += 64; Bp += 64;
            a0 = *(const uint4*)Ap; a1 = *(const uint4*)(Ap + 8);
            b0 = *(const uint4*)Bp; b1 = *(const uint4*)(Bp + 8);
        }
        #pragma unroll
        for (int ks = 0; ks < 2; ks++) {
            bf16x8 af0 = *(const bf16x8*)&As[(mw + fr) * LDA + ks * 32 + fq];
            bf16x8 af1 = *(const bf16x8*)&As[(mw + 16 + fr) * LDA + ks * 32 + fq];
            bf16x8 bg0 = *(const bf16x8*)&Bs[(nw + fr) * LDA + ks * 32 + fq];
            bf16x8 bg1 = *(const bf16x8*)&Bs[(nw + 16 + fr) * LDA + ks * 32 + fq];
            acc[0][0] = __builtin_amdgcn_mfma_f32_16x16x32_bf16(af0, bg0, acc[0][0], 0, 0, 0);
            acc[0][1] = __builtin_amdgcn_mfma_f32_16x16x32_bf16(af0, bg1, acc[0][1], 0, 0, 0);
            acc[1][0] = __builtin_amdgcn_mfma_f32_16x16x32_bf16(af1, bg0, acc[1][0], 0, 0, 0);
            acc[1][1] = __builtin_amdgcn_mfma_f32_16x16x32_bf16(af1, bg1, acc[1][1], 0, 0, 0);
        }
        __syncthreads();
    }
    float* Pz = P + (size_t)blockIdx.z * Mrows * COUT;
    int crow = (lane >> 4) * 4, ccol = lane & 15;
    #pragma unroll
    for (int i = 0; i < 2; i++)
        #pragma unroll
        for (int j = 0; j < 2; j++) {
            int m0 = mblk + mw + i * 16 + crow;
            int n0 = nblk + nw + j * 16 + ccol;
            #pragma unroll
            for (int r = 0; r < 4; r++)
                Pz[(size_t)(m0 + r) * COUT + n0] = acc[i][j][r];
        }
}

// ---------------- combine K-split partials + bias + ELU ----------------
__global__ void combine_kernel(const float* __restrict__ P, const float* __restrict__ b,
                               int Mrows, int COUT, int NS, float* __restrict__ xout)
{
    int i = blockIdx.x * blockDim.x + threadIdx.x;
    int total = Mrows * COUT;
    if (i >= total) return;
    float s = 0.f;
    for (int z = 0; z < NS; z++) s += P[(size_t)z * total + i];
    int o = i % COUT;
    xout[i] = elu_f(s + b[o]);
}

// ---------------- gathers ----------------
__global__ void xgather_kernel(const float* __restrict__ x_src, const int* __restrict__ idx,
                               int n, float* __restrict__ x_dst)
{
    int tid = blockIdx.x * blockDim.x + threadIdx.x;
    if (tid >= n * 64) return;
    int i = tid >> 6, c = tid & 63;
    x_dst[(size_t)i * 64 + c] = x_src[(size_t)idx[i] * 64 + c];
}

__global__ void posgather_kernel(const float* __restrict__ pos_src, const int* __restrict__ idx,
                                 int n, float* __restrict__ pos_dst)
{
    int tid = blockIdx.x * blockDim.x + threadIdx.x;
    if (tid >= n * 3) return;
    int i = tid / 3, d = tid - i * 3;
    pos_dst[tid] = pos_src[idx[i] * 3 + d];
}

__global__ void zero_kernel(float* __restrict__ p, int n)
{
    int i = blockIdx.x * blockDim.x + threadIdx.x;
    if (i < n) p[i] = 0.f;
}

// ---------------- Mean pool over clouds ----------------
__global__ void pool_kernel(const float* __restrict__ x3, const int* __restrict__ batch,
                            const int* __restrict__ idx1, const int* __restrict__ idx2, int n3,
                            float* __restrict__ gnum, float* __restrict__ cnt)
{
    int tid = blockIdx.x * blockDim.x + threadIdx.x;
    if (tid >= n3 * 128) return;
    int i = tid >> 7, c = tid & 127;
    int cloud = batch[idx1[idx2[i]]];
    fadd_atomic(&gnum[cloud * 128 + c], x3[(size_t)i * 128 + c]);
    if (c == 0) fadd_atomic(&cnt[cloud], 1.f);
}

// ---------------- Final MLP + log_softmax ----------------
__global__ void mlp_kernel(const float* __restrict__ gnum, const float* __restrict__ cnt,
                           const float* __restrict__ lw1, const float* __restrict__ lb1,
                           const float* __restrict__ lw2, const float* __restrict__ lb2,
                           const float* __restrict__ lw3, const float* __restrict__ lb3,
                           float* __restrict__ out)
{
    __shared__ float gv[128], h1[256], h2[256], lg[10];
    __shared__ float lse_s;
    int cl = blockIdx.x, t = threadIdx.x;   // blockDim = 256
    if (t < 128) gv[t] = gnum[cl * 128 + t] / fmaxf(cnt[cl], 1.f);
    __syncthreads();
    float a = lb1[t];
    for (int c = 0; c < 128; c++) a += gv[c] * lw1[c * 256 + t];
    h1[t] = elu_f(a);
    __syncthreads();
    a = lb2[t];
    for (int c = 0; c < 256; c++) a += h1[c] * lw2[c * 256 + t];
    h2[t] = elu_f(a);
    __syncthreads();
    if (t < 10) {
        a = lb3[t];
        for (int c = 0; c < 256; c++) a += h2[c] * lw3[c * 10 + t];
        lg[t] = a;
    }
    __syncthreads();
    if (t == 0) {
        float m = -1e30f;
        for (int i = 0; i < 10; i++) m = fmaxf(m, lg[i]);
        float s = 0.f;
        for (int i = 0; i < 10; i++) s += expf(lg[i] - m);
        lse_s = m + logf(s);
    }
    __syncthreads();
    if (t < 10) out[cl * 10 + t] = lg[t] - lse_s;
}

static void run_level(const unsigned* slots, const int* src, const int* rowptr,
                      const float* xin, const unsigned short* WfT, const float* bvec,
                      int n, int COUT, unsigned short* Abuf, int AbufRows, float* P,
                      float* xout, hipStream_t stream)
{
    int Ksz = KPAD / NSPLIT;
    for (int cs = 0; cs < n; cs += AbufRows) {
        int cr = min(AbufRows, n - cs);
        buildA_kernel<<<cr, 256, 0, stream>>>(slots, src, rowptr, xin, cs, Abuf);
        dim3 grid(cr / 64, COUT / 64, NSPLIT);
        gemm_kernel<<<grid, 256, 0, stream>>>(Abuf, WfT, cr, COUT, Ksz, KPAD, P);
        combine_kernel<<<(cr * COUT + 255) / 256, 256, 0, stream>>>(P, bvec, cr, COUT, NSPLIT,
                                                                    xout + (size_t)cs * COUT);
    }
}

extern "C" void kernel_launch(void* const* d_in, const int* in_sizes, int n_in,
                              void* d_out, int out_size, void* d_ws, size_t ws_size,
                              hipStream_t stream)
{
    const float* pos   = (const float*)d_in[0];
    const int*   batch = (const int*)d_in[1];
    const int*   src1  = (const int*)d_in[2];
    const int*   tgt1  = (const int*)d_in[3];
    const int*   src2  = (const int*)d_in[4];
    const int*   tgt2  = (const int*)d_in[5];
    const int*   src3  = (const int*)d_in[6];
    const int*   tgt3  = (const int*)d_in[7];
    const int*   idx1  = (const int*)d_in[8];
    const int*   idx2  = (const int*)d_in[9];
    const float* W1 = (const float*)d_in[10];
    const float* R1 = (const float*)d_in[11];
    const float* b1 = (const float*)d_in[12];
    const float* W2 = (const float*)d_in[13];
    const float* R2 = (const float*)d_in[14];
    const float* b2 = (const float*)d_in[15];
    const float* W3 = (const float*)d_in[16];
    const float* R3 = (const float*)d_in[17];
    const float* b3 = (const float*)d_in[18];
    const float* lw1 = (const float*)d_in[19];
    const float* lb1 = (const float*)d_in[20];
    const float* lw2 = (const float*)d_in[21];
    const float* lb2 = (const float*)d_in[22];
    const float* lw3 = (const float*)d_in[23];
    const float* lb3 = (const float*)d_in[24];

    int n1 = in_sizes[0] / 3;
    int E1 = in_sizes[2];
    int E2 = in_sizes[4];
    int E3 = in_sizes[6];
    int n2 = in_sizes[8];
    int n3 = in_sizes[9];

    float* ws = (float*)d_ws;
    float* x1   = ws;                               // n1*64
    float* x2in = x1   + (size_t)n1 * 64;           // n2*64
    float* x2o  = x2in + (size_t)n2 * 64;           // n2*64
    float* x3in = x2o  + (size_t)n2 * 64;           // n3*64
    float* x3o  = x3in + (size_t)n3 * 64;           // n3*128
    float* pos2 = x3o  + (size_t)n3 * 128;          // n2*3
    float* pos3 = pos2 + (size_t)n2 * 3;            // n3*3
    float* gnum = pos3 + (size_t)n3 * 3;            // 16*128
    float* cnt  = gnum + 16 * 128;                  // 16
    unsigned short* WfT1 = (unsigned short*)(cnt + 16);    // 64*128 bf16
    unsigned short* WfT2 = WfT1 + (size_t)64 * 128;        // 64*KPAD
    unsigned short* WfT3 = WfT2 + (size_t)64 * KPAD;       // 128*KPAD
    int*   rp1  = (int*)(WfT3 + (size_t)128 * KPAD);
    int*   rp2  = rp1 + ((n1 + 4) & ~3);
    int*   rp3  = rp2 + ((n2 + 4) & ~3);
    unsigned* slots1 = (unsigned*)(rp3 + ((n3 + 4) & ~3));
    unsigned* slots2 = slots1 + (size_t)E1 * 8;
    unsigned* slots3 = slots2 + (size_t)E2 * 8;
    unsigned short* A1buf = (unsigned short*)(slots3 + (size_t)E3 * 8);  // n1*128 bf16
    float*  P    = (float*)(A1buf + (size_t)n1 * 128);  // 8M floats
    unsigned short* Abuf = (unsigned short*)(P + (size_t)8 * 1024 * 1024);

    size_t usedBytes = (size_t)((char*)Abuf - (char*)ws);
    size_t availBytes = ws_size > usedBytes ? ws_size - usedBytes : 0;
    int maxRows = (int)(availBytes / ((size_t)KPAD * 2));
    maxRows &= ~63;
    if (maxRows < 64) maxRows = 64;
    int rowsP2 = ((8 * 1024 * 1024) / (NSPLIT * 64)) & ~63;
    int rowsP3 = ((8 * 1024 * 1024) / (NSPLIT * 128)) & ~63;
    int rows2 = min(min(maxRows, rowsP2), n2);
    int rows3 = min(min(maxRows, rowsP3), n3);

    float* out = (float*)d_out;

    // --- graph preprocessing ---
    rowptr_kernel<<<(E1 + 256) / 256, 256, 0, stream>>>(tgt1, E1, n1, rp1);
    rowptr_kernel<<<(E2 + 256) / 256, 256, 0, stream>>>(tgt2, E2, n2, rp2);
    rowptr_kernel<<<(E3 + 256) / 256, 256, 0, stream>>>(tgt3, E3, n3, rp3);
    posgather_kernel<<<(n2 * 3 + 255) / 256, 256, 0, stream>>>(pos, idx1, n2, pos2);
    posgather_kernel<<<(n3 * 3 + 255) / 256, 256, 0, stream>>>(pos2, idx2, n3, pos3);
    slots_kernel<<<(E1 + 255) / 256, 256, 0, stream>>>(pos,  src1, tgt1, E1, 2.5f,  126, slots1);
    slots_kernel<<<(E2 + 255) / 256, 256, 0, stream>>>(pos2, src2, tgt2, E2, 1.25f, 125, slots2);
    slots_kernel<<<(E3 + 255) / 256, 256, 0, stream>>>(pos3, src3, tgt3, E3, 0.5f,  125, slots3);
    concatWT_kernel<<<(64 * 128 + 255) / 256, 256, 0, stream>>>(W1, R1, 64, 128, KC, 1, WfT1);
    concatWT_kernel<<<(64 * KPAD + 255) / 256, 256, 0, stream>>>(W2, R2, 64, KPAD, KC * 64, 64, WfT2);
    concatWT_kernel<<<(128 * KPAD + 255) / 256, 256, 0, stream>>>(W3, R3, 128, KPAD, KC * 64, 64, WfT3);

    // --- level 1: histogram + GEMM(K=128) ---
    histo1_kernel<<<n1 / 4, 256, 0, stream>>>(slots1, rp1, A1buf);
    {
        dim3 g1(n1 / 64, 1, 1);
        gemm_kernel<<<g1, 256, 0, stream>>>(A1buf, WfT1, n1, 64, 128, 128, P);
        combine_kernel<<<(n1 * 64 + 255) / 256, 256, 0, stream>>>(P, b1, n1, 64, 1, x1);
    }
    xgather_kernel<<<(n2 * 64 + 255) / 256, 256, 0, stream>>>(x1, idx1, n2, x2in);

    // --- level 2 ---
    run_level(slots2, src2, rp2, x2in, WfT2, b2, n2, 64, Abuf, rows2, P, x2o, stream);
    xgather_kernel<<<(n3 * 64 + 255) / 256, 256, 0, stream>>>(x2o, idx2, n3, x3in);

    // --- level 3 ---
    run_level(slots3, src3, rp3, x3in, WfT3, b3, n3, 128, Abuf, rows3, P, x3o, stream);

    // --- pool + head ---
    zero_kernel<<<(16 * 128 + 16 + 255) / 256, 256, 0, stream>>>(gnum, 16 * 128 + 16);
    pool_kernel<<<(n3 * 128 + 255) / 256, 256, 0, stream>>>(x3o, batch, idx1, idx2, n3, gnum, cnt);
    mlp_kernel<<<16, 256, 0, stream>>>(gnum, cnt, lw1, lb1, lw2, lb2, lw3, lb3, out);
}

// Round 10
// 519.217 us; speedup vs baseline: 5.9459x; 1.0628x over previous
//
#include <hip/hip_runtime.h>
#include <hip/hip_bf16.h>
#include <math.h>

#define KDIM 5
#define KC 125
#define KPAD 8192   // 125*64 spline rows + 64 root rows + 128 zero pad (levels 2/3)
#define EPB 32      // edges per MFMA K-step (max_nb = 32)
#define NSPLIT 8    // GEMM K-split for levels 2/3
#define LDA 72      // GEMM LDS tile row stride in bf16 (64 + 8 pad)
#define SSTR 40     // buildA S row stride in bf16 (32 + 8: 16B-aligned rows, banks spread)
#define XSTR 40     // buildA XT row stride in bf16

typedef short bf16x8 __attribute__((ext_vector_type(8)));
typedef float f32x4 __attribute__((ext_vector_type(4)));

__device__ __forceinline__ float elu_f(float x) { return x > 0.f ? x : (expf(x) - 1.f); }

__device__ __forceinline__ void fadd_atomic(float* p, float v) {
    unsafeAtomicAdd(p, v);
}

__device__ __forceinline__ unsigned short f2bf(float x) {
    union { float f; unsigned u; } v; v.f = x;
    unsigned r = (v.u + 0x7FFFu + ((v.u >> 16) & 1u)) >> 16;
    return (unsigned short)r;
}
// HW packed cvt: v_cvt_pk_bf16_f32 (RNE, matches f2bf)
__device__ __forceinline__ unsigned pack2(float lo, float hi) {
    __hip_bfloat162 h = __float22bfloat162_rn(make_float2(lo, hi));
    unsigned r; __builtin_memcpy(&r, &h, 4); return r;
}

// ---------------- rowptr: tgt is sorted; rowptr[v] = first edge with tgt >= v ----------------
__global__ void rowptr_kernel(const int* __restrict__ tgt, int E, int n, int* __restrict__ rowptr)
{
    int e = blockIdx.x * blockDim.x + threadIdx.x;
    if (e > E) return;
    if (e < E) {
        int t = tgt[e];
        int p = (e == 0) ? -1 : tgt[e - 1];
        for (int v = p + 1; v <= t; v++) rowptr[v] = e;
    } else {
        int p = tgt[E - 1];
        for (int v = p + 1; v <= n; v++) rowptr[v] = E;
    }
}

// ---------------- slot table: per edge 8 words = (w with wi packed in low 7 mantissa bits) ----
__global__ void slots_kernel(const float* __restrict__ posL, const int* __restrict__ src,
                             const int* __restrict__ tgt, int E, float rinv2, int sinkrow,
                             unsigned* __restrict__ slots)
{
    int e = blockIdx.x * blockDim.x + threadIdx.x;
    if (e >= E) return;
    int s = src[e], t = tgt[e];
    float p0 = fminf(fmaxf((posL[t*3+0] - posL[s*3+0]) * rinv2 + 0.5f, 0.f), 1.f);
    float p1 = fminf(fmaxf((posL[t*3+1] - posL[s*3+1]) * rinv2 + 0.5f, 0.f), 1.f);
    float p2 = fminf(fmaxf((posL[t*3+2] - posL[s*3+2]) * rinv2 + 0.5f, 0.f), 1.f);
    float v0 = p0 * (KDIM - 1), v1 = p1 * (KDIM - 1), v2 = p2 * (KDIM - 1);
    int b0 = (int)floorf(v0), b1 = (int)floorf(v1), b2 = (int)floorf(v2);
    float f0 = v0 - (float)b0, f1 = v1 - (float)b1, f2 = v2 - (float)b2;
    unsigned out[8];
    #pragma unroll
    for (int sb = 0; sb < 8; sb++) {
        int i0 = sb & 1, i1 = (sb >> 1) & 1, i2 = (sb >> 2) & 1;
        float w = (i0 ? f0 : 1.f - f0) * (i1 ? f1 : 1.f - f1) * (i2 ? f2 : 1.f - f2);
        int k0 = min(b0 + i0, KDIM - 1), k1 = min(b1 + i1, KDIM - 1), k2 = min(b2 + i2, KDIM - 1);
        int wi = k0 + KDIM * k1 + KDIM * KDIM * k2;
        if (w == 0.f) wi = sinkrow;
        out[sb] = (__float_as_uint(w) & ~127u) | (unsigned)wi;
    }
    uint4* dst = (uint4*)&slots[(size_t)e * 8];
    dst[0] = make_uint4(out[0], out[1], out[2], out[3]);
    dst[1] = make_uint4(out[4], out[5], out[6], out[7]);
}

// ---------------- Level 1 histogram: one wave per node, A1 bf16 [node][128] ----------------
__global__ __launch_bounds__(256) void histo1_kernel(const unsigned* __restrict__ slots,
                                                     const int* __restrict__ rowptr,
                                                     unsigned short* __restrict__ Aout)
{
    __shared__ float A1s[4][128];
    int wave = threadIdx.x >> 6, lane = threadIdx.x & 63;
    int node = blockIdx.x * 4 + wave;
    A1s[wave][lane] = 0.f;
    A1s[wave][64 + lane] = 0.f;
    int rs = rowptr[node], re = rowptr[node + 1];
    for (int e = rs + lane; e < re; e += 64) {
        uint4 s0 = *(const uint4*)&slots[(size_t)e * 8];
        uint4 s1 = *(const uint4*)&slots[(size_t)e * 8 + 4];
        unsafeAtomicAdd(&A1s[wave][s0.x & 127u], __uint_as_float(s0.x));
        unsafeAtomicAdd(&A1s[wave][s0.y & 127u], __uint_as_float(s0.y));
        unsafeAtomicAdd(&A1s[wave][s0.z & 127u], __uint_as_float(s0.z));
        unsafeAtomicAdd(&A1s[wave][s0.w & 127u], __uint_as_float(s0.w));
        unsafeAtomicAdd(&A1s[wave][s1.x & 127u], __uint_as_float(s1.x));
        unsafeAtomicAdd(&A1s[wave][s1.y & 127u], __uint_as_float(s1.y));
        unsafeAtomicAdd(&A1s[wave][s1.z & 127u], __uint_as_float(s1.z));
        unsafeAtomicAdd(&A1s[wave][s1.w & 127u], __uint_as_float(s1.w));
    }
    __syncthreads();
    float deg = (float)(re - rs);
    float invdeg = 1.f / fmaxf(deg, 1.f);
    if (lane == 0) {
        A1s[wave][125] = fmaxf(deg, 1.f);
        A1s[wave][126] = 0.f;
        A1s[wave][127] = 0.f;
    }
    __syncthreads();
    unsigned* out = (unsigned*)(Aout + (size_t)node * 128);
    out[lane] = pack2(A1s[wave][2 * lane] * invdeg, A1s[wave][2 * lane + 1] * invdeg);
}

// ---------------- buildA (levels 2/3): MFMA formulation ----------------
// A[128 wi x 64 c] = S[128 wi x 32 e] x X[32 e x 64 c]; deg <= 32 = one K-step.
// Wave w owns wi-tiles {2w, 2w+1}; accumulators hold the full 128x64 tile.
__global__ __launch_bounds__(256) void buildA_kernel(
    const unsigned* __restrict__ slots, const int* __restrict__ src,
    const int* __restrict__ rowptr, const float* __restrict__ xin,
    int nodeBase, unsigned short* __restrict__ Aout)
{
    __shared__ __attribute__((aligned(16))) unsigned short S[128 * SSTR];   // S[wi][e]
    __shared__ __attribute__((aligned(16))) unsigned short XT[64 * XSTR];   // XT[c][e]
    __shared__ int Es[EPB];
    int node = nodeBase + blockIdx.x;
    int t = threadIdx.x;                      // blockDim = 256
    int rs = rowptr[node], re = rowptr[node + 1];
    int wave = t >> 6, lane = t & 63;
    int fr = lane & 15, fq = (lane >> 4) * 8;

    f32x4 acc[2][4];
    #pragma unroll
    for (int i = 0; i < 2; i++)
        #pragma unroll
        for (int j = 0; j < 4; j++) acc[i][j] = (f32x4){0.f, 0.f, 0.f, 0.f};

    for (int ts = rs; ts < re; ts += EPB) {
        int ne = min(EPB, re - ts);
        __syncthreads();                      // prior MFMA reads done before re-zero
        for (int i = t; i < 128 * SSTR / 2; i += 256) ((unsigned*)S)[i] = 0;
        for (int i = t; i < 64 * XSTR / 2; i += 256) ((unsigned*)XT)[i] = 0;
        if (t < ne) Es[t] = src[ts + t];
        __syncthreads();
        if (t < ne * 8) {                     // scatter slot weights into S (bf16)
            int e = t >> 3;
            unsigned word = slots[(size_t)(ts + e) * 8 + (t & 7)];
            int wi = word & 127u;
            S[wi * SSTR + e] = f2bf(__uint_as_float(word & ~127u));
        }
        for (int i = t; i < ne * 64; i += 256) {   // stage X^T (coalesced global reads)
            int c = i & 63, el = i >> 6;
            XT[c * XSTR + el] = f2bf(xin[(size_t)Es[el] * 64 + c]);
        }
        __syncthreads();
        #pragma unroll
        for (int i = 0; i < 2; i++) {
            bf16x8 af = *(const bf16x8*)&S[((2 * wave + i) * 16 + fr) * SSTR + fq];
            #pragma unroll
            for (int j = 0; j < 4; j++) {
                bf16x8 bg = *(const bf16x8*)&XT[(j * 16 + fr) * XSTR + fq];
                acc[i][j] = __builtin_amdgcn_mfma_f32_16x16x32_bf16(af, bg, acc[i][j], 0, 0, 0);
            }
        }
    }
    float invdeg = 1.f / fmaxf((float)(re - rs), 1.f);
    unsigned short* out = Aout + (size_t)blockIdx.x * KPAD;
    int quad = lane >> 4;
    #pragma unroll
    for (int i = 0; i < 2; i++) {
        int wibase = (2 * wave + i) * 16 + quad * 4;
        #pragma unroll
        for (int r = 0; r < 4; r++) {
            int wi = wibase + r;
            if (wi < KC) {                    // rows 125..127 discarded
                #pragma unroll
                for (int j = 0; j < 4; j++)
                    out[wi * 64 + j * 16 + fr] = f2bf(acc[i][j][r] * invdeg);
            }
        }
    }
    if (t < 64) out[8000 + t] = f2bf(xin[(size_t)node * 64 + t]);  // root rows
    if (t < 128) out[8064 + t] = 0;                                // zero pad rows
}

// ---------------- concat + transpose weights to bf16: WfT[n][k], K padded ----------------
__global__ void concatWT_kernel(const float* __restrict__ W, const float* __restrict__ R,
                                int COUT, int kpad, int krows, int cin,
                                unsigned short* __restrict__ WfT)
{
    int i = blockIdx.x * blockDim.x + threadIdx.x;
    if (i >= COUT * kpad) return;
    int n = i / kpad, k = i - n * kpad;
    float v = 0.f;
    if (k < krows) v = W[(size_t)k * COUT + n];
    else if (k < krows + cin) v = R[(size_t)(k - krows) * COUT + n];
    WfT[i] = f2bf(v);
}

// ---------------- bf16 MFMA GEMM: P[z] = A[:, zslice] x BT[:, zslice]^T ----------------
__global__ __launch_bounds__(256) void gemm_kernel(const unsigned short* __restrict__ A,
                                                   const unsigned short* __restrict__ BT,
                                                   int Mrows, int COUT, int Ksz, int lda,
                                                   float* __restrict__ P)
{
    __shared__ __attribute__((aligned(16))) unsigned short As[64 * LDA];
    __shared__ __attribute__((aligned(16))) unsigned short Bs[64 * LDA];
    int t = threadIdx.x;
    int mblk = blockIdx.x * 64, nblk = blockIdx.y * 64;
    int kBase = blockIdx.z * Ksz;

    int lr = t >> 2;                 // staging row 0..63
    int lc = (t & 3) * 16;           // staging col (bf16 units)

    const unsigned short* Ap = A + (size_t)(mblk + lr) * lda + kBase + lc;
    const unsigned short* Bp = BT + (size_t)(nblk + lr) * lda + kBase + lc;

    uint4 a0 = *(const uint4*)Ap;  uint4 a1 = *(const uint4*)(Ap + 8);
    uint4 b0 = *(const uint4*)Bp;  uint4 b1 = *(const uint4*)(Bp + 8);

    int wave = t >> 6, lane = t & 63;
    int mw = (wave & 1) * 32, nw = (wave >> 1) * 32;
    int fr = lane & 15;
    int fq = (lane >> 4) * 8;

    f32x4 acc[2][2];
    #pragma unroll
    for (int i = 0; i < 2; i++)
        #pragma unroll
        for (int j = 0; j < 2; j++) acc[i][j] = (f32x4){0.f, 0.f, 0.f, 0.f};

    int ktiles = Ksz / 64;
    for (int kt = 0; kt < ktiles; kt++) {
        *(uint4*)&As[lr * LDA + lc]     = a0;
        *(uint4*)&As[lr * LDA + lc + 8] = a1;
        *(uint4*)&Bs[lr * LDA + lc]     = b0;
        *(uint4*)&Bs[lr * LDA + lc + 8] = b1;
        __syncthreads();
        if (kt + 1 < ktiles) {
            Ap += 64; Bp += 64;
            a0 = *(const uint4*)Ap; a1 = *(const uint4*)(Ap + 8);
            b0 = *(const uint4*)Bp; b1 = *(const uint4*)(Bp + 8);
        }
        #pragma unroll
        for (int ks = 0; ks < 2; ks++) {
            bf16x8 af0 = *(const bf16x8*)&As[(mw + fr) * LDA + ks * 32 + fq];
            bf16x8 af1 = *(const bf16x8*)&As[(mw + 16 + fr) * LDA + ks * 32 + fq];
            bf16x8 bg0 = *(const bf16x8*)&Bs[(nw + fr) * LDA + ks * 32 + fq];
            bf16x8 bg1 = *(const bf16x8*)&Bs[(nw + 16 + fr) * LDA + ks * 32 + fq];
            acc[0][0] = __builtin_amdgcn_mfma_f32_16x16x32_bf16(af0, bg0, acc[0][0], 0, 0, 0);
            acc[0][1] = __builtin_amdgcn_mfma_f32_16x16x32_bf16(af0, bg1, acc[0][1], 0, 0, 0);
            acc[1][0] = __builtin_amdgcn_mfma_f32_16x16x32_bf16(af1, bg0, acc[1][0], 0, 0, 0);
            acc[1][1] = __builtin_amdgcn_mfma_f32_16x16x32_bf16(af1, bg1, acc[1][1], 0, 0, 0);
        }
        __syncthreads();
    }
    float* Pz = P + (size_t)blockIdx.z * Mrows * COUT;
    int crow = (lane >> 4) * 4, ccol = lane & 15;
    #pragma unroll
    for (int i = 0; i < 2; i++)
        #pragma unroll
        for (int j = 0; j < 2; j++) {
            int m0 = mblk + mw + i * 16 + crow;
            int n0 = nblk + nw + j * 16 + ccol;
            #pragma unroll
            for (int r = 0; r < 4; r++)
                Pz[(size_t)(m0 + r) * COUT + n0] = acc[i][j][r];
        }
}

// ---------------- combine K-split partials + bias + ELU ----------------
__global__ void combine_kernel(const float* __restrict__ P, const float* __restrict__ b,
                               int Mrows, int COUT, int NS, float* __restrict__ xout)
{
    int i = blockIdx.x * blockDim.x + threadIdx.x;
    int total = Mrows * COUT;
    if (i >= total) return;
    float s = 0.f;
    for (int z = 0; z < NS; z++) s += P[(size_t)z * total + i];
    int o = i % COUT;
    xout[i] = elu_f(s + b[o]);
}

// ---------------- gathers ----------------
__global__ void xgather_kernel(const float* __restrict__ x_src, const int* __restrict__ idx,
                               int n, float* __restrict__ x_dst)
{
    int tid = blockIdx.x * blockDim.x + threadIdx.x;
    if (tid >= n * 64) return;
    int i = tid >> 6, c = tid & 63;
    x_dst[(size_t)i * 64 + c] = x_src[(size_t)idx[i] * 64 + c];
}

__global__ void posgather_kernel(const float* __restrict__ pos_src, const int* __restrict__ idx,
                                 int n, float* __restrict__ pos_dst)
{
    int tid = blockIdx.x * blockDim.x + threadIdx.x;
    if (tid >= n * 3) return;
    int i = tid / 3, d = tid - i * 3;
    pos_dst[tid] = pos_src[idx[i] * 3 + d];
}

__global__ void zero_kernel(float* __restrict__ p, int n)
{
    int i = blockIdx.x * blockDim.x + threadIdx.x;
    if (i < n) p[i] = 0.f;
}

// ---------------- Mean pool over clouds ----------------
__global__ void pool_kernel(const float* __restrict__ x3, const int* __restrict__ batch,
                            const int* __restrict__ idx1, const int* __restrict__ idx2, int n3,
                            float* __restrict__ gnum, float* __restrict__ cnt)
{
    int tid = blockIdx.x * blockDim.x + threadIdx.x;
    if (tid >= n3 * 128) return;
    int i = tid >> 7, c = tid & 127;
    int cloud = batch[idx1[idx2[i]]];
    fadd_atomic(&gnum[cloud * 128 + c], x3[(size_t)i * 128 + c]);
    if (c == 0) fadd_atomic(&cnt[cloud], 1.f);
}

// ---------------- Final MLP + log_softmax ----------------
__global__ void mlp_kernel(const float* __restrict__ gnum, const float* __restrict__ cnt,
                           const float* __restrict__ lw1, const float* __restrict__ lb1,
                           const float* __restrict__ lw2, const float* __restrict__ lb2,
                           const float* __restrict__ lw3, const float* __restrict__ lb3,
                           float* __restrict__ out)
{
    __shared__ float gv[128], h1[256], h2[256], lg[10];
    __shared__ float lse_s;
    int cl = blockIdx.x, t = threadIdx.x;   // blockDim = 256
    if (t < 128) gv[t] = gnum[cl * 128 + t] / fmaxf(cnt[cl], 1.f);
    __syncthreads();
    float a = lb1[t];
    for (int c = 0; c < 128; c++) a += gv[c] * lw1[c * 256 + t];
    h1[t] = elu_f(a);
    __syncthreads();
    a = lb2[t];
    for (int c = 0; c < 256; c++) a += h1[c] * lw2[c * 256 + t];
    h2[t] = elu_f(a);
    __syncthreads();
    if (t < 10) {
        a = lb3[t];
        for (int c = 0; c < 256; c++) a += h2[c] * lw3[c * 10 + t];
        lg[t] = a;
    }
    __syncthreads();
    if (t == 0) {
        float m = -1e30f;
        for (int i = 0; i < 10; i++) m = fmaxf(m, lg[i]);
        float s = 0.f;
        for (int i = 0; i < 10; i++) s += expf(lg[i] - m);
        lse_s = m + logf(s);
    }
    __syncthreads();
    if (t < 10) out[cl * 10 + t] = lg[t] - lse_s;
}

static void run_level(const unsigned* slots, const int* src, const int* rowptr,
                      const float* xin, const unsigned short* WfT, const float* bvec,
                      int n, int COUT, unsigned short* Abuf, int AbufRows, float* P,
                      float* xout, hipStream_t stream)
{
    int Ksz = KPAD / NSPLIT;
    for (int cs = 0; cs < n; cs += AbufRows) {
        int cr = min(AbufRows, n - cs);
        buildA_kernel<<<cr, 256, 0, stream>>>(slots, src, rowptr, xin, cs, Abuf);
        dim3 grid(cr / 64, COUT / 64, NSPLIT);
        gemm_kernel<<<grid, 256, 0, stream>>>(Abuf, WfT, cr, COUT, Ksz, KPAD, P);
        combine_kernel<<<(cr * COUT + 255) / 256, 256, 0, stream>>>(P, bvec, cr, COUT, NSPLIT,
                                                                    xout + (size_t)cs * COUT);
    }
}

extern "C" void kernel_launch(void* const* d_in, const int* in_sizes, int n_in,
                              void* d_out, int out_size, void* d_ws, size_t ws_size,
                              hipStream_t stream)
{
    const float* pos   = (const float*)d_in[0];
    const int*   batch = (const int*)d_in[1];
    const int*   src1  = (const int*)d_in[2];
    const int*   tgt1  = (const int*)d_in[3];
    const int*   src2  = (const int*)d_in[4];
    const int*   tgt2  = (const int*)d_in[5];
    const int*   src3  = (const int*)d_in[6];
    const int*   tgt3  = (const int*)d_in[7];
    const int*   idx1  = (const int*)d_in[8];
    const int*   idx2  = (const int*)d_in[9];
    const float* W1 = (const float*)d_in[10];
    const float* R1 = (const float*)d_in[11];
    const float* b1 = (const float*)d_in[12];
    const float* W2 = (const float*)d_in[13];
    const float* R2 = (const float*)d_in[14];
    const float* b2 = (const float*)d_in[15];
    const float* W3 = (const float*)d_in[16];
    const float* R3 = (const float*)d_in[17];
    const float* b3 = (const float*)d_in[18];
    const float* lw1 = (const float*)d_in[19];
    const float* lb1 = (const float*)d_in[20];
    const float* lw2 = (const float*)d_in[21];
    const float* lb2 = (const float*)d_in[22];
    const float* lw3 = (const float*)d_in[23];
    const float* lb3 = (const float*)d_in[24];

    int n1 = in_sizes[0] / 3;
    int E1 = in_sizes[2];
    int E2 = in_sizes[4];
    int E3 = in_sizes[6];
    int n2 = in_sizes[8];
    int n3 = in_sizes[9];

    float* ws = (float*)d_ws;
    float* x1   = ws;                               // n1*64
    float* x2in = x1   + (size_t)n1 * 64;           // n2*64
    float* x2o  = x2in + (size_t)n2 * 64;           // n2*64
    float* x3in = x2o  + (size_t)n2 * 64;           // n3*64
    float* x3o  = x3in + (size_t)n3 * 64;           // n3*128
    float* pos2 = x3o  + (size_t)n3 * 128;          // n2*3
    float* pos3 = pos2 + (size_t)n2 * 3;            // n3*3
    float* gnum = pos3 + (size_t)n3 * 3;            // 16*128
    float* cnt  = gnum + 16 * 128;                  // 16
    unsigned short* WfT1 = (unsigned short*)(cnt + 16);    // 64*128 bf16
    unsigned short* WfT2 = WfT1 + (size_t)64 * 128;        // 64*KPAD
    unsigned short* WfT3 = WfT2 + (size_t)64 * KPAD;       // 128*KPAD
    int*   rp1  = (int*)(WfT3 + (size_t)128 * KPAD);
    int*   rp2  = rp1 + ((n1 + 4) & ~3);
    int*   rp3  = rp2 + ((n2 + 4) & ~3);
    unsigned* slots1 = (unsigned*)(rp3 + ((n3 + 4) & ~3));
    unsigned* slots2 = slots1 + (size_t)E1 * 8;
    unsigned* slots3 = slots2 + (size_t)E2 * 8;
    unsigned short* A1buf = (unsigned short*)(slots3 + (size_t)E3 * 8);  // n1*128 bf16
    float*  P    = (float*)(A1buf + (size_t)n1 * 128);  // 8M floats
    unsigned short* Abuf = (unsigned short*)(P + (size_t)8 * 1024 * 1024);

    size_t usedBytes = (size_t)((char*)Abuf - (char*)ws);
    size_t availBytes = ws_size > usedBytes ? ws_size - usedBytes : 0;
    int maxRows = (int)(availBytes / ((size_t)KPAD * 2));
    maxRows &= ~63;
    if (maxRows < 64) maxRows = 64;
    int rowsP2 = ((8 * 1024 * 1024) / (NSPLIT * 64)) & ~63;
    int rowsP3 = ((8 * 1024 * 1024) / (NSPLIT * 128)) & ~63;
    int rows2 = min(min(maxRows, rowsP2), n2);
    int rows3 = min(min(maxRows, rowsP3), n3);

    float* out = (float*)d_out;

    // --- graph preprocessing ---
    rowptr_kernel<<<(E1 + 256) / 256, 256, 0, stream>>>(tgt1, E1, n1, rp1);
    rowptr_kernel<<<(E2 + 256) / 256, 256, 0, stream>>>(tgt2, E2, n2, rp2);
    rowptr_kernel<<<(E3 + 256) / 256, 256, 0, stream>>>(tgt3, E3, n3, rp3);
    posgather_kernel<<<(n2 * 3 + 255) / 256, 256, 0, stream>>>(pos, idx1, n2, pos2);
    posgather_kernel<<<(n3 * 3 + 255) / 256, 256, 0, stream>>>(pos2, idx2, n3, pos3);
    slots_kernel<<<(E1 + 255) / 256, 256, 0, stream>>>(pos,  src1, tgt1, E1, 2.5f,  126, slots1);
    slots_kernel<<<(E2 + 255) / 256, 256, 0, stream>>>(pos2, src2, tgt2, E2, 1.25f, 125, slots2);
    slots_kernel<<<(E3 + 255) / 256, 256, 0, stream>>>(pos3, src3, tgt3, E3, 0.5f,  125, slots3);
    concatWT_kernel<<<(64 * 128 + 255) / 256, 256, 0, stream>>>(W1, R1, 64, 128, KC, 1, WfT1);
    concatWT_kernel<<<(64 * KPAD + 255) / 256, 256, 0, stream>>>(W2, R2, 64, KPAD, KC * 64, 64, WfT2);
    concatWT_kernel<<<(128 * KPAD + 255) / 256, 256, 0, stream>>>(W3, R3, 128, KPAD, KC * 64, 64, WfT3);

    // --- level 1: histogram + GEMM(K=128) ---
    histo1_kernel<<<n1 / 4, 256, 0, stream>>>(slots1, rp1, A1buf);
    {
        dim3 g1(n1 / 64, 1, 1);
        gemm_kernel<<<g1, 256, 0, stream>>>(A1buf, WfT1, n1, 64, 128, 128, P);
        combine_kernel<<<(n1 * 64 + 255) / 256, 256, 0, stream>>>(P, b1, n1, 64, 1, x1);
    }
    xgather_kernel<<<(n2 * 64 + 255) / 256, 256, 0, stream>>>(x1, idx1, n2, x2in);

    // --- level 2 ---
    run_level(slots2, src2, rp2, x2in, WfT2, b2, n2, 64, Abuf, rows2, P, x2o, stream);
    xgather_kernel<<<(n3 * 64 + 255) / 256, 256, 0, stream>>>(x2o, idx2, n3, x3in);

    // --- level 3 ---
    run_level(slots3, src3, rp3, x3in, WfT3, b3, n3, 128, Abuf, rows3, P, x3o, stream);

    // --- pool + head ---
    zero_kernel<<<(16 * 128 + 16 + 255) / 256, 256, 0, stream>>>(gnum, 16 * 128 + 16);
    pool_kernel<<<(n3 * 128 + 255) / 256, 256, 0, stream>>>(x3o, batch, idx1, idx2, n3, gnum, cnt);
    mlp_kernel<<<16, 256, 0, stream>>>(gnum, cnt, lw1, lb1, lw2, lb2, lw3, lb3, out);
}

// Round 11
// 457.513 us; speedup vs baseline: 6.7479x; 1.1349x over previous
//
#include <hip/hip_runtime.h>
#include <hip/hip_bf16.h>
#include <math.h>

#define KDIM 5
#define KC 125
#define KPAD 8192   // 125*64 spline rows + 64 root rows + 128 zero pad (levels 2/3)
#define EPB 32      // edges per MFMA K-step (max_nb = 32)
#define NSPLIT 8    // GEMM K-split for levels 2/3
#define LDA 72      // GEMM LDS tile row stride in bf16 (64 + 8 pad)
#define SSTR 40     // buildA S row stride in bf16
#define XSTR 40     // buildA XT row stride in bf16

typedef short bf16x8 __attribute__((ext_vector_type(8)));
typedef float f32x4 __attribute__((ext_vector_type(4)));

__device__ __forceinline__ float elu_f(float x) { return x > 0.f ? x : (expf(x) - 1.f); }

__device__ __forceinline__ void fadd_atomic(float* p, float v) {
    unsafeAtomicAdd(p, v);
}

__device__ __forceinline__ unsigned short f2bf(float x) {
    union { float f; unsigned u; } v; v.f = x;
    unsigned r = (v.u + 0x7FFFu + ((v.u >> 16) & 1u)) >> 16;
    return (unsigned short)r;
}
__device__ __forceinline__ unsigned pack2(float lo, float hi) {
    __hip_bfloat162 h = __float22bfloat162_rn(make_float2(lo, hi));
    unsigned r; __builtin_memcpy(&r, &h, 4); return r;
}

// ---------------- rowptr ----------------
__global__ void rowptr_kernel(const int* __restrict__ tgt, int E, int n, int* __restrict__ rowptr)
{
    int e = blockIdx.x * blockDim.x + threadIdx.x;
    if (e > E) return;
    if (e < E) {
        int t = tgt[e];
        int p = (e == 0) ? -1 : tgt[e - 1];
        for (int v = p + 1; v <= t; v++) rowptr[v] = e;
    } else {
        int p = tgt[E - 1];
        for (int v = p + 1; v <= n; v++) rowptr[v] = E;
    }
}

// ---------------- slot table ----------------
__global__ void slots_kernel(const float* __restrict__ posL, const int* __restrict__ src,
                             const int* __restrict__ tgt, int E, float rinv2, int sinkrow,
                             unsigned* __restrict__ slots)
{
    int e = blockIdx.x * blockDim.x + threadIdx.x;
    if (e >= E) return;
    int s = src[e], t = tgt[e];
    float p0 = fminf(fmaxf((posL[t*3+0] - posL[s*3+0]) * rinv2 + 0.5f, 0.f), 1.f);
    float p1 = fminf(fmaxf((posL[t*3+1] - posL[s*3+1]) * rinv2 + 0.5f, 0.f), 1.f);
    float p2 = fminf(fmaxf((posL[t*3+2] - posL[s*3+2]) * rinv2 + 0.5f, 0.f), 1.f);
    float v0 = p0 * (KDIM - 1), v1 = p1 * (KDIM - 1), v2 = p2 * (KDIM - 1);
    int b0 = (int)floorf(v0), b1 = (int)floorf(v1), b2 = (int)floorf(v2);
    float f0 = v0 - (float)b0, f1 = v1 - (float)b1, f2 = v2 - (float)b2;
    unsigned out[8];
    #pragma unroll
    for (int sb = 0; sb < 8; sb++) {
        int i0 = sb & 1, i1 = (sb >> 1) & 1, i2 = (sb >> 2) & 1;
        float w = (i0 ? f0 : 1.f - f0) * (i1 ? f1 : 1.f - f1) * (i2 ? f2 : 1.f - f2);
        int k0 = min(b0 + i0, KDIM - 1), k1 = min(b1 + i1, KDIM - 1), k2 = min(b2 + i2, KDIM - 1);
        int wi = k0 + KDIM * k1 + KDIM * KDIM * k2;
        if (w == 0.f) wi = sinkrow;
        out[sb] = (__float_as_uint(w) & ~127u) | (unsigned)wi;
    }
    uint4* dst = (uint4*)&slots[(size_t)e * 8];
    dst[0] = make_uint4(out[0], out[1], out[2], out[3]);
    dst[1] = make_uint4(out[4], out[5], out[6], out[7]);
}

// ---------------- Level 1 histogram ----------------
__global__ __launch_bounds__(256) void histo1_kernel(const unsigned* __restrict__ slots,
                                                     const int* __restrict__ rowptr,
                                                     unsigned short* __restrict__ Aout)
{
    __shared__ float A1s[4][128];
    int wave = threadIdx.x >> 6, lane = threadIdx.x & 63;
    int node = blockIdx.x * 4 + wave;
    A1s[wave][lane] = 0.f;
    A1s[wave][64 + lane] = 0.f;
    int rs = rowptr[node], re = rowptr[node + 1];
    for (int e = rs + lane; e < re; e += 64) {
        uint4 s0 = *(const uint4*)&slots[(size_t)e * 8];
        uint4 s1 = *(const uint4*)&slots[(size_t)e * 8 + 4];
        unsafeAtomicAdd(&A1s[wave][s0.x & 127u], __uint_as_float(s0.x));
        unsafeAtomicAdd(&A1s[wave][s0.y & 127u], __uint_as_float(s0.y));
        unsafeAtomicAdd(&A1s[wave][s0.z & 127u], __uint_as_float(s0.z));
        unsafeAtomicAdd(&A1s[wave][s0.w & 127u], __uint_as_float(s0.w));
        unsafeAtomicAdd(&A1s[wave][s1.x & 127u], __uint_as_float(s1.x));
        unsafeAtomicAdd(&A1s[wave][s1.y & 127u], __uint_as_float(s1.y));
        unsafeAtomicAdd(&A1s[wave][s1.z & 127u], __uint_as_float(s1.z));
        unsafeAtomicAdd(&A1s[wave][s1.w & 127u], __uint_as_float(s1.w));
    }
    __syncthreads();
    float deg = (float)(re - rs);
    float invdeg = 1.f / fmaxf(deg, 1.f);
    if (lane == 0) {
        A1s[wave][125] = fmaxf(deg, 1.f);
        A1s[wave][126] = 0.f;
        A1s[wave][127] = 0.f;
    }
    __syncthreads();
    unsigned* out = (unsigned*)(Aout + (size_t)node * 128);
    out[lane] = pack2(A1s[wave][2 * lane] * invdeg, A1s[wave][2 * lane + 1] * invdeg);
}

// ---------------- buildA (levels 2/3): MFMA formulation ----------------
__global__ __launch_bounds__(256) void buildA_kernel(
    const unsigned* __restrict__ slots, const int* __restrict__ src,
    const int* __restrict__ rowptr, const float* __restrict__ xin,
    int nodeBase, unsigned short* __restrict__ Aout)
{
    __shared__ __attribute__((aligned(16))) unsigned short S[128 * SSTR];   // S[wi][e]
    __shared__ __attribute__((aligned(16))) unsigned short XT[64 * XSTR];   // XT[c][e]
    __shared__ int Es[EPB];
    int node = nodeBase + blockIdx.x;
    int t = threadIdx.x;                      // blockDim = 256
    int rs = rowptr[node], re = rowptr[node + 1];
    int wave = t >> 6, lane = t & 63;
    int fr = lane & 15, fq = (lane >> 4) * 8;

    f32x4 acc[2][4];
    #pragma unroll
    for (int i = 0; i < 2; i++)
        #pragma unroll
        for (int j = 0; j < 4; j++) acc[i][j] = (f32x4){0.f, 0.f, 0.f, 0.f};

    for (int ts = rs; ts < re; ts += EPB) {
        int ne = min(EPB, re - ts);
        __syncthreads();
        for (int i = t; i < 128 * SSTR / 2; i += 256) ((unsigned*)S)[i] = 0;
        for (int i = t; i < 64 * XSTR / 2; i += 256) ((unsigned*)XT)[i] = 0;
        if (t < ne) Es[t] = src[ts + t];
        __syncthreads();
        if (t < ne * 8) {
            int e = t >> 3;
            unsigned word = slots[(size_t)(ts + e) * 8 + (t & 7)];
            int wi = word & 127u;
            S[wi * SSTR + e] = f2bf(__uint_as_float(word & ~127u));
        }
        for (int i = t; i < ne * 64; i += 256) {
            int c = i & 63, el = i >> 6;
            XT[c * XSTR + el] = f2bf(xin[(size_t)Es[el] * 64 + c]);
        }
        __syncthreads();
        #pragma unroll
        for (int i = 0; i < 2; i++) {
            bf16x8 af = *(const bf16x8*)&S[((2 * wave + i) * 16 + fr) * SSTR + fq];
            #pragma unroll
            for (int j = 0; j < 4; j++) {
                bf16x8 bg = *(const bf16x8*)&XT[(j * 16 + fr) * XSTR + fq];
                acc[i][j] = __builtin_amdgcn_mfma_f32_16x16x32_bf16(af, bg, acc[i][j], 0, 0, 0);
            }
        }
    }
    float invdeg = 1.f / fmaxf((float)(re - rs), 1.f);
    unsigned short* out = Aout + (size_t)blockIdx.x * KPAD;
    int quad = lane >> 4;
    #pragma unroll
    for (int i = 0; i < 2; i++) {
        int wibase = (2 * wave + i) * 16 + quad * 4;
        #pragma unroll
        for (int r = 0; r < 4; r++) {
            int wi = wibase + r;
            if (wi < KC) {
                #pragma unroll
                for (int j = 0; j < 4; j++)
                    out[wi * 64 + j * 16 + fr] = f2bf(acc[i][j][r] * invdeg);
            }
        }
    }
    if (t < 64) out[8000 + t] = f2bf(xin[(size_t)node * 64 + t]);
    if (t < 128) out[8064 + t] = 0;
}

// ---------------- concat + transpose weights ----------------
__global__ void concatWT_kernel(const float* __restrict__ W, const float* __restrict__ R,
                                int COUT, int kpad, int krows, int cin,
                                unsigned short* __restrict__ WfT)
{
    int i = blockIdx.x * blockDim.x + threadIdx.x;
    if (i >= COUT * kpad) return;
    int n = i / kpad, k = i - n * kpad;
    float v = 0.f;
    if (k < krows) v = W[(size_t)k * COUT + n];
    else if (k < krows + cin) v = R[(size_t)(k - krows) * COUT + n];
    WfT[i] = f2bf(v);
}

// ---------------- bf16 MFMA GEMM ----------------
__global__ __launch_bounds__(256) void gemm_kernel(const unsigned short* __restrict__ A,
                                                   const unsigned short* __restrict__ BT,
                                                   int Mrows, int COUT, int Ksz, int lda,
                                                   float* __restrict__ P)
{
    __shared__ __attribute__((aligned(16))) unsigned short As[64 * LDA];
    __shared__ __attribute__((aligned(16))) unsigned short Bs[64 * LDA];
    int t = threadIdx.x;
    int mblk = blockIdx.x * 64, nblk = blockIdx.y * 64;
    int kBase = blockIdx.z * Ksz;

    int lr = t >> 2;
    int lc = (t & 3) * 16;

    const unsigned short* Ap = A + (size_t)(mblk + lr) * lda + kBase + lc;
    const unsigned short* Bp = BT + (size_t)(nblk + lr) * lda + kBase + lc;

    uint4 a0 = *(const uint4*)Ap;  uint4 a1 = *(const uint4*)(Ap + 8);
    uint4 b0 = *(const uint4*)Bp;  uint4 b1 = *(const uint4*)(Bp + 8);

    int wave = t >> 6, lane = t & 63;
    int mw = (wave & 1) * 32, nw = (wave >> 1) * 32;
    int fr = lane & 15;
    int fq = (lane >> 4) * 8;

    f32x4 acc[2][2];
    #pragma unroll
    for (int i = 0; i < 2; i++)
        #pragma unroll
        for (int j = 0; j < 2; j++) acc[i][j] = (f32x4){0.f, 0.f, 0.f, 0.f};

    int ktiles = Ksz / 64;
    for (int kt = 0; kt < ktiles; kt++) {
        *(uint4*)&As[lr * LDA + lc]     = a0;
        *(uint4*)&As[lr * LDA + lc + 8] = a1;
        *(uint4*)&Bs[lr * LDA + lc]     = b0;
        *(uint4*)&Bs[lr * LDA + lc + 8] = b1;
        __syncthreads();
        if (kt + 1 < ktiles) {
            Ap += 64; Bp += 64;
            a0 = *(const uint4*)Ap; a1 = *(const uint4*)(Ap + 8);
            b0 = *(const uint4*)Bp; b1 = *(const uint4*)(Bp + 8);
        }
        #pragma unroll
        for (int ks = 0; ks < 2; ks++) {
            bf16x8 af0 = *(const bf16x8*)&As[(mw + fr) * LDA + ks * 32 + fq];
            bf16x8 af1 = *(const bf16x8*)&As[(mw + 16 + fr) * LDA + ks * 32 + fq];
            bf16x8 bg0 = *(const bf16x8*)&Bs[(nw + fr) * LDA + ks * 32 + fq];
            bf16x8 bg1 = *(const bf16x8*)&Bs[(nw + 16 + fr) * LDA + ks * 32 + fq];
            acc[0][0] = __builtin_amdgcn_mfma_f32_16x16x32_bf16(af0, bg0, acc[0][0], 0, 0, 0);
            acc[0][1] = __builtin_amdgcn_mfma_f32_16x16x32_bf16(af0, bg1, acc[0][1], 0, 0, 0);
            acc[1][0] = __builtin_amdgcn_mfma_f32_16x16x32_bf16(af1, bg0, acc[1][0], 0, 0, 0);
            acc[1][1] = __builtin_amdgcn_mfma_f32_16x16x32_bf16(af1, bg1, acc[1][1], 0, 0, 0);
        }
        __syncthreads();
    }
    float* Pz = P + (size_t)blockIdx.z * Mrows * COUT;
    int crow = (lane >> 4) * 4, ccol = lane & 15;
    #pragma unroll
    for (int i = 0; i < 2; i++)
        #pragma unroll
        for (int j = 0; j < 2; j++) {
            int m0 = mblk + mw + i * 16 + crow;
            int n0 = nblk + nw + j * 16 + ccol;
            #pragma unroll
            for (int r = 0; r < 4; r++)
                Pz[(size_t)(m0 + r) * COUT + n0] = acc[i][j][r];
        }
}

// ---------------- combine K-split partials + bias + ELU ----------------
__global__ void combine_kernel(const float* __restrict__ P, const float* __restrict__ b,
                               int Mrows, int COUT, int NS, float* __restrict__ xout)
{
    int i = blockIdx.x * blockDim.x + threadIdx.x;
    int total = Mrows * COUT;
    if (i >= total) return;
    float s = 0.f;
    for (int z = 0; z < NS; z++) s += P[(size_t)z * total + i];
    int o = i % COUT;
    xout[i] = elu_f(s + b[o]);
}

// ---------------- gathers ----------------
__global__ void xgather_kernel(const float* __restrict__ x_src, const int* __restrict__ idx,
                               int n, float* __restrict__ x_dst)
{
    int tid = blockIdx.x * blockDim.x + threadIdx.x;
    if (tid >= n * 64) return;
    int i = tid >> 6, c = tid & 63;
    x_dst[(size_t)i * 64 + c] = x_src[(size_t)idx[i] * 64 + c];
}

__global__ void posgather_kernel(const float* __restrict__ pos_src, const int* __restrict__ idx,
                                 int n, float* __restrict__ pos_dst)
{
    int tid = blockIdx.x * blockDim.x + threadIdx.x;
    if (tid >= n * 3) return;
    int i = tid / 3, d = tid - i * 3;
    pos_dst[tid] = pos_src[idx[i] * 3 + d];
}

__global__ void zero_kernel(float* __restrict__ p, int n)
{
    int i = blockIdx.x * blockDim.x + threadIdx.x;
    if (i < n) p[i] = 0.f;
}

// ---------------- cloud ids + counts (per-block LDS histogram) ----------------
__global__ void cid_kernel(const int* __restrict__ batch, const int* __restrict__ idx1,
                           const int* __restrict__ idx2, int n3,
                           int* __restrict__ cid, float* __restrict__ cnt)
{
    __shared__ int h[16];
    int t = threadIdx.x;
    int i = blockIdx.x * 256 + t;
    if (t < 16) h[t] = 0;
    __syncthreads();
    if (i < n3) {
        int cl = batch[idx1[idx2[i]]];
        cid[i] = cl;
        atomicAdd(&h[cl], 1);
    }
    __syncthreads();
    if (t < 16 && h[t] > 0) fadd_atomic(&cnt[t], (float)h[t]);
}

// ---------------- Mean-pool stage: per-thread run accumulation, few atomics ----------------
// 64 nodes per block; thread (c = t&127, h = t>>7) sums its half's nodes per cloud run.
__global__ void pool2_kernel(const float* __restrict__ x3, const int* __restrict__ cid,
                             int n3, float* __restrict__ gnum)
{
    int t = threadIdx.x;
    int c = t & 127, h = t >> 7;
    int base = blockIdx.x * 64;
    int nn = min(64, n3 - base);
    float sum = 0.f; int cur = -1;
    for (int j = h; j < nn; j += 2) {
        int i = base + j;
        int cl = cid[i];
        if (cl != cur) {
            if (cur >= 0) fadd_atomic(&gnum[cur * 128 + c], sum);
            cur = cl; sum = 0.f;
        }
        sum += x3[(size_t)i * 128 + c];
    }
    if (cur >= 0) fadd_atomic(&gnum[cur * 128 + c], sum);
}

// ---------------- Final MLP + log_softmax ----------------
__global__ void mlp_kernel(const float* __restrict__ gnum, const float* __restrict__ cnt,
                           const float* __restrict__ lw1, const float* __restrict__ lb1,
                           const float* __restrict__ lw2, const float* __restrict__ lb2,
                           const float* __restrict__ lw3, const float* __restrict__ lb3,
                           float* __restrict__ out)
{
    __shared__ float gv[128], h1[256], h2[256], lg[10];
    __shared__ float lse_s;
    int cl = blockIdx.x, t = threadIdx.x;   // blockDim = 256
    if (t < 128) gv[t] = gnum[cl * 128 + t] / fmaxf(cnt[cl], 1.f);
    __syncthreads();
    float a = lb1[t];
    for (int c = 0; c < 128; c++) a += gv[c] * lw1[c * 256 + t];
    h1[t] = elu_f(a);
    __syncthreads();
    a = lb2[t];
    for (int c = 0; c < 256; c++) a += h1[c] * lw2[c * 256 + t];
    h2[t] = elu_f(a);
    __syncthreads();
    if (t < 10) {
        a = lb3[t];
        for (int c = 0; c < 256; c++) a += h2[c] * lw3[c * 10 + t];
        lg[t] = a;
    }
    __syncthreads();
    if (t == 0) {
        float m = -1e30f;
        for (int i = 0; i < 10; i++) m = fmaxf(m, lg[i]);
        float s = 0.f;
        for (int i = 0; i < 10; i++) s += expf(lg[i] - m);
        lse_s = m + logf(s);
    }
    __syncthreads();
    if (t < 10) out[cl * 10 + t] = lg[t] - lse_s;
}

static void run_level(const unsigned* slots, const int* src, const int* rowptr,
                      const float* xin, const unsigned short* WfT, const float* bvec,
                      int n, int COUT, unsigned short* Abuf, int AbufRows, float* P,
                      float* xout, hipStream_t stream)
{
    int Ksz = KPAD / NSPLIT;
    for (int cs = 0; cs < n; cs += AbufRows) {
        int cr = min(AbufRows, n - cs);
        buildA_kernel<<<cr, 256, 0, stream>>>(slots, src, rowptr, xin, cs, Abuf);
        dim3 grid(cr / 64, COUT / 64, NSPLIT);
        gemm_kernel<<<grid, 256, 0, stream>>>(Abuf, WfT, cr, COUT, Ksz, KPAD, P);
        combine_kernel<<<(cr * COUT + 255) / 256, 256, 0, stream>>>(P, bvec, cr, COUT, NSPLIT,
                                                                    xout + (size_t)cs * COUT);
    }
}

extern "C" void kernel_launch(void* const* d_in, const int* in_sizes, int n_in,
                              void* d_out, int out_size, void* d_ws, size_t ws_size,
                              hipStream_t stream)
{
    const float* pos   = (const float*)d_in[0];
    const int*   batch = (const int*)d_in[1];
    const int*   src1  = (const int*)d_in[2];
    const int*   tgt1  = (const int*)d_in[3];
    const int*   src2  = (const int*)d_in[4];
    const int*   tgt2  = (const int*)d_in[5];
    const int*   src3  = (const int*)d_in[6];
    const int*   tgt3  = (const int*)d_in[7];
    const int*   idx1  = (const int*)d_in[8];
    const int*   idx2  = (const int*)d_in[9];
    const float* W1 = (const float*)d_in[10];
    const float* R1 = (const float*)d_in[11];
    const float* b1 = (const float*)d_in[12];
    const float* W2 = (const float*)d_in[13];
    const float* R2 = (const float*)d_in[14];
    const float* b2 = (const float*)d_in[15];
    const float* W3 = (const float*)d_in[16];
    const float* R3 = (const float*)d_in[17];
    const float* b3 = (const float*)d_in[18];
    const float* lw1 = (const float*)d_in[19];
    const float* lb1 = (const float*)d_in[20];
    const float* lw2 = (const float*)d_in[21];
    const float* lb2 = (const float*)d_in[22];
    const float* lw3 = (const float*)d_in[23];
    const float* lb3 = (const float*)d_in[24];

    int n1 = in_sizes[0] / 3;
    int E1 = in_sizes[2];
    int E2 = in_sizes[4];
    int E3 = in_sizes[6];
    int n2 = in_sizes[8];
    int n3 = in_sizes[9];

    float* ws = (float*)d_ws;
    float* x1   = ws;                               // n1*64
    float* x2in = x1   + (size_t)n1 * 64;           // n2*64
    float* x2o  = x2in + (size_t)n2 * 64;           // n2*64
    float* x3in = x2o  + (size_t)n2 * 64;           // n3*64
    float* x3o  = x3in + (size_t)n3 * 64;           // n3*128
    float* pos2 = x3o  + (size_t)n3 * 128;          // n2*3
    float* pos3 = pos2 + (size_t)n2 * 3;            // n3*3
    float* gnum = pos3 + (size_t)n3 * 3;            // 16*128
    float* cnt  = gnum + 16 * 128;                  // 16
    int*   cid  = (int*)(cnt + 16);                 // n3
    unsigned short* WfT1 = (unsigned short*)(cid + ((n3 + 4) & ~3));   // 64*128 bf16
    unsigned short* WfT2 = WfT1 + (size_t)64 * 128;        // 64*KPAD
    unsigned short* WfT3 = WfT2 + (size_t)64 * KPAD;       // 128*KPAD
    int*   rp1  = (int*)(WfT3 + (size_t)128 * KPAD);
    int*   rp2  = rp1 + ((n1 + 4) & ~3);
    int*   rp3  = rp2 + ((n2 + 4) & ~3);
    unsigned* slots1 = (unsigned*)(rp3 + ((n3 + 4) & ~3));
    unsigned* slots2 = slots1 + (size_t)E1 * 8;
    unsigned* slots3 = slots2 + (size_t)E2 * 8;
    unsigned short* A1buf = (unsigned short*)(slots3 + (size_t)E3 * 8);  // n1*128 bf16
    float*  P    = (float*)(A1buf + (size_t)n1 * 128);  // 8M floats
    unsigned short* Abuf = (unsigned short*)(P + (size_t)8 * 1024 * 1024);

    size_t usedBytes = (size_t)((char*)Abuf - (char*)ws);
    size_t availBytes = ws_size > usedBytes ? ws_size - usedBytes : 0;
    int maxRows = (int)(availBytes / ((size_t)KPAD * 2));
    maxRows &= ~63;
    if (maxRows < 64) maxRows = 64;
    int rowsP2 = ((8 * 1024 * 1024) / (NSPLIT * 64)) & ~63;
    int rowsP3 = ((8 * 1024 * 1024) / (NSPLIT * 128)) & ~63;
    int rows2 = min(min(maxRows, rowsP2), n2);
    int rows3 = min(min(maxRows, rowsP3), n3);

    float* out = (float*)d_out;

    // --- graph preprocessing ---
    rowptr_kernel<<<(E1 + 256) / 256, 256, 0, stream>>>(tgt1, E1, n1, rp1);
    rowptr_kernel<<<(E2 + 256) / 256, 256, 0, stream>>>(tgt2, E2, n2, rp2);
    rowptr_kernel<<<(E3 + 256) / 256, 256, 0, stream>>>(tgt3, E3, n3, rp3);
    posgather_kernel<<<(n2 * 3 + 255) / 256, 256, 0, stream>>>(pos, idx1, n2, pos2);
    posgather_kernel<<<(n3 * 3 + 255) / 256, 256, 0, stream>>>(pos2, idx2, n3, pos3);
    slots_kernel<<<(E1 + 255) / 256, 256, 0, stream>>>(pos,  src1, tgt1, E1, 2.5f,  126, slots1);
    slots_kernel<<<(E2 + 255) / 256, 256, 0, stream>>>(pos2, src2, tgt2, E2, 1.25f, 125, slots2);
    slots_kernel<<<(E3 + 255) / 256, 256, 0, stream>>>(pos3, src3, tgt3, E3, 0.5f,  125, slots3);
    concatWT_kernel<<<(64 * 128 + 255) / 256, 256, 0, stream>>>(W1, R1, 64, 128, KC, 1, WfT1);
    concatWT_kernel<<<(64 * KPAD + 255) / 256, 256, 0, stream>>>(W2, R2, 64, KPAD, KC * 64, 64, WfT2);
    concatWT_kernel<<<(128 * KPAD + 255) / 256, 256, 0, stream>>>(W3, R3, 128, KPAD, KC * 64, 64, WfT3);

    // --- pool prep (independent): zero accumulators, compute cloud ids + counts ---
    zero_kernel<<<(16 * 128 + 16 + 255) / 256, 256, 0, stream>>>(gnum, 16 * 128 + 16);
    cid_kernel<<<(n3 + 255) / 256, 256, 0, stream>>>(batch, idx1, idx2, n3, cid, cnt);

    // --- level 1: histogram + GEMM(K=128) ---
    histo1_kernel<<<n1 / 4, 256, 0, stream>>>(slots1, rp1, A1buf);
    {
        dim3 g1(n1 / 64, 1, 1);
        gemm_kernel<<<g1, 256, 0, stream>>>(A1buf, WfT1, n1, 64, 128, 128, P);
        combine_kernel<<<(n1 * 64 + 255) / 256, 256, 0, stream>>>(P, b1, n1, 64, 1, x1);
    }
    xgather_kernel<<<(n2 * 64 + 255) / 256, 256, 0, stream>>>(x1, idx1, n2, x2in);

    // --- level 2 ---
    run_level(slots2, src2, rp2, x2in, WfT2, b2, n2, 64, Abuf, rows2, P, x2o, stream);
    xgather_kernel<<<(n3 * 64 + 255) / 256, 256, 0, stream>>>(x2o, idx2, n3, x3in);

    // --- level 3 ---
    run_level(slots3, src3, rp3, x3in, WfT3, b3, n3, 128, Abuf, rows3, P, x3o, stream);

    // --- pool + head ---
    pool2_kernel<<<(n3 + 63) / 64, 256, 0, stream>>>(x3o, cid, n3, gnum);
    mlp_kernel<<<16, 256, 0, stream>>>(gnum, cnt, lw1, lb1, lw2, lb2, lw3, lb3, out);
}